// Round 8
// baseline (12197.896 us; speedup 1.0000x reference)
//
#include <hip/hip_runtime.h>
#include <cstdint>
#include <cstddef>

#define DEV static __device__ __forceinline__

typedef short bf16x8 __attribute__((ext_vector_type(8)));
typedef float f32x4 __attribute__((ext_vector_type(4)));
typedef unsigned short u16;

DEV float wredf(float v) {
  v += __shfl_xor(v, 32, 64); v += __shfl_xor(v, 16, 64);
  v += __shfl_xor(v, 8, 64);  v += __shfl_xor(v, 4, 64);
  v += __shfl_xor(v, 2, 64);  v += __shfl_xor(v, 1, 64);
  return v;
}

DEV void ld4(float* d, const float* p) {
  float4 t = *(const float4*)p;
  d[0] = t.x; d[1] = t.y; d[2] = t.z; d[3] = t.w;
}
DEV void st4(float* p, const float* s) {
  *(float4*)p = make_float4(s[0], s[1], s[2], s[3]);
}

// round-to-nearest-even fp32 -> bf16 bits
DEV unsigned int bfh16(float v) {
  unsigned int u = __float_as_uint(v);
  return (u + 0x7FFFu + ((u >> 16) & 1u)) >> 16;
}
// split pair (a,b) -> packed hi-word / lo-word (2x bf16 each)
DEV uint2 splitpk(float a, float b) {
  unsigned int ha = bfh16(a), hb = bfh16(b);
  float la = a - __uint_as_float(ha << 16);
  float lb = b - __uint_as_float(hb << 16);
  return make_uint2(ha | (hb << 16), bfh16(la) | (bfh16(lb) << 16));
}

// T2 swizzle for plane buffers: within each 32-elem k-segment, 16B chunk
// c -> c ^ ((row>>1)&3).  Writers store swizzled; gemm_lds reads swizzled;
// global_load_lds stages linearly (rule #21).
DEV size_t swz_idx(int row, int col, int ld) {
  return (size_t)row * ld + (col & ~31) +
         ((((col >> 3) & 3) ^ ((row >> 1) & 3)) << 3) + (col & 7);
}

// async global->LDS, 16B per lane: LDS dest = base + lane*16 (HW)
DEV void gload_lds16(const void* g, void* l) {
  __builtin_amdgcn_global_load_lds(
      (const __attribute__((address_space(1))) unsigned int*)g,
      (__attribute__((address_space(3))) unsigned int*)l, 16, 0, 0);
}

// ---- rotation/decay tables (once per launch) -----------------------------
// floats: [0,16384) rotq (s*32+i)*2 = {cos*sc, sin*sc}
//         [16384,32768) rotk = {cos/sc, sin/sc}
//         [32768,34816) gq[h][s] = gamma_h^s
//         [34816,36864) gk[h][s] = gamma_h^-s
__global__ __launch_bounds__(256)
void tab_kernel(float* __restrict__ rtab) {
  const int idx = blockIdx.x * 256 + threadIdx.x;
  if (idx < 16384) {
    const int tk = idx >> 13;          // 0=q, 1=k
    const int e = idx & 8191;
    const int s = e >> 5, i = e & 31;
    const float sv = (2.0f * i + 25.6f) / 89.6f;
    const float sc = powf(sv, (float)s / 512.0f);
    const float invf = powf(10000.0f, -(float)i / 32.0f);
    const float ang = (float)s * invf;
    const float f = tk ? 1.0f / sc : sc;
    rtab[tk * 16384 + e * 2]     = cosf(ang) * f;
    rtab[tk * 16384 + e * 2 + 1] = sinf(ang) * f;
  } else if (idx < 20480) {
    const int e = idx - 16384;         // 0..4095
    const int tk = e >> 11;            // 0=gq, 1=gk
    const int he = e & 2047;
    const int h = he >> 8, s = he & 255;
    const float l32 = logf(1.0f / 32.0f), l512 = logf(1.0f / 512.0f);
    const float gamma = 1.0f - expf(l32 + (float)h * (l512 - l32) / 7.0f);
    const float g = powf(gamma, (float)s);
    rtab[32768 + e] = tk ? 1.0f / g : g;
  }
}

// ---- embed: src = [x,t] @ emb_W + emb_b  (fp32) --------------------------
__global__ __launch_bounds__(256)
void embed_kernel(const float* __restrict__ x, const float* __restrict__ t,
                  const float* __restrict__ W, const float* __restrict__ eb,
                  float* __restrict__ X) {
  const int gid = blockIdx.x * 256 + threadIdx.x;  // R*64
  const int row = gid >> 6, d = (gid & 63) * 8;
  const float xv = x[row], tv = t[row];
  #pragma unroll
  for (int j = 0; j < 8; j++)
    X[(size_t)row * 512 + d + j] =
        xv * W[d + j] + tv * W[512 + d + j] + eb[d + j];
}

// ---- layernorm row=512, fp32 -> split bf16 hi/lo planes (swizzled) -------
__global__ __launch_bounds__(256)
void ln_split(const float* __restrict__ X, const float* __restrict__ w,
              const float* __restrict__ bb, u16* __restrict__ hi,
              u16* __restrict__ lo) {
  const int row = blockIdx.x * 4 + (threadIdx.x >> 6);
  const int lane = threadIdx.x & 63;
  const float* xp = X + (size_t)row * 512 + lane * 8;
  float4 a0 = *(const float4*)xp;
  float4 a1 = *(const float4*)(xp + 4);
  float v[8] = {a0.x, a0.y, a0.z, a0.w, a1.x, a1.y, a1.z, a1.w};
  float s = 0.f, sq = 0.f;
  #pragma unroll
  for (int j = 0; j < 8; j++) { s += v[j]; sq += v[j] * v[j]; }
  s = wredf(s); sq = wredf(sq);
  const float mean = s * (1.f / 512.f);
  const float var = fmaxf(sq * (1.f / 512.f) - mean * mean, 0.f);
  const float inv = rsqrtf(var + 1e-5f);
  const float* wp = w + lane * 8;
  const float* bp = bb + lane * 8;
  float o[8];
  #pragma unroll
  for (int j = 0; j < 8; j++)
    o[j] = (v[j] - mean) * inv * wp[j] + bp[j];
  uint2 p0 = splitpk(o[0], o[1]), p1 = splitpk(o[2], o[3]);
  uint2 p2 = splitpk(o[4], o[5]), p3 = splitpk(o[6], o[7]);
  const size_t off = swz_idx(row, lane * 8, 512);
  *(int4*)(hi + off) = make_int4(p0.x, p1.x, p2.x, p3.x);
  *(int4*)(lo + off) = make_int4(p0.y, p1.y, p2.y, p3.y);
}

// ---- plain fp32 -> split planes (swizzled), no norm (head input) ---------
__global__ __launch_bounds__(256)
void split_kernel(const float* __restrict__ X, u16* __restrict__ hi,
                  u16* __restrict__ lo) {
  const int row = blockIdx.x * 4 + (threadIdx.x >> 6);
  const int lane = threadIdx.x & 63;
  const float* xp = X + (size_t)row * 512 + lane * 8;
  float v[8];
  ld4(v, xp); ld4(v + 4, xp + 4);
  uint2 p0 = splitpk(v[0], v[1]), p1 = splitpk(v[2], v[3]);
  uint2 p2 = splitpk(v[4], v[5]), p3 = splitpk(v[6], v[7]);
  const size_t off = swz_idx(row, lane * 8, 512);
  *(int4*)(hi + off) = make_int4(p0.x, p1.x, p2.x, p3.x);
  *(int4*)(lo + off) = make_int4(p0.y, p1.y, p2.y, p3.y);
}

// ---- tiled causal retention attention + fused groupnorm ------------------
// QKV row: [Q(512) K(512) V(1024)], Q/K already rotated+decayed by the GEMM
// epilogue. Epilogue: group-norm over 128 v-dims per (row,h) + affine.
__global__ __launch_bounds__(256)
void attn_fused(const float* __restrict__ QKV, float* __restrict__ Y,
                const float* __restrict__ gw, const float* __restrict__ gb) {
  __shared__ float Qs[64][68];   // [e][s]
  __shared__ float Ks[64][68];   // [e][m]
  __shared__ float At[64][68];   // [m][s]
  const int h = blockIdx.y;
  const int r0 = blockIdx.x * 64;       // chunk-local first row
  const int b = r0 >> 8;
  const int s0 = r0 & 255;
  const int st = s0 >> 6;               // diagonal m-tile index
  const int tid = threadIdx.x;
  const int ty = tid >> 4, tx = tid & 15;

  {  // stage Q transposed
    const int rr = tid >> 2, e0 = (tid & 3) * 16;
    const float* qp = QKV + (size_t)(r0 + rr) * 2048 + h * 64 + e0;
    #pragma unroll
    for (int j = 0; j < 16; j++) Qs[e0 + j][rr] = qp[j];
  }

  float acc2[4][8];
  #pragma unroll
  for (int i = 0; i < 4; i++)
    #pragma unroll
    for (int j = 0; j < 8; j++) acc2[i][j] = 0.f;

  for (int mt = 0; mt <= st; mt++) {
    const int m0 = mt * 64;
    {  // stage K tile transposed
      const int rr = tid >> 2, e0 = (tid & 3) * 16;
      const float* kp = QKV + (size_t)(b * 256 + m0 + rr) * 2048 + 512 + h * 64 + e0;
      #pragma unroll
      for (int j = 0; j < 16; j++) Ks[e0 + j][rr] = kp[j];
    }
    __syncthreads();
    float a1[4][4];
    #pragma unroll
    for (int i = 0; i < 4; i++)
      #pragma unroll
      for (int j = 0; j < 4; j++) a1[i][j] = 0.f;
    #pragma unroll 4
    for (int e = 0; e < 64; e++) {
      float qa[4], kb[4];
      ld4(qa, &Qs[e][ty * 4]);
      ld4(kb, &Ks[e][tx * 4]);
      #pragma unroll
      for (int i = 0; i < 4; i++)
        #pragma unroll
        for (int j = 0; j < 4; j++)
          a1[i][j] = fmaf(qa[i], kb[j], a1[i][j]);
    }
    #pragma unroll
    for (int i = 0; i < 4; i++)
      #pragma unroll
      for (int j = 0; j < 4; j++) {
        float v = a1[i][j];
        if (mt == st && (m0 + tx * 4 + j) > (s0 + ty * 4 + i)) v = 0.f;
        At[tx * 4 + j][ty * 4 + i] = v;
      }
    __syncthreads();
    const float* vp = QKV + (size_t)(b * 256 + m0) * 2048 + 1024 + h * 128 + tx * 8;
    #pragma unroll 4
    for (int m = 0; m < 64; m++) {
      float av[4], vv[8];
      ld4(av, &At[m][ty * 4]);
      ld4(vv, vp);
      ld4(vv + 4, vp + 4);
      vp += 2048;
      #pragma unroll
      for (int i = 0; i < 4; i++)
        #pragma unroll
        for (int j = 0; j < 8; j++)
          acc2[i][j] = fmaf(av[i], vv[j], acc2[i][j]);
    }
    __syncthreads();
  }

  // fused group-norm epilogue: per row, reduce over the 16-lane tx group
  const int vi = h * 128 + tx * 8;
  float gwv[8], gbv[8];
  ld4(gwv, gw + vi); ld4(gwv + 4, gw + vi + 4);
  ld4(gbv, gb + vi); ld4(gbv + 4, gb + vi + 4);
  #pragma unroll
  for (int i = 0; i < 4; i++) {
    float s = 0.f, sq = 0.f;
    #pragma unroll
    for (int j = 0; j < 8; j++) { s += acc2[i][j]; sq += acc2[i][j] * acc2[i][j]; }
    #pragma unroll
    for (int msk = 1; msk <= 8; msk <<= 1) {
      s += __shfl_xor(s, msk, 64);
      sq += __shfl_xor(sq, msk, 64);
    }
    const float mean = s * (1.f / 128.f);
    const float var = fmaxf(sq * (1.f / 128.f) - mean * mean, 0.f);
    const float inv = rsqrtf(var + 1e-5f);
    float o[8];
    #pragma unroll
    for (int j = 0; j < 8; j++)
      o[j] = (acc2[i][j] - mean) * inv * gwv[j] + gbv[j];
    float* yp = Y + (size_t)(r0 + ty * 4 + i) * 1024 + vi;
    st4(yp, o);
    st4(yp + 4, o + 4);
  }
}

// ---- final N=1 dot (fp32) ------------------------------------------------
__global__ __launch_bounds__(256)
void head3_kernel(const float* __restrict__ X, const float* __restrict__ w,
                  const float* __restrict__ b3, float* __restrict__ out) {
  const int row = blockIdx.x * 4 + (threadIdx.x >> 6);
  const int lane = threadIdx.x & 63;
  const float* xp = X + (size_t)row * 512 + lane * 8;
  const float* wp = w + lane * 8;
  float s = 0.f;
  #pragma unroll
  for (int j = 0; j < 8; j++) s += xp[j] * wp[j];
  s = wredf(s);
  if (lane == 0) out[row] = s + b3[0];
}

// ---- weight pre-pack: W[K][N] -> swizzled Bt_hi/Bt_lo [N][K] bf16 --------
__global__ __launch_bounds__(256)
void pack_plain(const float* __restrict__ W, u16* __restrict__ hi,
                u16* __restrict__ lo, int N, int kshift) {
  const int idx = blockIdx.x * 256 + threadIdx.x;   // n*K + k (logical)
  const int K = 1 << kshift;
  const int n = idx >> kshift, k = idx & (K - 1);
  const float v = W[(size_t)k * N + n];
  const unsigned int h = bfh16(v);
  const float l = v - __uint_as_float(h << 16);
  const size_t o = swz_idx(n, k, K);
  hi[o] = (u16)h;
  lo[o] = (u16)bfh16(l);
}

// QKV head-interleaved mapping: col c<512 -> WQ(h,k,e), <1024 -> WK, else WV
__global__ __launch_bounds__(256)
void pack_qkv(const float* __restrict__ WQ, const float* __restrict__ WK,
              const float* __restrict__ WV, u16* __restrict__ hi,
              u16* __restrict__ lo) {
  const int idx = blockIdx.x * 256 + threadIdx.x;   // c*512 + k (logical)
  const int c = idx >> 9, k = idx & 511;
  float v;
  if (c < 512)
    v = WQ[((size_t)(c >> 6) * 512 + k) * 64 + (c & 63)];
  else if (c < 1024)
    v = WK[((size_t)((c - 512) >> 6) * 512 + k) * 64 + ((c - 512) & 63)];
  else
    v = WV[((size_t)((c - 1024) >> 7) * 512 + k) * 128 + ((c - 1024) & 127)];
  const unsigned int h = bfh16(v);
  const float l = v - __uint_as_float(h << 16);
  const size_t o = swz_idx(c, k, 512);
  hi[o] = (u16)h;
  lo[o] = (u16)bfh16(l);
}

// ---- bf16x3 MFMA GEMM, single-buffer gload_lds (m97 structure) -----------
// 32 KiB LDS -> 4-5 blocks/CU; implicit wave-level TLP hides the
// stage+drain stall (m114/m97; dbuf at 64 KiB capped occupancy at 2 - m132).
// K-step: stage(t) -> syncthreads -> frag reads + 48 MFMA -> syncthreads.
// XCD-chunked bijective remap, n-major (T1): B-panels stay L2-resident.
// EPI 0: store    1: silu(acc)*aux     2: acc+aux
//     3: gelu(acc+bias)   4: acc+bias+aux   5: w0*sin(acc+b)+w1*cos(acc+b)
//     6: QKV xpos-rotation + retention decay via rtab (V pass-through)
// OSPLIT 0: fp32 C.  1: swizzled split bf16 planes Ch/Cl.
template<int EPI, int OSPLIT>
__global__ __launch_bounds__(256)
void gemm_lds(const u16* __restrict__ Agh, const u16* __restrict__ Agl,
              const u16* __restrict__ Bh, const u16* __restrict__ Bl,
              float* __restrict__ C, u16* __restrict__ Ch, u16* __restrict__ Cl,
              const int N, const int K,
              const float* __restrict__ bias, const float* __restrict__ aux,
              const float* __restrict__ wave2, const float* __restrict__ rtab) {
  __shared__ __align__(16) u16 S[4][128][32];   // {Ah,Al,Bh,Bl} - 32 KiB
  const int tid = threadIdx.x;
  const int lane = tid & 63;
  const int wave = tid >> 6;
  const int wr = (wave >> 1) * 64, wc = (wave & 1) * 64;

  // XCD-chunked bijective remap, n-major logical order (T1)
  int bx = blockIdx.x, by = blockIdx.y;
  {
    const int gx = gridDim.x, gy = gridDim.y;
    const int nwg = gx * gy;
    if ((nwg & 7) == 0) {
      const int id = by * gx + bx;          // dispatch order (x fastest)
      const int q = nwg >> 3;
      const int L = (id & 7) * q + (id >> 3);
      bx = L / gy;                          // n-panel (contiguous per XCD)
      by = L - bx * gy;                     // m-panel
    }
  }
  const int m0 = by * 128, n0 = bx * 128;

  const int fm = lane & 15;
  const int q = lane >> 4;            // logical 16B chunk 0..3

  const u16* pb;
  if (wave == 0)      pb = Agh + (size_t)m0 * K;
  else if (wave == 1) pb = Agl + (size_t)m0 * K;
  else if (wave == 2) pb = Bh + (size_t)n0 * K;
  else                pb = Bl + (size_t)n0 * K;
  const u16* src0 = pb + (size_t)(lane >> 2) * K + (lane & 3) * 8;
  u16* dst0 = &S[wave][0][0];

  f32x4 acc[4][4];
  #pragma unroll
  for (int i = 0; i < 4; i++)
    #pragma unroll
    for (int j = 0; j < 4; j++)
      acc[i][j] = (f32x4){0.f, 0.f, 0.f, 0.f};

  for (int kt = 0; kt < K; kt += 32) {
    #pragma unroll
    for (int i = 0; i < 8; i++)
      gload_lds16(src0 + (size_t)(i * 16) * K + kt, dst0 + i * 512);
    __syncthreads();    // compiler drains vmcnt before barrier

    bf16x8 avh[4], avl[4];
    #pragma unroll
    for (int mf = 0; mf < 4; mf++) {
      const int m = wr + mf * 16 + fm;
      const int c = (q ^ ((m >> 1) & 3)) * 8;   // swizzled read
      avh[mf] = *(const bf16x8*)&S[0][m][c];
      avl[mf] = *(const bf16x8*)&S[1][m][c];
    }
    #pragma unroll
    for (int nf = 0; nf < 4; nf++) {
      const int n = wc + nf * 16 + fm;
      const int c = (q ^ ((n >> 1) & 3)) * 8;
      bf16x8 bh = *(const bf16x8*)&S[2][n][c];
      bf16x8 bl = *(const bf16x8*)&S[3][n][c];
      #pragma unroll
      for (int mf = 0; mf < 4; mf++) {
        acc[mf][nf] = __builtin_amdgcn_mfma_f32_16x16x32_bf16(avh[mf], bh, acc[mf][nf], 0, 0, 0);
        acc[mf][nf] = __builtin_amdgcn_mfma_f32_16x16x32_bf16(avl[mf], bh, acc[mf][nf], 0, 0, 0);
        acc[mf][nf] = __builtin_amdgcn_mfma_f32_16x16x32_bf16(avh[mf], bl, acc[mf][nf], 0, 0, 0);
      }
    }
    __syncthreads();
  }

  // epilogue: D frag: col = lane&15, row = (lane>>4)*4 + r
  const int r0 = m0 + wr + (lane >> 4) * 4;
  const int c0 = n0 + wc + fm;
  #pragma unroll
  for (int mf = 0; mf < 4; mf++) {
    #pragma unroll
    for (int nf = 0; nf < 4; nf++) {
      const int col = c0 + nf * 16;
      #pragma unroll
      for (int r = 0; r < 4; r++) {
        const int row = r0 + mf * 16 + r;
        const size_t idx = (size_t)row * N + col;   // logical (C, aux)
        float v = acc[mf][nf][r];
        float o;
        if constexpr (EPI == 0) {
          o = v;
        } else if constexpr (EPI == 1) {
          const float g = v / (1.f + expf(-v));
          o = g * aux[idx];
        } else if constexpr (EPI == 2) {
          o = v + aux[idx];
        } else if constexpr (EPI == 3) {
          v += bias[col];
          o = 0.5f * v * (1.f + erff(v * 0.70710678118654752f));
        } else if constexpr (EPI == 4) {
          o = v + bias[col] + aux[idx];
        } else if constexpr (EPI == 5) {
          v += bias[col];
          o = wave2[0] * sinf(v) + wave2[1] * cosf(v);
        } else {
          // EPI 6: xpos rotation + decay for Q/K cols; V pass-through.
          // partner col = col^1 lives in lane^1, same row/regs.
          const float p = __shfl_xor(v, 1, 64);
          if (col < 1024) {               // wave-uniform branch
            const int s = row & 255;
            const int cc = col & 511;
            const int hh = cc >> 6;
            const int ii = (cc & 63) >> 1;
            const bool isK = col >= 512;
            const float2 cs2 = *(const float2*)(
                rtab + (isK ? 16384 : 0) + ((size_t)s * 32 + ii) * 2);
            const float g = rtab[(isK ? 34816 : 32768) + hh * 256 + s];
            o = ((col & 1) ? (v * cs2.x + p * cs2.y)
                           : (v * cs2.x - p * cs2.y)) * g;
          } else {
            o = v;
          }
        }
        if constexpr (OSPLIT == 0) {
          C[idx] = o;
        } else {
          const size_t sidx = swz_idx(row, col, N);
          const unsigned int hb = bfh16(o);
          Ch[sidx] = (u16)hb;
          Cl[sidx] = (u16)bfh16(o - __uint_as_float(hb << 16));
        }
      }
    }
  }
}

// ---- launch --------------------------------------------------------------

extern "C" void kernel_launch(void* const* d_in, const int* in_sizes, int n_in,
                              void* d_out, int out_size, void* d_ws, size_t ws_size,
                              hipStream_t stream) {
  (void)in_sizes; (void)n_in; (void)out_size;
  const float* x    = (const float*)d_in[0];
  const float* t    = (const float*)d_in[1];
  const float* embW = (const float*)d_in[2];
  const float* embB = (const float*)d_in[3];
  const float* ln1w = (const float*)d_in[4];
  const float* ln1b = (const float*)d_in[5];
  const float* ln2w = (const float*)d_in[6];
  const float* ln2b = (const float*)d_in[7];
  const float* WQ   = (const float*)d_in[8];
  const float* WK   = (const float*)d_in[9];
  const float* WV   = (const float*)d_in[10];
  const float* WG   = (const float*)d_in[11];
  const float* WO   = (const float*)d_in[12];
  const float* gnw  = (const float*)d_in[13];
  const float* gnb  = (const float*)d_in[14];
  const float* f1W  = (const float*)d_in[15];
  const float* f1b  = (const float*)d_in[16];
  const float* f2W  = (const float*)d_in[17];
  const float* f2bp = (const float*)d_in[18];
  const float* h1W  = (const float*)d_in[19];
  const float* h1b  = (const float*)d_in[20];
  const float* wvw  = (const float*)d_in[21];
  const float* h2W  = (const float*)d_in[22];
  const float* h2b  = (const float*)d_in[23];
  const float* h3W  = (const float*)d_in[24];
  const float* h3b  = (const float*)d_in[25];

  // ---- packed-weight area (bf16 hi/lo, swizzled [N][K]) ----
  u16* P = (u16*)d_ws;
  const size_t SQKV = 2048 * 512, SWG = 1024 * 512, SWO = 512 * 1024;
  const size_t SF1 = 128 * 512, SF2 = 512 * 128;
  const size_t PERL = 2 * (SQKV + SWG + SWO + SF1 + SF2);
  const size_t HOFF = 4 * PERL;                 // heads after layers
  const size_t PACK_BYTES = (HOFF + 4 * 512 * 512) * 2;  // = 37748736
  const size_t TAB_BYTES = 36864 * 4;           // rotation/decay tables

  u16* h1h = P + HOFF;
  u16* h1l = h1h + 512 * 512;
  u16* h2h = h1l + 512 * 512;
  u16* h2l = h2h + 512 * 512;
  float* RT = (float*)((char*)d_ws + PACK_BYTES);

  const dim3 blk(256);

  // tables + pack all weights once
  tab_kernel<<<dim3(80), blk, 0, stream>>>(RT);
  for (int l = 0; l < 4; l++) {
    u16* qkvh = P + l * PERL;
    u16* qkvl = qkvh + SQKV;
    u16* wgh  = qkvl + SQKV;
    u16* wgl  = wgh + SWG;
    u16* woh  = wgl + SWG;
    u16* wol  = woh + SWO;
    u16* f1h  = wol + SWO;
    u16* f1l  = f1h + SF1;
    u16* f2h  = f1l + SF1;
    u16* f2l  = f2h + SF2;
    pack_qkv<<<dim3(SQKV / 256), blk, 0, stream>>>(
        WQ + (size_t)l * 262144, WK + (size_t)l * 262144,
        WV + (size_t)l * 524288, qkvh, qkvl);
    pack_plain<<<dim3(SWG / 256), blk, 0, stream>>>(WG + (size_t)l * 524288, wgh, wgl, 1024, 9);
    pack_plain<<<dim3(SWO / 256), blk, 0, stream>>>(WO + (size_t)l * 524288, woh, wol, 512, 10);
    pack_plain<<<dim3(SF1 / 256), blk, 0, stream>>>(f1W + (size_t)l * 65536, f1h, f1l, 128, 9);
    pack_plain<<<dim3(SF2 / 256), blk, 0, stream>>>(f2W + (size_t)l * 65536, f2h, f2l, 512, 7);
  }
  pack_plain<<<dim3(1024), blk, 0, stream>>>(h1W, h1h, h1l, 512, 9);
  pack_plain<<<dim3(1024), blk, 0, stream>>>(h2W, h2h, h2l, 512, 9);

  // ---- batch-chunking so fp32 activations fit after pack+tables ----
  const size_t BASE = PACK_BYTES + TAB_BYTES;
  int NC = 1;
  while (NC < 256) {
    const size_t R = 65536u / NC;
    if (BASE + R * 18432 + 4096 <= ws_size) break;
    NC <<= 1;
  }
  const int R = 65536 / NC;   // rows per chunk (multiple of 256)

  float* Xf   = (float*)((char*)d_ws + BASE);  // R x 512 residual
  float* Xn   = Xf  + (size_t)R * 512;   // R x 512   slot: LN planes
  float* QKVb = Xn  + (size_t)R * 512;   // R x 2048  QKV fp32; later GY planes
  float* Yb   = QKVb + (size_t)R * 2048; // R x 1024  Y fp32 / mid planes / H1
  float* Yr   = Yb  + (size_t)R * 1024;  // R x 512   Yr residual / H2 fp32

  u16* Xnh = (u16*)Xn;           u16* Xnl = Xnh + (size_t)R * 512;
  u16* GYh = (u16*)QKVb;         u16* GYl = GYh + (size_t)R * 1024;
  u16* midh = (u16*)Yb;          u16* midl = midh + (size_t)R * 128;
  u16* H1h = (u16*)Yb;           u16* H1l = H1h + (size_t)R * 512;

  for (int c = 0; c < NC; c++) {
    const size_t off = (size_t)c * R;
    embed_kernel<<<dim3(R / 4), blk, 0, stream>>>(x + off, t + off, embW, embB, Xf);

    for (int l = 0; l < 4; l++) {
      u16* qkvh = P + l * PERL;
      u16* qkvl = qkvh + SQKV;
      u16* wgh  = qkvl + SQKV;
      u16* wgl  = wgh + SWG;
      u16* woh  = wgl + SWG;
      u16* wol  = woh + SWO;
      u16* f1h  = wol + SWO;
      u16* f1l  = f1h + SF1;
      u16* f2h  = f1l + SF1;
      u16* f2l  = f2h + SF2;

      ln_split<<<dim3(R / 4), blk, 0, stream>>>(Xf, ln1w + l * 512, ln1b + l * 512, Xnh, Xnl);
      // QKV = Xn @ [WQ|WK|WV][l], rotation+decay fused in epilogue
      gemm_lds<6, 0><<<dim3(16, R / 128), blk, 0, stream>>>(
          Xnh, Xnl, qkvh, qkvl, QKVb, nullptr, nullptr,
          2048, 512, nullptr, nullptr, nullptr, RT);
      // causal retention attention + fused groupnorm
      attn_fused<<<dim3(R / 64, 8), blk, 0, stream>>>(
          QKVb, Yb, gnw + l * 1024, gnb + l * 1024);
      // GY = silu(Xn @ WG[l]) * Y  -> split planes in QKVb (QKV dead)
      gemm_lds<1, 1><<<dim3(8, R / 128), blk, 0, stream>>>(
          Xnh, Xnl, wgh, wgl, nullptr, GYh, GYl,
          1024, 512, nullptr, Yb, nullptr, nullptr);
      // Yr = GY @ WO[l] + X
      gemm_lds<2, 0><<<dim3(4, R / 128), blk, 0, stream>>>(
          GYh, GYl, woh, wol, Yr, nullptr, nullptr,
          512, 1024, nullptr, Xf, nullptr, nullptr);
      ln_split<<<dim3(R / 4), blk, 0, stream>>>(Yr, ln2w + l * 512, ln2b + l * 512, Xnh, Xnl);
      // mid = gelu(Xn @ f1[l] + b1)  -> split planes in Yb
      gemm_lds<3, 1><<<dim3(1, R / 128), blk, 0, stream>>>(
          Xnh, Xnl, f1h, f1l, nullptr, midh, midl,
          128, 512, f1b + l * 128, nullptr, nullptr, nullptr);
      // X = mid @ f2[l] + b2 + Yr
      gemm_lds<4, 0><<<dim3(4, R / 128), blk, 0, stream>>>(
          midh, midl, f2h, f2l, Xf, nullptr, nullptr,
          512, 128, f2bp + l * 512, Yr, nullptr, nullptr);
    }

    // head: split Xf once, then gemm_lds all the way
    split_kernel<<<dim3(R / 4), blk, 0, stream>>>(Xf, Xnh, Xnl);
    gemm_lds<5, 1><<<dim3(4, R / 128), blk, 0, stream>>>(
        Xnh, Xnl, h1h, h1l, nullptr, H1h, H1l,
        512, 512, h1b, nullptr, wvw, nullptr);
    gemm_lds<5, 0><<<dim3(4, R / 128), blk, 0, stream>>>(
        H1h, H1l, h2h, h2l, Yr, nullptr, nullptr,
        512, 512, h2b, nullptr, wvw + 2, nullptr);
    head3_kernel<<<dim3(R / 4), blk, 0, stream>>>(
        Yr, h3W, h3b, (float*)d_out + off);
  }
}

// Round 9
// 11163.966 us; speedup vs baseline: 1.0926x; 1.0926x over previous
//
#include <hip/hip_runtime.h>
#include <cstdint>
#include <cstddef>

#define DEV static __device__ __forceinline__

typedef short bf16x8 __attribute__((ext_vector_type(8)));
typedef float f32x4 __attribute__((ext_vector_type(4)));
typedef unsigned short u16;

DEV float wredf(float v) {
  v += __shfl_xor(v, 32, 64); v += __shfl_xor(v, 16, 64);
  v += __shfl_xor(v, 8, 64);  v += __shfl_xor(v, 4, 64);
  v += __shfl_xor(v, 2, 64);  v += __shfl_xor(v, 1, 64);
  return v;
}

DEV void ld4(float* d, const float* p) {
  float4 t = *(const float4*)p;
  d[0] = t.x; d[1] = t.y; d[2] = t.z; d[3] = t.w;
}
DEV void st4(float* p, const float* s) {
  *(float4*)p = make_float4(s[0], s[1], s[2], s[3]);
}

// round-to-nearest-even fp32 -> bf16 bits
DEV unsigned int bfh16(float v) {
  unsigned int u = __float_as_uint(v);
  return (u + 0x7FFFu + ((u >> 16) & 1u)) >> 16;
}
// split pair (a,b) -> packed hi-word / lo-word (2x bf16 each)
DEV uint2 splitpk(float a, float b) {
  unsigned int ha = bfh16(a), hb = bfh16(b);
  float la = a - __uint_as_float(ha << 16);
  float lb = b - __uint_as_float(hb << 16);
  return make_uint2(ha | (hb << 16), bfh16(la) | (bfh16(lb) << 16));
}

// T2 swizzle for plane buffers: within each 32-elem k-segment, 16B chunk
// c -> c ^ ((row>>1)&3).  Writers store swizzled; gemm_lds reads swizzled;
// global_load_lds stages linearly (rule #21).
DEV size_t swz_idx(int row, int col, int ld) {
  return (size_t)row * ld + (col & ~31) +
         ((((col >> 3) & 3) ^ ((row >> 1) & 3)) << 3) + (col & 7);
}

// async global->LDS, 16B per lane: LDS dest = base + lane*16 (HW)
DEV void gload_lds16(const void* g, void* l) {
  __builtin_amdgcn_global_load_lds(
      (const __attribute__((address_space(1))) unsigned int*)g,
      (__attribute__((address_space(3))) unsigned int*)l, 16, 0, 0);
}

// ---- rotation/decay tables (once per launch) -----------------------------
// floats: [0,16384) rotq (s*32+i)*2 = {cos*sc, sin*sc}
//         [16384,32768) rotk = {cos/sc, sin/sc}
//         [32768,34816) gq[h][s] = gamma_h^s
//         [34816,36864) gk[h][s] = gamma_h^-s
__global__ __launch_bounds__(256)
void tab_kernel(float* __restrict__ rtab) {
  const int idx = blockIdx.x * 256 + threadIdx.x;
  if (idx < 16384) {
    const int tk = idx >> 13;          // 0=q, 1=k
    const int e = idx & 8191;
    const int s = e >> 5, i = e & 31;
    const float sv = (2.0f * i + 25.6f) / 89.6f;
    const float sc = powf(sv, (float)s / 512.0f);
    const float invf = powf(10000.0f, -(float)i / 32.0f);
    const float ang = (float)s * invf;
    const float f = tk ? 1.0f / sc : sc;
    rtab[tk * 16384 + e * 2]     = cosf(ang) * f;
    rtab[tk * 16384 + e * 2 + 1] = sinf(ang) * f;
  } else if (idx < 20480) {
    const int e = idx - 16384;         // 0..4095
    const int tk = e >> 11;            // 0=gq, 1=gk
    const int he = e & 2047;
    const int h = he >> 8, s = he & 255;
    const float l32 = logf(1.0f / 32.0f), l512 = logf(1.0f / 512.0f);
    const float gamma = 1.0f - expf(l32 + (float)h * (l512 - l32) / 7.0f);
    const float g = powf(gamma, (float)s);
    rtab[32768 + e] = tk ? 1.0f / g : g;
  }
}

// ---- embed: src = [x,t] @ emb_W + emb_b  (fp32) --------------------------
__global__ __launch_bounds__(256)
void embed_kernel(const float* __restrict__ x, const float* __restrict__ t,
                  const float* __restrict__ W, const float* __restrict__ eb,
                  float* __restrict__ X) {
  const int gid = blockIdx.x * 256 + threadIdx.x;  // R*64
  const int row = gid >> 6, d = (gid & 63) * 8;
  const float xv = x[row], tv = t[row];
  #pragma unroll
  for (int j = 0; j < 8; j++)
    X[(size_t)row * 512 + d + j] =
        xv * W[d + j] + tv * W[512 + d + j] + eb[d + j];
}

// ---- layernorm row=512, fp32 -> split bf16 hi/lo planes (swizzled) -------
__global__ __launch_bounds__(256)
void ln_split(const float* __restrict__ X, const float* __restrict__ w,
              const float* __restrict__ bb, u16* __restrict__ hi,
              u16* __restrict__ lo) {
  const int row = blockIdx.x * 4 + (threadIdx.x >> 6);
  const int lane = threadIdx.x & 63;
  const float* xp = X + (size_t)row * 512 + lane * 8;
  float4 a0 = *(const float4*)xp;
  float4 a1 = *(const float4*)(xp + 4);
  float v[8] = {a0.x, a0.y, a0.z, a0.w, a1.x, a1.y, a1.z, a1.w};
  float s = 0.f, sq = 0.f;
  #pragma unroll
  for (int j = 0; j < 8; j++) { s += v[j]; sq += v[j] * v[j]; }
  s = wredf(s); sq = wredf(sq);
  const float mean = s * (1.f / 512.f);
  const float var = fmaxf(sq * (1.f / 512.f) - mean * mean, 0.f);
  const float inv = rsqrtf(var + 1e-5f);
  const float* wp = w + lane * 8;
  const float* bp = bb + lane * 8;
  float o[8];
  #pragma unroll
  for (int j = 0; j < 8; j++)
    o[j] = (v[j] - mean) * inv * wp[j] + bp[j];
  uint2 p0 = splitpk(o[0], o[1]), p1 = splitpk(o[2], o[3]);
  uint2 p2 = splitpk(o[4], o[5]), p3 = splitpk(o[6], o[7]);
  const size_t off = swz_idx(row, lane * 8, 512);
  *(int4*)(hi + off) = make_int4(p0.x, p1.x, p2.x, p3.x);
  *(int4*)(lo + off) = make_int4(p0.y, p1.y, p2.y, p3.y);
}

// ---- plain fp32 -> split planes (swizzled), no norm (head input) ---------
__global__ __launch_bounds__(256)
void split_kernel(const float* __restrict__ X, u16* __restrict__ hi,
                  u16* __restrict__ lo) {
  const int row = blockIdx.x * 4 + (threadIdx.x >> 6);
  const int lane = threadIdx.x & 63;
  const float* xp = X + (size_t)row * 512 + lane * 8;
  float v[8];
  ld4(v, xp); ld4(v + 4, xp + 4);
  uint2 p0 = splitpk(v[0], v[1]), p1 = splitpk(v[2], v[3]);
  uint2 p2 = splitpk(v[4], v[5]), p3 = splitpk(v[6], v[7]);
  const size_t off = swz_idx(row, lane * 8, 512);
  *(int4*)(hi + off) = make_int4(p0.x, p1.x, p2.x, p3.x);
  *(int4*)(lo + off) = make_int4(p0.y, p1.y, p2.y, p3.y);
}

// ---- tiled causal retention attention + groupnorm + gate -> GY planes ----
// QKVG row (3072): [Q(512) K(512) V(1024) G(1024)]; Q/K pre-rotated+decayed,
// G pre-silu'd (all by the QKVG GEMM epilogue). Epilogue here: group-norm
// over 128 v-dims per (row,h), affine, multiply by G, write split planes.
__global__ __launch_bounds__(256)
void attn_fused(const float* __restrict__ QKV, u16* __restrict__ GYh,
                u16* __restrict__ GYl, const float* __restrict__ gw,
                const float* __restrict__ gb) {
  __shared__ float Qs[64][68];   // [e][s]
  __shared__ float Ks[64][68];   // [e][m]
  __shared__ float At[64][68];   // [m][s]
  const int h = blockIdx.y;
  const int r0 = blockIdx.x * 64;       // chunk-local first row
  const int b = r0 >> 8;
  const int s0 = r0 & 255;
  const int st = s0 >> 6;               // diagonal m-tile index
  const int tid = threadIdx.x;
  const int ty = tid >> 4, tx = tid & 15;

  {  // stage Q transposed
    const int rr = tid >> 2, e0 = (tid & 3) * 16;
    const float* qp = QKV + (size_t)(r0 + rr) * 3072 + h * 64 + e0;
    #pragma unroll
    for (int j = 0; j < 16; j++) Qs[e0 + j][rr] = qp[j];
  }

  float acc2[4][8];
  #pragma unroll
  for (int i = 0; i < 4; i++)
    #pragma unroll
    for (int j = 0; j < 8; j++) acc2[i][j] = 0.f;

  for (int mt = 0; mt <= st; mt++) {
    const int m0 = mt * 64;
    {  // stage K tile transposed
      const int rr = tid >> 2, e0 = (tid & 3) * 16;
      const float* kp = QKV + (size_t)(b * 256 + m0 + rr) * 3072 + 512 + h * 64 + e0;
      #pragma unroll
      for (int j = 0; j < 16; j++) Ks[e0 + j][rr] = kp[j];
    }
    __syncthreads();
    float a1[4][4];
    #pragma unroll
    for (int i = 0; i < 4; i++)
      #pragma unroll
      for (int j = 0; j < 4; j++) a1[i][j] = 0.f;
    #pragma unroll 4
    for (int e = 0; e < 64; e++) {
      float qa[4], kb[4];
      ld4(qa, &Qs[e][ty * 4]);
      ld4(kb, &Ks[e][tx * 4]);
      #pragma unroll
      for (int i = 0; i < 4; i++)
        #pragma unroll
        for (int j = 0; j < 4; j++)
          a1[i][j] = fmaf(qa[i], kb[j], a1[i][j]);
    }
    #pragma unroll
    for (int i = 0; i < 4; i++)
      #pragma unroll
      for (int j = 0; j < 4; j++) {
        float v = a1[i][j];
        if (mt == st && (m0 + tx * 4 + j) > (s0 + ty * 4 + i)) v = 0.f;
        At[tx * 4 + j][ty * 4 + i] = v;
      }
    __syncthreads();
    const float* vp = QKV + (size_t)(b * 256 + m0) * 3072 + 1024 + h * 128 + tx * 8;
    #pragma unroll 4
    for (int m = 0; m < 64; m++) {
      float av[4], vv[8];
      ld4(av, &At[m][ty * 4]);
      ld4(vv, vp);
      ld4(vv + 4, vp + 4);
      vp += 3072;
      #pragma unroll
      for (int i = 0; i < 4; i++)
        #pragma unroll
        for (int j = 0; j < 8; j++)
          acc2[i][j] = fmaf(av[i], vv[j], acc2[i][j]);
    }
    __syncthreads();
  }

  // epilogue: groupnorm (16-lane tx reduce) + affine + gate + split planes
  const int vi = h * 128 + tx * 8;
  float gwv[8], gbv[8];
  ld4(gwv, gw + vi); ld4(gwv + 4, gw + vi + 4);
  ld4(gbv, gb + vi); ld4(gbv + 4, gb + vi + 4);
  #pragma unroll
  for (int i = 0; i < 4; i++) {
    const int row = r0 + ty * 4 + i;
    float s = 0.f, sq = 0.f;
    #pragma unroll
    for (int j = 0; j < 8; j++) { s += acc2[i][j]; sq += acc2[i][j] * acc2[i][j]; }
    #pragma unroll
    for (int msk = 1; msk <= 8; msk <<= 1) {
      s += __shfl_xor(s, msk, 64);
      sq += __shfl_xor(sq, msk, 64);
    }
    const float mean = s * (1.f / 128.f);
    const float var = fmaxf(sq * (1.f / 128.f) - mean * mean, 0.f);
    const float inv = rsqrtf(var + 1e-5f);
    const float* gp = QKV + (size_t)row * 3072 + 2048 + vi;
    float gs[8];
    ld4(gs, gp); ld4(gs + 4, gp + 4);
    float o[8];
    #pragma unroll
    for (int j = 0; j < 8; j++)
      o[j] = ((acc2[i][j] - mean) * inv * gwv[j] + gbv[j]) * gs[j];
    uint2 p0 = splitpk(o[0], o[1]), p1 = splitpk(o[2], o[3]);
    uint2 p2 = splitpk(o[4], o[5]), p3 = splitpk(o[6], o[7]);
    const size_t off = swz_idx(row, vi, 1024);
    *(int4*)(GYh + off) = make_int4(p0.x, p1.x, p2.x, p3.x);
    *(int4*)(GYl + off) = make_int4(p0.y, p1.y, p2.y, p3.y);
  }
}

// ---- final N=1 dot (fp32) ------------------------------------------------
__global__ __launch_bounds__(256)
void head3_kernel(const float* __restrict__ X, const float* __restrict__ w,
                  const float* __restrict__ b3, float* __restrict__ out) {
  const int row = blockIdx.x * 4 + (threadIdx.x >> 6);
  const int lane = threadIdx.x & 63;
  const float* xp = X + (size_t)row * 512 + lane * 8;
  const float* wp = w + lane * 8;
  float s = 0.f;
  #pragma unroll
  for (int j = 0; j < 8; j++) s += xp[j] * wp[j];
  s = wredf(s);
  if (lane == 0) out[row] = s + b3[0];
}

// ---- weight pre-pack: W[K][N] -> swizzled Bt_hi/Bt_lo [N][K] bf16 --------
__global__ __launch_bounds__(256)
void pack_plain(const float* __restrict__ W, u16* __restrict__ hi,
                u16* __restrict__ lo, int N, int kshift) {
  const int idx = blockIdx.x * 256 + threadIdx.x;   // n*K + k (logical)
  const int K = 1 << kshift;
  const int n = idx >> kshift, k = idx & (K - 1);
  const float v = W[(size_t)k * N + n];
  const unsigned int h = bfh16(v);
  const float l = v - __uint_as_float(h << 16);
  const size_t o = swz_idx(n, k, K);
  hi[o] = (u16)h;
  lo[o] = (u16)bfh16(l);
}

// QKVG mapping: c<512 WQ(h,k,e); <1024 WK; <2048 WV(h,k,v); else WG[k][c-2048]
__global__ __launch_bounds__(256)
void pack_qkvg(const float* __restrict__ WQ, const float* __restrict__ WK,
               const float* __restrict__ WV, const float* __restrict__ WG,
               u16* __restrict__ hi, u16* __restrict__ lo) {
  const int idx = blockIdx.x * 256 + threadIdx.x;   // c*512 + k (logical)
  const int c = idx >> 9, k = idx & 511;
  float v;
  if (c < 512)
    v = WQ[((size_t)(c >> 6) * 512 + k) * 64 + (c & 63)];
  else if (c < 1024)
    v = WK[((size_t)((c - 512) >> 6) * 512 + k) * 64 + ((c - 512) & 63)];
  else if (c < 2048)
    v = WV[((size_t)((c - 1024) >> 7) * 512 + k) * 128 + ((c - 1024) & 127)];
  else
    v = WG[(size_t)k * 1024 + (c - 2048)];
  const unsigned int h = bfh16(v);
  const float l = v - __uint_as_float(h << 16);
  const size_t o = swz_idx(c, k, 512);
  hi[o] = (u16)h;
  lo[o] = (u16)bfh16(l);
}

// ---- bf16x3 MFMA GEMM, dbuf gload_lds + counted vmcnt + XCD swizzle ------
// (R7 structure - best measured.)  K-step t: issue stage(t+1) ->
// s_waitcnt vmcnt(8) -> s_barrier -> frag reads + 48 MFMA -> s_barrier.
// EPI 0: store    2: acc+aux   3: gelu(acc+bias)   4: acc+bias+aux
//     5: w0*sin(acc+b)+w1*cos(acc+b)
//     6: QKVG epilogue: col<1024 rotate+decay; <2048 V pass; >=2048 silu
// OSPLIT 0: fp32 C.  1: swizzled split bf16 planes Ch/Cl.
template<int EPI, int OSPLIT>
__global__ __launch_bounds__(256, 2)
void gemm_lds(const u16* __restrict__ Agh, const u16* __restrict__ Agl,
              const u16* __restrict__ Bh, const u16* __restrict__ Bl,
              float* __restrict__ C, u16* __restrict__ Ch, u16* __restrict__ Cl,
              const int N, const int K,
              const float* __restrict__ bias, const float* __restrict__ aux,
              const float* __restrict__ wave2, const float* __restrict__ rtab) {
  __shared__ __align__(16) u16 S[2][4][128][32];   // dbuf x {Ah,Al,Bh,Bl}
  const int tid = threadIdx.x;
  const int lane = tid & 63;
  const int wave = tid >> 6;
  const int wr = (wave >> 1) * 64, wc = (wave & 1) * 64;

  // XCD-chunked bijective remap, n-major logical order (T1)
  int bx = blockIdx.x, by = blockIdx.y;
  {
    const int gx = gridDim.x, gy = gridDim.y;
    const int nwg = gx * gy;
    if ((nwg & 7) == 0) {
      const int id = by * gx + bx;          // dispatch order (x fastest)
      const int q = nwg >> 3;
      const int L = (id & 7) * q + (id >> 3);
      bx = L / gy;                          // n-panel (contiguous per XCD)
      by = L - bx * gy;                     // m-panel
    }
  }
  const int m0 = by * 128, n0 = bx * 128;

  const int fm = lane & 15;
  const int q = lane >> 4;            // logical 16B chunk 0..3

  const u16* pb;
  if (wave == 0)      pb = Agh + (size_t)m0 * K;
  else if (wave == 1) pb = Agl + (size_t)m0 * K;
  else if (wave == 2) pb = Bh + (size_t)n0 * K;
  else                pb = Bl + (size_t)n0 * K;
  const u16* src0 = pb + (size_t)(lane >> 2) * K + (lane & 3) * 8;

  f32x4 acc[4][4];
  #pragma unroll
  for (int i = 0; i < 4; i++)
    #pragma unroll
    for (int j = 0; j < 4; j++)
      acc[i][j] = (f32x4){0.f, 0.f, 0.f, 0.f};

  {  // prologue: stage tile 0 into buf 0 (full drain via __syncthreads)
    u16* dst = &S[0][wave][0][0];
    #pragma unroll
    for (int i = 0; i < 8; i++)
      gload_lds16(src0 + (size_t)(i * 16) * K, dst + i * 512);
  }
  __syncthreads();

  for (int kt = 0; kt < K; kt += 32) {
    const int cur = (kt >> 5) & 1;
    if (kt + 32 < K) {  // issue next tile; keep its 8 loads in flight
      u16* dst = &S[cur ^ 1][wave][0][0];
      const u16* s = src0 + kt + 32;
      #pragma unroll
      for (int i = 0; i < 8; i++)
        gload_lds16(s + (size_t)(i * 16) * K, dst + i * 512);
      asm volatile("s_waitcnt vmcnt(8)" ::: "memory");
    } else {
      asm volatile("s_waitcnt vmcnt(0)" ::: "memory");
    }
    __builtin_amdgcn_sched_barrier(0);
    __builtin_amdgcn_s_barrier();
    __builtin_amdgcn_sched_barrier(0);

    bf16x8 avh[4], avl[4];
    #pragma unroll
    for (int mf = 0; mf < 4; mf++) {
      const int m = wr + mf * 16 + fm;
      const int c = (q ^ ((m >> 1) & 3)) * 8;   // swizzled read
      avh[mf] = *(const bf16x8*)&S[cur][0][m][c];
      avl[mf] = *(const bf16x8*)&S[cur][1][m][c];
    }
    #pragma unroll
    for (int nf = 0; nf < 4; nf++) {
      const int n = wc + nf * 16 + fm;
      const int c = (q ^ ((n >> 1) & 3)) * 8;
      bf16x8 bh = *(const bf16x8*)&S[cur][2][n][c];
      bf16x8 bl = *(const bf16x8*)&S[cur][3][n][c];
      #pragma unroll
      for (int mf = 0; mf < 4; mf++) {
        acc[mf][nf] = __builtin_amdgcn_mfma_f32_16x16x32_bf16(avh[mf], bh, acc[mf][nf], 0, 0, 0);
        acc[mf][nf] = __builtin_amdgcn_mfma_f32_16x16x32_bf16(avl[mf], bh, acc[mf][nf], 0, 0, 0);
        acc[mf][nf] = __builtin_amdgcn_mfma_f32_16x16x32_bf16(avh[mf], bl, acc[mf][nf], 0, 0, 0);
      }
    }
    __builtin_amdgcn_sched_barrier(0);
    __builtin_amdgcn_s_barrier();
  }

  // epilogue: D frag: col = lane&15, row = (lane>>4)*4 + r
  const int r0 = m0 + wr + (lane >> 4) * 4;
  const int c0 = n0 + wc + fm;
  #pragma unroll
  for (int mf = 0; mf < 4; mf++) {
    #pragma unroll
    for (int nf = 0; nf < 4; nf++) {
      const int col = c0 + nf * 16;
      #pragma unroll
      for (int r = 0; r < 4; r++) {
        const int row = r0 + mf * 16 + r;
        const size_t idx = (size_t)row * N + col;   // logical (C, aux)
        float v = acc[mf][nf][r];
        float o;
        if constexpr (EPI == 0) {
          o = v;
        } else if constexpr (EPI == 2) {
          o = v + aux[idx];
        } else if constexpr (EPI == 3) {
          v += bias[col];
          o = 0.5f * v * (1.f + erff(v * 0.70710678118654752f));
        } else if constexpr (EPI == 4) {
          o = v + bias[col] + aux[idx];
        } else if constexpr (EPI == 5) {
          v += bias[col];
          o = wave2[0] * sinf(v) + wave2[1] * cosf(v);
        } else {
          // EPI 6: QKVG.  partner col = col^1 lives in lane^1.
          const float p = __shfl_xor(v, 1, 64);
          if (col < 1024) {               // wave-uniform per nf
            const int s = row & 255;
            const int cc = col & 511;
            const int hh = cc >> 6;
            const int ii = (cc & 63) >> 1;
            const bool isK = col >= 512;
            const float2 cs2 = *(const float2*)(
                rtab + (isK ? 16384 : 0) + ((size_t)s * 32 + ii) * 2);
            const float g = rtab[(isK ? 34816 : 32768) + hh * 256 + s];
            o = ((col & 1) ? (v * cs2.x + p * cs2.y)
                           : (v * cs2.x - p * cs2.y)) * g;
          } else if (col < 2048) {
            o = v;                        // V pass-through
          } else {
            o = v / (1.f + expf(-v));     // silu for gate
          }
        }
        if constexpr (OSPLIT == 0) {
          C[idx] = o;
        } else {
          const size_t sidx = swz_idx(row, col, N);
          const unsigned int hb = bfh16(o);
          Ch[sidx] = (u16)hb;
          Cl[sidx] = (u16)bfh16(o - __uint_as_float(hb << 16));
        }
      }
    }
  }
}

// ---- launch --------------------------------------------------------------

extern "C" void kernel_launch(void* const* d_in, const int* in_sizes, int n_in,
                              void* d_out, int out_size, void* d_ws, size_t ws_size,
                              hipStream_t stream) {
  (void)in_sizes; (void)n_in; (void)out_size;
  const float* x    = (const float*)d_in[0];
  const float* t    = (const float*)d_in[1];
  const float* embW = (const float*)d_in[2];
  const float* embB = (const float*)d_in[3];
  const float* ln1w = (const float*)d_in[4];
  const float* ln1b = (const float*)d_in[5];
  const float* ln2w = (const float*)d_in[6];
  const float* ln2b = (const float*)d_in[7];
  const float* WQ   = (const float*)d_in[8];
  const float* WK   = (const float*)d_in[9];
  const float* WV   = (const float*)d_in[10];
  const float* WG   = (const float*)d_in[11];
  const float* WO   = (const float*)d_in[12];
  const float* gnw  = (const float*)d_in[13];
  const float* gnb  = (const float*)d_in[14];
  const float* f1W  = (const float*)d_in[15];
  const float* f1b  = (const float*)d_in[16];
  const float* f2W  = (const float*)d_in[17];
  const float* f2bp = (const float*)d_in[18];
  const float* h1W  = (const float*)d_in[19];
  const float* h1b  = (const float*)d_in[20];
  const float* wvw  = (const float*)d_in[21];
  const float* h2W  = (const float*)d_in[22];
  const float* h2b  = (const float*)d_in[23];
  const float* h3W  = (const float*)d_in[24];
  const float* h3b  = (const float*)d_in[25];

  // ---- packed-weight area (bf16 hi/lo, swizzled [N][K]) ----
  u16* P = (u16*)d_ws;
  const size_t SQKVG = 3072 * 512, SWO = 512 * 1024;
  const size_t SF1 = 128 * 512, SF2 = 512 * 128;
  const size_t PERL = 2 * (SQKVG + SWO + SF1 + SF2);
  const size_t HOFF = 4 * PERL;                 // heads after layers
  const size_t PACK_BYTES = (HOFF + 4 * 512 * 512) * 2;  // = 37748736
  const size_t TAB_BYTES = 36864 * 4;           // rotation/decay tables

  u16* h1h = P + HOFF;
  u16* h1l = h1h + 512 * 512;
  u16* h2h = h1l + 512 * 512;
  u16* h2l = h2h + 512 * 512;
  float* RT = (float*)((char*)d_ws + PACK_BYTES);

  const dim3 blk(256);

  // tables + pack all weights once
  tab_kernel<<<dim3(80), blk, 0, stream>>>(RT);
  for (int l = 0; l < 4; l++) {
    u16* qkvh = P + l * PERL;
    u16* qkvl = qkvh + SQKVG;
    u16* woh  = qkvl + SQKVG;
    u16* wol  = woh + SWO;
    u16* f1h  = wol + SWO;
    u16* f1l  = f1h + SF1;
    u16* f2h  = f1l + SF1;
    u16* f2l  = f2h + SF2;
    pack_qkvg<<<dim3(SQKVG / 256), blk, 0, stream>>>(
        WQ + (size_t)l * 262144, WK + (size_t)l * 262144,
        WV + (size_t)l * 524288, WG + (size_t)l * 524288, qkvh, qkvl);
    pack_plain<<<dim3(SWO / 256), blk, 0, stream>>>(WO + (size_t)l * 524288, woh, wol, 512, 10);
    pack_plain<<<dim3(SF1 / 256), blk, 0, stream>>>(f1W + (size_t)l * 65536, f1h, f1l, 128, 9);
    pack_plain<<<dim3(SF2 / 256), blk, 0, stream>>>(f2W + (size_t)l * 65536, f2h, f2l, 512, 7);
  }
  pack_plain<<<dim3(1024), blk, 0, stream>>>(h1W, h1h, h1l, 512, 9);
  pack_plain<<<dim3(1024), blk, 0, stream>>>(h2W, h2h, h2l, 512, 9);

  // ---- batch-chunking so fp32 activations fit after pack+tables ----
  // per-row floats: Xf 512 + Xn 512 + QKVG 3072 + GY 1024 + Yr 512 = 5632
  const size_t BASE = PACK_BYTES + TAB_BYTES;
  int NC = 1;
  while (NC < 256) {
    const size_t R = 65536u / NC;
    if (BASE + R * 22528 + 4096 <= ws_size) break;
    NC <<= 1;
  }
  const int R = 65536 / NC;   // rows per chunk (multiple of 256)

  float* Xf   = (float*)((char*)d_ws + BASE);  // R x 512 residual
  float* Xn   = Xf  + (size_t)R * 512;   // R x 512   LN planes
  float* QKVG = Xn  + (size_t)R * 512;   // R x 3072  QKVG fp32
  float* GYb  = QKVG + (size_t)R * 3072; // R x 1024  GY planes / mid / H1
  float* Yr   = GYb + (size_t)R * 1024;  // R x 512   Yr residual / H2 fp32

  u16* Xnh = (u16*)Xn;           u16* Xnl = Xnh + (size_t)R * 512;
  u16* GYh = (u16*)GYb;          u16* GYl = GYh + (size_t)R * 1024;
  u16* midh = (u16*)GYb;         u16* midl = midh + (size_t)R * 128;
  u16* H1h = (u16*)GYb;          u16* H1l = H1h + (size_t)R * 512;

  for (int c = 0; c < NC; c++) {
    const size_t off = (size_t)c * R;
    embed_kernel<<<dim3(R / 4), blk, 0, stream>>>(x + off, t + off, embW, embB, Xf);

    for (int l = 0; l < 4; l++) {
      u16* qkvh = P + l * PERL;
      u16* qkvl = qkvh + SQKVG;
      u16* woh  = qkvl + SQKVG;
      u16* wol  = woh + SWO;
      u16* f1h  = wol + SWO;
      u16* f1l  = f1h + SF1;
      u16* f2h  = f1l + SF1;
      u16* f2l  = f2h + SF2;

      ln_split<<<dim3(R / 4), blk, 0, stream>>>(Xf, ln1w + l * 512, ln1b + l * 512, Xnh, Xnl);
      // [Q|K|V|G] = Xn @ [WQ|WK|WV|WG][l]; rotate/decay + silu in epilogue
      gemm_lds<6, 0><<<dim3(24, R / 128), blk, 0, stream>>>(
          Xnh, Xnl, qkvh, qkvl, QKVG, nullptr, nullptr,
          3072, 512, nullptr, nullptr, nullptr, RT);
      // retention attention + groupnorm + gate -> GY planes
      attn_fused<<<dim3(R / 64, 8), blk, 0, stream>>>(
          QKVG, GYh, GYl, gnw + l * 1024, gnb + l * 1024);
      // Yr = GY @ WO[l] + X
      gemm_lds<2, 0><<<dim3(4, R / 128), blk, 0, stream>>>(
          GYh, GYl, woh, wol, Yr, nullptr, nullptr,
          512, 1024, nullptr, Xf, nullptr, nullptr);
      ln_split<<<dim3(R / 4), blk, 0, stream>>>(Yr, ln2w + l * 512, ln2b + l * 512, Xnh, Xnl);
      // mid = gelu(Xn @ f1[l] + b1)  -> split planes (GY slot dead)
      gemm_lds<3, 1><<<dim3(1, R / 128), blk, 0, stream>>>(
          Xnh, Xnl, f1h, f1l, nullptr, midh, midl,
          128, 512, f1b + l * 128, nullptr, nullptr, nullptr);
      // X = mid @ f2[l] + b2 + Yr
      gemm_lds<4, 0><<<dim3(4, R / 128), blk, 0, stream>>>(
          midh, midl, f2h, f2l, Xf, nullptr, nullptr,
          512, 128, f2bp + l * 512, Yr, nullptr, nullptr);
    }

    // head: split Xf once, then gemm_lds all the way
    split_kernel<<<dim3(R / 4), blk, 0, stream>>>(Xf, Xnh, Xnl);
    gemm_lds<5, 1><<<dim3(4, R / 128), blk, 0, stream>>>(
        Xnh, Xnl, h1h, h1l, nullptr, H1h, H1l,
        512, 512, h1b, nullptr, wvw, nullptr);
    gemm_lds<5, 0><<<dim3(4, R / 128), blk, 0, stream>>>(
        H1h, H1l, h2h, h2l, Yr, nullptr, nullptr,
        512, 512, h2b, nullptr, wvw + 2, nullptr);
    head3_kernel<<<dim3(R / 4), blk, 0, stream>>>(
        Yr, h3W, h3b, (float*)d_out + off);
  }
}

// Round 10
// 10100.614 us; speedup vs baseline: 1.2076x; 1.1053x over previous
//
#include <hip/hip_runtime.h>
#include <cstdint>
#include <cstddef>

#define DEV static __device__ __forceinline__

typedef short bf16x8 __attribute__((ext_vector_type(8)));
typedef float f32x4 __attribute__((ext_vector_type(4)));
typedef unsigned short u16;

DEV float wredf(float v) {
  v += __shfl_xor(v, 32, 64); v += __shfl_xor(v, 16, 64);
  v += __shfl_xor(v, 8, 64);  v += __shfl_xor(v, 4, 64);
  v += __shfl_xor(v, 2, 64);  v += __shfl_xor(v, 1, 64);
  return v;
}

DEV void ld4(float* d, const float* p) {
  float4 t = *(const float4*)p;
  d[0] = t.x; d[1] = t.y; d[2] = t.z; d[3] = t.w;
}
DEV void st4(float* p, const float* s) {
  *(float4*)p = make_float4(s[0], s[1], s[2], s[3]);
}

// round-to-nearest-even fp32 -> bf16 bits
DEV unsigned int bfh16(float v) {
  unsigned int u = __float_as_uint(v);
  return (u + 0x7FFFu + ((u >> 16) & 1u)) >> 16;
}
// split pair (a,b) -> packed hi-word / lo-word (2x bf16 each)
DEV uint2 splitpk(float a, float b) {
  unsigned int ha = bfh16(a), hb = bfh16(b);
  float la = a - __uint_as_float(ha << 16);
  float lb = b - __uint_as_float(hb << 16);
  return make_uint2(ha | (hb << 16), bfh16(la) | (bfh16(lb) << 16));
}

// T2 swizzle for plane buffers: within each 32-elem k-segment, 16B chunk
// c -> c ^ ((row>>1)&3).  Writers store swizzled; gemm_lds reads swizzled;
// global_load_lds stages linearly (rule #21).
DEV size_t swz_idx(int row, int col, int ld) {
  return (size_t)row * ld + (col & ~31) +
         ((((col >> 3) & 3) ^ ((row >> 1) & 3)) << 3) + (col & 7);
}

// async global->LDS, 16B per lane: LDS dest = base + lane*16 (HW)
DEV void gload_lds16(const void* g, void* l) {
  __builtin_amdgcn_global_load_lds(
      (const __attribute__((address_space(1))) unsigned int*)g,
      (__attribute__((address_space(3))) unsigned int*)l, 16, 0, 0);
}

// ---- rotation/decay tables (once per launch) -----------------------------
// floats: [0,16384) rotq (s*32+i)*2 = {cos*sc, sin*sc}
//         [16384,32768) rotk = {cos/sc, sin/sc}
//         [32768,34816) gq[h][s] = gamma_h^s
//         [34816,36864) gk[h][s] = gamma_h^-s
__global__ __launch_bounds__(256)
void tab_kernel(float* __restrict__ rtab) {
  const int idx = blockIdx.x * 256 + threadIdx.x;
  if (idx < 16384) {
    const int tk = idx >> 13;          // 0=q, 1=k
    const int e = idx & 8191;
    const int s = e >> 5, i = e & 31;
    const float sv = (2.0f * i + 25.6f) / 89.6f;
    const float sc = powf(sv, (float)s / 512.0f);
    const float invf = powf(10000.0f, -(float)i / 32.0f);
    const float ang = (float)s * invf;
    const float f = tk ? 1.0f / sc : sc;
    rtab[tk * 16384 + e * 2]     = cosf(ang) * f;
    rtab[tk * 16384 + e * 2 + 1] = sinf(ang) * f;
  } else if (idx < 20480) {
    const int e = idx - 16384;         // 0..4095
    const int tk = e >> 11;            // 0=gq, 1=gk
    const int he = e & 2047;
    const int h = he >> 8, s = he & 255;
    const float l32 = logf(1.0f / 32.0f), l512 = logf(1.0f / 512.0f);
    const float gamma = 1.0f - expf(l32 + (float)h * (l512 - l32) / 7.0f);
    const float g = powf(gamma, (float)s);
    rtab[32768 + e] = tk ? 1.0f / g : g;
  }
}

// ---- embed: src = [x,t] @ emb_W + emb_b  (fp32) --------------------------
__global__ __launch_bounds__(256)
void embed_kernel(const float* __restrict__ x, const float* __restrict__ t,
                  const float* __restrict__ W, const float* __restrict__ eb,
                  float* __restrict__ X) {
  const int gid = blockIdx.x * 256 + threadIdx.x;  // R*64
  const int row = gid >> 6, d = (gid & 63) * 8;
  const float xv = x[row], tv = t[row];
  #pragma unroll
  for (int j = 0; j < 8; j++)
    X[(size_t)row * 512 + d + j] =
        xv * W[d + j] + tv * W[512 + d + j] + eb[d + j];
}

// ---- layernorm row=512, fp32 -> split bf16 hi/lo planes (swizzled) -------
__global__ __launch_bounds__(256)
void ln_split(const float* __restrict__ X, const float* __restrict__ w,
              const float* __restrict__ bb, u16* __restrict__ hi,
              u16* __restrict__ lo) {
  const int row = blockIdx.x * 4 + (threadIdx.x >> 6);
  const int lane = threadIdx.x & 63;
  const float* xp = X + (size_t)row * 512 + lane * 8;
  float4 a0 = *(const float4*)xp;
  float4 a1 = *(const float4*)(xp + 4);
  float v[8] = {a0.x, a0.y, a0.z, a0.w, a1.x, a1.y, a1.z, a1.w};
  float s = 0.f, sq = 0.f;
  #pragma unroll
  for (int j = 0; j < 8; j++) { s += v[j]; sq += v[j] * v[j]; }
  s = wredf(s); sq = wredf(sq);
  const float mean = s * (1.f / 512.f);
  const float var = fmaxf(sq * (1.f / 512.f) - mean * mean, 0.f);
  const float inv = rsqrtf(var + 1e-5f);
  const float* wp = w + lane * 8;
  const float* bp = bb + lane * 8;
  float o[8];
  #pragma unroll
  for (int j = 0; j < 8; j++)
    o[j] = (v[j] - mean) * inv * wp[j] + bp[j];
  uint2 p0 = splitpk(o[0], o[1]), p1 = splitpk(o[2], o[3]);
  uint2 p2 = splitpk(o[4], o[5]), p3 = splitpk(o[6], o[7]);
  const size_t off = swz_idx(row, lane * 8, 512);
  *(int4*)(hi + off) = make_int4(p0.x, p1.x, p2.x, p3.x);
  *(int4*)(lo + off) = make_int4(p0.y, p1.y, p2.y, p3.y);
}

// ---- plain fp32 -> split planes (swizzled), no norm (head input) ---------
__global__ __launch_bounds__(256)
void split_kernel(const float* __restrict__ X, u16* __restrict__ hi,
                  u16* __restrict__ lo) {
  const int row = blockIdx.x * 4 + (threadIdx.x >> 6);
  const int lane = threadIdx.x & 63;
  const float* xp = X + (size_t)row * 512 + lane * 8;
  float v[8];
  ld4(v, xp); ld4(v + 4, xp + 4);
  uint2 p0 = splitpk(v[0], v[1]), p1 = splitpk(v[2], v[3]);
  uint2 p2 = splitpk(v[4], v[5]), p3 = splitpk(v[6], v[7]);
  const size_t off = swz_idx(row, lane * 8, 512);
  *(int4*)(hi + off) = make_int4(p0.x, p1.x, p2.x, p3.x);
  *(int4*)(lo + off) = make_int4(p0.y, p1.y, p2.y, p3.y);
}

// ---- tiled causal retention attention + groupnorm + gate -> GY planes ----
// QKVG row (3072): [Q(512) K(512) V(1024) G(1024)]; Q/K RAW — rotation and
// decay applied here during LDS staging via rtab lookups (cheap: 8x float2
// + 1 scalar per 16 elems). G pre-silu'd by the GEMM epilogue.
__global__ __launch_bounds__(256)
void attn_fused(const float* __restrict__ QKV, u16* __restrict__ GYh,
                u16* __restrict__ GYl, const float* __restrict__ gw,
                const float* __restrict__ gb, const float* __restrict__ rtab) {
  __shared__ float Qs[64][68];   // [e][s]
  __shared__ float Ks[64][68];   // [e][m]
  __shared__ float At[64][68];   // [m][s]
  const int h = blockIdx.y;
  const int r0 = blockIdx.x * 64;       // chunk-local first row
  const int b = r0 >> 8;
  const int s0 = r0 & 255;
  const int st = s0 >> 6;               // diagonal m-tile index
  const int tid = threadIdx.x;
  const int ty = tid >> 4, tx = tid & 15;
  const int rr = tid >> 2, e0 = (tid & 3) * 16;

  {  // stage Q transposed, rotated (*gamma^s * scale)
    const int s = (r0 + rr) & 255;
    const float gq = rtab[32768 + h * 256 + s];
    const float* qp = QKV + (size_t)(r0 + rr) * 3072 + h * 64 + e0;
    const float* rt = rtab + ((size_t)s * 32 + (e0 >> 1)) * 2;
    #pragma unroll
    for (int j = 0; j < 8; j++) {
      const float c = rt[2 * j] * gq, sn = rt[2 * j + 1] * gq;
      const float v0 = qp[2 * j], v1 = qp[2 * j + 1];
      Qs[e0 + 2 * j][rr]     = v0 * c - v1 * sn;
      Qs[e0 + 2 * j + 1][rr] = v1 * c + v0 * sn;
    }
  }

  float acc2[4][8];
  #pragma unroll
  for (int i = 0; i < 4; i++)
    #pragma unroll
    for (int j = 0; j < 8; j++) acc2[i][j] = 0.f;

  for (int mt = 0; mt <= st; mt++) {
    const int m0 = mt * 64;
    {  // stage K tile transposed, rotated (/gamma^m / scale)
      const int m = m0 + rr;
      const float gk = rtab[34816 + h * 256 + m];
      const float* kp = QKV + (size_t)(b * 256 + m) * 3072 + 512 + h * 64 + e0;
      const float* rt = rtab + 16384 + ((size_t)m * 32 + (e0 >> 1)) * 2;
      #pragma unroll
      for (int j = 0; j < 8; j++) {
        const float c = rt[2 * j] * gk, sn = rt[2 * j + 1] * gk;
        const float v0 = kp[2 * j], v1 = kp[2 * j + 1];
        Ks[e0 + 2 * j][rr]     = v0 * c - v1 * sn;
        Ks[e0 + 2 * j + 1][rr] = v1 * c + v0 * sn;
      }
    }
    __syncthreads();
    float a1[4][4];
    #pragma unroll
    for (int i = 0; i < 4; i++)
      #pragma unroll
      for (int j = 0; j < 4; j++) a1[i][j] = 0.f;
    #pragma unroll 4
    for (int e = 0; e < 64; e++) {
      float qa[4], kb[4];
      ld4(qa, &Qs[e][ty * 4]);
      ld4(kb, &Ks[e][tx * 4]);
      #pragma unroll
      for (int i = 0; i < 4; i++)
        #pragma unroll
        for (int j = 0; j < 4; j++)
          a1[i][j] = fmaf(qa[i], kb[j], a1[i][j]);
    }
    #pragma unroll
    for (int i = 0; i < 4; i++)
      #pragma unroll
      for (int j = 0; j < 4; j++) {
        float v = a1[i][j];
        if (mt == st && (m0 + tx * 4 + j) > (s0 + ty * 4 + i)) v = 0.f;
        At[tx * 4 + j][ty * 4 + i] = v;
      }
    __syncthreads();
    const float* vp = QKV + (size_t)(b * 256 + m0) * 3072 + 1024 + h * 128 + tx * 8;
    #pragma unroll 4
    for (int m = 0; m < 64; m++) {
      float av[4], vv[8];
      ld4(av, &At[m][ty * 4]);
      ld4(vv, vp);
      ld4(vv + 4, vp + 4);
      vp += 3072;
      #pragma unroll
      for (int i = 0; i < 4; i++)
        #pragma unroll
        for (int j = 0; j < 8; j++)
          acc2[i][j] = fmaf(av[i], vv[j], acc2[i][j]);
    }
    __syncthreads();
  }

  // epilogue: groupnorm (16-lane tx reduce) + affine + gate + split planes
  const int vi = h * 128 + tx * 8;
  float gwv[8], gbv[8];
  ld4(gwv, gw + vi); ld4(gwv + 4, gw + vi + 4);
  ld4(gbv, gb + vi); ld4(gbv + 4, gb + vi + 4);
  #pragma unroll
  for (int i = 0; i < 4; i++) {
    const int row = r0 + ty * 4 + i;
    float s = 0.f, sq = 0.f;
    #pragma unroll
    for (int j = 0; j < 8; j++) { s += acc2[i][j]; sq += acc2[i][j] * acc2[i][j]; }
    #pragma unroll
    for (int msk = 1; msk <= 8; msk <<= 1) {
      s += __shfl_xor(s, msk, 64);
      sq += __shfl_xor(sq, msk, 64);
    }
    const float mean = s * (1.f / 128.f);
    const float var = fmaxf(sq * (1.f / 128.f) - mean * mean, 0.f);
    const float inv = rsqrtf(var + 1e-5f);
    const float* gp = QKV + (size_t)row * 3072 + 2048 + vi;
    float gs[8];
    ld4(gs, gp); ld4(gs + 4, gp + 4);
    float o[8];
    #pragma unroll
    for (int j = 0; j < 8; j++)
      o[j] = ((acc2[i][j] - mean) * inv * gwv[j] + gbv[j]) * gs[j];
    uint2 p0 = splitpk(o[0], o[1]), p1 = splitpk(o[2], o[3]);
    uint2 p2 = splitpk(o[4], o[5]), p3 = splitpk(o[6], o[7]);
    const size_t off = swz_idx(row, vi, 1024);
    *(int4*)(GYh + off) = make_int4(p0.x, p1.x, p2.x, p3.x);
    *(int4*)(GYl + off) = make_int4(p0.y, p1.y, p2.y, p3.y);
  }
}

// ---- final N=1 dot (fp32) ------------------------------------------------
__global__ __launch_bounds__(256)
void head3_kernel(const float* __restrict__ X, const float* __restrict__ w,
                  const float* __restrict__ b3, float* __restrict__ out) {
  const int row = blockIdx.x * 4 + (threadIdx.x >> 6);
  const int lane = threadIdx.x & 63;
  const float* xp = X + (size_t)row * 512 + lane * 8;
  const float* wp = w + lane * 8;
  float s = 0.f;
  #pragma unroll
  for (int j = 0; j < 8; j++) s += xp[j] * wp[j];
  s = wredf(s);
  if (lane == 0) out[row] = s + b3[0];
}

// ---- weight pre-pack: W[K][N] -> swizzled Bt_hi/Bt_lo [N][K] bf16 --------
__global__ __launch_bounds__(256)
void pack_plain(const float* __restrict__ W, u16* __restrict__ hi,
                u16* __restrict__ lo, int N, int kshift) {
  const int idx = blockIdx.x * 256 + threadIdx.x;   // n*K + k (logical)
  const int K = 1 << kshift;
  const int n = idx >> kshift, k = idx & (K - 1);
  const float v = W[(size_t)k * N + n];
  const unsigned int h = bfh16(v);
  const float l = v - __uint_as_float(h << 16);
  const size_t o = swz_idx(n, k, K);
  hi[o] = (u16)h;
  lo[o] = (u16)bfh16(l);
}

// QKVG mapping: c<512 WQ(h,k,e); <1024 WK; <2048 WV(h,k,v); else WG[k][c-2048]
__global__ __launch_bounds__(256)
void pack_qkvg(const float* __restrict__ WQ, const float* __restrict__ WK,
               const float* __restrict__ WV, const float* __restrict__ WG,
               u16* __restrict__ hi, u16* __restrict__ lo) {
  const int idx = blockIdx.x * 256 + threadIdx.x;   // c*512 + k (logical)
  const int c = idx >> 9, k = idx & 511;
  float v;
  if (c < 512)
    v = WQ[((size_t)(c >> 6) * 512 + k) * 64 + (c & 63)];
  else if (c < 1024)
    v = WK[((size_t)((c - 512) >> 6) * 512 + k) * 64 + ((c - 512) & 63)];
  else if (c < 2048)
    v = WV[((size_t)((c - 1024) >> 7) * 512 + k) * 128 + ((c - 1024) & 127)];
  else
    v = WG[(size_t)k * 1024 + (c - 2048)];
  const unsigned int h = bfh16(v);
  const float l = v - __uint_as_float(h << 16);
  const size_t o = swz_idx(c, k, 512);
  hi[o] = (u16)h;
  lo[o] = (u16)bfh16(l);
}

// ---- bf16x3 MFMA GEMM, dbuf gload_lds + counted vmcnt + XCD swizzle ------
// (R7 structure.)  K-step t: issue stage(t+1) -> s_waitcnt vmcnt(8) ->
// s_barrier -> setprio(1) frag reads + 48 MFMA setprio(0) -> s_barrier.
// EPI 0: store    2: acc+aux   3: gelu(acc+bias)   4: acc+bias+aux
//     5: w0*sin(acc+b)+w1*cos(acc+b)
//     6: QKVG: col<2048 pass (raw Q/K/V); >=2048 silu (gate)
// OSPLIT 0: fp32 C.  1: swizzled split bf16 planes Ch/Cl.
template<int EPI, int OSPLIT>
__global__ __launch_bounds__(256, 2)
void gemm_lds(const u16* __restrict__ Agh, const u16* __restrict__ Agl,
              const u16* __restrict__ Bh, const u16* __restrict__ Bl,
              float* __restrict__ C, u16* __restrict__ Ch, u16* __restrict__ Cl,
              const int N, const int K,
              const float* __restrict__ bias, const float* __restrict__ aux,
              const float* __restrict__ wave2) {
  __shared__ __align__(16) u16 S[2][4][128][32];   // dbuf x {Ah,Al,Bh,Bl}
  const int tid = threadIdx.x;
  const int lane = tid & 63;
  const int wave = tid >> 6;
  const int wr = (wave >> 1) * 64, wc = (wave & 1) * 64;

  // XCD-chunked bijective remap, n-major logical order (T1)
  int bx = blockIdx.x, by = blockIdx.y;
  {
    const int gx = gridDim.x, gy = gridDim.y;
    const int nwg = gx * gy;
    if ((nwg & 7) == 0) {
      const int id = by * gx + bx;          // dispatch order (x fastest)
      const int q = nwg >> 3;
      const int L = (id & 7) * q + (id >> 3);
      bx = L / gy;                          // n-panel (contiguous per XCD)
      by = L - bx * gy;                     // m-panel
    }
  }
  const int m0 = by * 128, n0 = bx * 128;

  const int fm = lane & 15;
  const int q = lane >> 4;            // logical 16B chunk 0..3

  const u16* pb;
  if (wave == 0)      pb = Agh + (size_t)m0 * K;
  else if (wave == 1) pb = Agl + (size_t)m0 * K;
  else if (wave == 2) pb = Bh + (size_t)n0 * K;
  else                pb = Bl + (size_t)n0 * K;
  const u16* src0 = pb + (size_t)(lane >> 2) * K + (lane & 3) * 8;

  f32x4 acc[4][4];
  #pragma unroll
  for (int i = 0; i < 4; i++)
    #pragma unroll
    for (int j = 0; j < 4; j++)
      acc[i][j] = (f32x4){0.f, 0.f, 0.f, 0.f};

  {  // prologue: stage tile 0 into buf 0 (full drain via __syncthreads)
    u16* dst = &S[0][wave][0][0];
    #pragma unroll
    for (int i = 0; i < 8; i++)
      gload_lds16(src0 + (size_t)(i * 16) * K, dst + i * 512);
  }
  __syncthreads();

  for (int kt = 0; kt < K; kt += 32) {
    const int cur = (kt >> 5) & 1;
    if (kt + 32 < K) {  // issue next tile; keep its 8 loads in flight
      u16* dst = &S[cur ^ 1][wave][0][0];
      const u16* s = src0 + kt + 32;
      #pragma unroll
      for (int i = 0; i < 8; i++)
        gload_lds16(s + (size_t)(i * 16) * K, dst + i * 512);
      asm volatile("s_waitcnt vmcnt(8)" ::: "memory");
    } else {
      asm volatile("s_waitcnt vmcnt(0)" ::: "memory");
    }
    __builtin_amdgcn_sched_barrier(0);
    __builtin_amdgcn_s_barrier();
    __builtin_amdgcn_sched_barrier(0);
    __builtin_amdgcn_s_setprio(1);

    bf16x8 avh[4], avl[4];
    #pragma unroll
    for (int mf = 0; mf < 4; mf++) {
      const int m = wr + mf * 16 + fm;
      const int c = (q ^ ((m >> 1) & 3)) * 8;   // swizzled read
      avh[mf] = *(const bf16x8*)&S[cur][0][m][c];
      avl[mf] = *(const bf16x8*)&S[cur][1][m][c];
    }
    #pragma unroll
    for (int nf = 0; nf < 4; nf++) {
      const int n = wc + nf * 16 + fm;
      const int c = (q ^ ((n >> 1) & 3)) * 8;
      bf16x8 bh = *(const bf16x8*)&S[cur][2][n][c];
      bf16x8 bl = *(const bf16x8*)&S[cur][3][n][c];
      #pragma unroll
      for (int mf = 0; mf < 4; mf++) {
        acc[mf][nf] = __builtin_amdgcn_mfma_f32_16x16x32_bf16(avh[mf], bh, acc[mf][nf], 0, 0, 0);
        acc[mf][nf] = __builtin_amdgcn_mfma_f32_16x16x32_bf16(avl[mf], bh, acc[mf][nf], 0, 0, 0);
        acc[mf][nf] = __builtin_amdgcn_mfma_f32_16x16x32_bf16(avh[mf], bl, acc[mf][nf], 0, 0, 0);
      }
    }
    __builtin_amdgcn_s_setprio(0);
    __builtin_amdgcn_sched_barrier(0);
    __builtin_amdgcn_s_barrier();
  }

  // epilogue: D frag: col = lane&15, row = (lane>>4)*4 + r
  const int r0 = m0 + wr + (lane >> 4) * 4;
  const int c0 = n0 + wc + fm;
  #pragma unroll
  for (int mf = 0; mf < 4; mf++) {
    #pragma unroll
    for (int nf = 0; nf < 4; nf++) {
      const int col = c0 + nf * 16;
      #pragma unroll
      for (int r = 0; r < 4; r++) {
        const int row = r0 + mf * 16 + r;
        const size_t idx = (size_t)row * N + col;   // logical (C, aux)
        float v = acc[mf][nf][r];
        float o;
        if constexpr (EPI == 0) {
          o = v;
        } else if constexpr (EPI == 2) {
          o = v + aux[idx];
        } else if constexpr (EPI == 3) {
          v += bias[col];
          o = 0.5f * v * (1.f + erff(v * 0.70710678118654752f));
        } else if constexpr (EPI == 4) {
          o = v + bias[col] + aux[idx];
        } else if constexpr (EPI == 5) {
          v += bias[col];
          o = wave2[0] * sinf(v) + wave2[1] * cosf(v);
        } else {
          // EPI 6: raw Q/K/V pass; silu for gate cols (wave-uniform per nf)
          if (col < 2048) o = v;
          else            o = v / (1.f + expf(-v));
        }
        if constexpr (OSPLIT == 0) {
          C[idx] = o;
        } else {
          const size_t sidx = swz_idx(row, col, N);
          const unsigned int hb = bfh16(o);
          Ch[sidx] = (u16)hb;
          Cl[sidx] = (u16)bfh16(o - __uint_as_float(hb << 16));
        }
      }
    }
  }
}

// ---- launch --------------------------------------------------------------

extern "C" void kernel_launch(void* const* d_in, const int* in_sizes, int n_in,
                              void* d_out, int out_size, void* d_ws, size_t ws_size,
                              hipStream_t stream) {
  (void)in_sizes; (void)n_in; (void)out_size;
  const float* x    = (const float*)d_in[0];
  const float* t    = (const float*)d_in[1];
  const float* embW = (const float*)d_in[2];
  const float* embB = (const float*)d_in[3];
  const float* ln1w = (const float*)d_in[4];
  const float* ln1b = (const float*)d_in[5];
  const float* ln2w = (const float*)d_in[6];
  const float* ln2b = (const float*)d_in[7];
  const float* WQ   = (const float*)d_in[8];
  const float* WK   = (const float*)d_in[9];
  const float* WV   = (const float*)d_in[10];
  const float* WG   = (const float*)d_in[11];
  const float* WO   = (const float*)d_in[12];
  const float* gnw  = (const float*)d_in[13];
  const float* gnb  = (const float*)d_in[14];
  const float* f1W  = (const float*)d_in[15];
  const float* f1b  = (const float*)d_in[16];
  const float* f2W  = (const float*)d_in[17];
  const float* f2bp = (const float*)d_in[18];
  const float* h1W  = (const float*)d_in[19];
  const float* h1b  = (const float*)d_in[20];
  const float* wvw  = (const float*)d_in[21];
  const float* h2W  = (const float*)d_in[22];
  const float* h2b  = (const float*)d_in[23];
  const float* h3W  = (const float*)d_in[24];
  const float* h3b  = (const float*)d_in[25];

  // ---- packed-weight area (bf16 hi/lo, swizzled [N][K]) ----
  u16* P = (u16*)d_ws;
  const size_t SQKVG = 3072 * 512, SWO = 512 * 1024;
  const size_t SF1 = 128 * 512, SF2 = 512 * 128;
  const size_t PERL = 2 * (SQKVG + SWO + SF1 + SF2);
  const size_t HOFF = 4 * PERL;                 // heads after layers
  const size_t PACK_BYTES = (HOFF + 4 * 512 * 512) * 2;  // = 37748736
  const size_t TAB_BYTES = 36864 * 4;           // rotation/decay tables

  u16* h1h = P + HOFF;
  u16* h1l = h1h + 512 * 512;
  u16* h2h = h1l + 512 * 512;
  u16* h2l = h2h + 512 * 512;
  float* RT = (float*)((char*)d_ws + PACK_BYTES);

  const dim3 blk(256);

  // tables + pack all weights once
  tab_kernel<<<dim3(80), blk, 0, stream>>>(RT);
  for (int l = 0; l < 4; l++) {
    u16* qkvh = P + l * PERL;
    u16* qkvl = qkvh + SQKVG;
    u16* woh  = qkvl + SQKVG;
    u16* wol  = woh + SWO;
    u16* f1h  = wol + SWO;
    u16* f1l  = f1h + SF1;
    u16* f2h  = f1l + SF1;
    u16* f2l  = f2h + SF2;
    pack_qkvg<<<dim3(SQKVG / 256), blk, 0, stream>>>(
        WQ + (size_t)l * 262144, WK + (size_t)l * 262144,
        WV + (size_t)l * 524288, WG + (size_t)l * 524288, qkvh, qkvl);
    pack_plain<<<dim3(SWO / 256), blk, 0, stream>>>(WO + (size_t)l * 524288, woh, wol, 512, 10);
    pack_plain<<<dim3(SF1 / 256), blk, 0, stream>>>(f1W + (size_t)l * 65536, f1h, f1l, 128, 9);
    pack_plain<<<dim3(SF2 / 256), blk, 0, stream>>>(f2W + (size_t)l * 65536, f2h, f2l, 512, 7);
  }
  pack_plain<<<dim3(1024), blk, 0, stream>>>(h1W, h1h, h1l, 512, 9);
  pack_plain<<<dim3(1024), blk, 0, stream>>>(h2W, h2h, h2l, 512, 9);

  // ---- batch-chunking so fp32 activations fit after pack+tables ----
  // per-row floats: Xf 512 + Xn 512 + QKVG 3072 + GY 1024 + Yr 512 = 5632
  const size_t BASE = PACK_BYTES + TAB_BYTES;
  int NC = 1;
  while (NC < 256) {
    const size_t R = 65536u / NC;
    if (BASE + R * 22528 + 4096 <= ws_size) break;
    NC <<= 1;
  }
  const int R = 65536 / NC;   // rows per chunk (multiple of 256)

  float* Xf   = (float*)((char*)d_ws + BASE);  // R x 512 residual
  float* Xn   = Xf  + (size_t)R * 512;   // R x 512   LN planes
  float* QKVG = Xn  + (size_t)R * 512;   // R x 3072  QKVG fp32
  float* GYb  = QKVG + (size_t)R * 3072; // R x 1024  GY planes / mid / H1
  float* Yr   = GYb + (size_t)R * 1024;  // R x 512   Yr residual / H2 fp32

  u16* Xnh = (u16*)Xn;           u16* Xnl = Xnh + (size_t)R * 512;
  u16* GYh = (u16*)GYb;          u16* GYl = GYh + (size_t)R * 1024;
  u16* midh = (u16*)GYb;         u16* midl = midh + (size_t)R * 128;
  u16* H1h = (u16*)GYb;          u16* H1l = H1h + (size_t)R * 512;

  for (int c = 0; c < NC; c++) {
    const size_t off = (size_t)c * R;
    embed_kernel<<<dim3(R / 4), blk, 0, stream>>>(x + off, t + off, embW, embB, Xf);

    for (int l = 0; l < 4; l++) {
      u16* qkvh = P + l * PERL;
      u16* qkvl = qkvh + SQKVG;
      u16* woh  = qkvl + SQKVG;
      u16* wol  = woh + SWO;
      u16* f1h  = wol + SWO;
      u16* f1l  = f1h + SF1;
      u16* f2h  = f1l + SF1;
      u16* f2l  = f2h + SF2;

      ln_split<<<dim3(R / 4), blk, 0, stream>>>(Xf, ln1w + l * 512, ln1b + l * 512, Xnh, Xnl);
      // [Q|K|V|G] = Xn @ [WQ|WK|WV|WG][l]; silu on gate cols in epilogue
      gemm_lds<6, 0><<<dim3(24, R / 128), blk, 0, stream>>>(
          Xnh, Xnl, qkvh, qkvl, QKVG, nullptr, nullptr,
          3072, 512, nullptr, nullptr, nullptr);
      // retention attention (rotation at staging) + groupnorm + gate
      attn_fused<<<dim3(R / 64, 8), blk, 0, stream>>>(
          QKVG, GYh, GYl, gnw + l * 1024, gnb + l * 1024, RT);
      // Yr = GY @ WO[l] + X
      gemm_lds<2, 0><<<dim3(4, R / 128), blk, 0, stream>>>(
          GYh, GYl, woh, wol, Yr, nullptr, nullptr,
          512, 1024, nullptr, Xf, nullptr);
      ln_split<<<dim3(R / 4), blk, 0, stream>>>(Yr, ln2w + l * 512, ln2b + l * 512, Xnh, Xnl);
      // mid = gelu(Xn @ f1[l] + b1)  -> split planes (GY slot dead)
      gemm_lds<3, 1><<<dim3(1, R / 128), blk, 0, stream>>>(
          Xnh, Xnl, f1h, f1l, nullptr, midh, midl,
          128, 512, f1b + l * 128, nullptr, nullptr);
      // X = mid @ f2[l] + b2 + Yr
      gemm_lds<4, 0><<<dim3(4, R / 128), blk, 0, stream>>>(
          midh, midl, f2h, f2l, Xf, nullptr, nullptr,
          512, 128, f2bp + l * 512, Yr, nullptr);
    }

    // head: split Xf once, then gemm_lds all the way
    split_kernel<<<dim3(R / 4), blk, 0, stream>>>(Xf, Xnh, Xnl);
    gemm_lds<5, 1><<<dim3(4, R / 128), blk, 0, stream>>>(
        Xnh, Xnl, h1h, h1l, nullptr, H1h, H1l,
        512, 512, h1b, nullptr, wvw);
    gemm_lds<5, 0><<<dim3(4, R / 128), blk, 0, stream>>>(
        H1h, H1l, h2h, h2l, Yr, nullptr, nullptr,
        512, 512, h2b, nullptr, wvw + 2);
    head3_kernel<<<dim3(R / 4), blk, 0, stream>>>(
        Yr, h3W, h3b, (float*)d_out + off);
  }
}

// Round 11
// 10022.562 us; speedup vs baseline: 1.2170x; 1.0078x over previous
//
#include <hip/hip_runtime.h>
#include <cstdint>
#include <cstddef>

#define DEV static __device__ __forceinline__

typedef short bf16x8 __attribute__((ext_vector_type(8)));
typedef float f32x4 __attribute__((ext_vector_type(4)));
typedef unsigned short u16;

DEV float wredf(float v) {
  v += __shfl_xor(v, 32, 64); v += __shfl_xor(v, 16, 64);
  v += __shfl_xor(v, 8, 64);  v += __shfl_xor(v, 4, 64);
  v += __shfl_xor(v, 2, 64);  v += __shfl_xor(v, 1, 64);
  return v;
}

DEV void ld4(float* d, const float* p) {
  float4 t = *(const float4*)p;
  d[0] = t.x; d[1] = t.y; d[2] = t.z; d[3] = t.w;
}
DEV void st4(float* p, const float* s) {
  *(float4*)p = make_float4(s[0], s[1], s[2], s[3]);
}

// round-to-nearest-even fp32 -> bf16 bits
DEV unsigned int bfh16(float v) {
  unsigned int u = __float_as_uint(v);
  return (u + 0x7FFFu + ((u >> 16) & 1u)) >> 16;
}
// split pair (a,b) -> packed hi-word / lo-word (2x bf16 each)
DEV uint2 splitpk(float a, float b) {
  unsigned int ha = bfh16(a), hb = bfh16(b);
  float la = a - __uint_as_float(ha << 16);
  float lb = b - __uint_as_float(hb << 16);
  return make_uint2(ha | (hb << 16), bfh16(la) | (bfh16(lb) << 16));
}

// T2 swizzle for plane buffers: within each 32-elem k-segment, 16B chunk
// c -> c ^ ((row>>1)&3).  Writers store swizzled; gemm_lds reads swizzled;
// global_load_lds stages linearly (rule #21).
DEV size_t swz_idx(int row, int col, int ld) {
  return (size_t)row * ld + (col & ~31) +
         ((((col >> 3) & 3) ^ ((row >> 1) & 3)) << 3) + (col & 7);
}

// async global->LDS, 16B per lane: LDS dest = base + lane*16 (HW)
DEV void gload_lds16(const void* g, void* l) {
  __builtin_amdgcn_global_load_lds(
      (const __attribute__((address_space(1))) unsigned int*)g,
      (__attribute__((address_space(3))) unsigned int*)l, 16, 0, 0);
}

// ---- rotation/decay tables (once per launch) -----------------------------
// floats: [0,16384) rotq (s*32+i)*2 = {cos*sc, sin*sc}
//         [16384,32768) rotk = {cos/sc, sin/sc}
//         [32768,34816) gq[h][s] = gamma_h^s
//         [34816,36864) gk[h][s] = gamma_h^-s
__global__ __launch_bounds__(256)
void tab_kernel(float* __restrict__ rtab) {
  const int idx = blockIdx.x * 256 + threadIdx.x;
  if (idx < 16384) {
    const int tk = idx >> 13;          // 0=q, 1=k
    const int e = idx & 8191;
    const int s = e >> 5, i = e & 31;
    const float sv = (2.0f * i + 25.6f) / 89.6f;
    const float sc = powf(sv, (float)s / 512.0f);
    const float invf = powf(10000.0f, -(float)i / 32.0f);
    const float ang = (float)s * invf;
    const float f = tk ? 1.0f / sc : sc;
    rtab[tk * 16384 + e * 2]     = cosf(ang) * f;
    rtab[tk * 16384 + e * 2 + 1] = sinf(ang) * f;
  } else if (idx < 20480) {
    const int e = idx - 16384;         // 0..4095
    const int tk = e >> 11;            // 0=gq, 1=gk
    const int he = e & 2047;
    const int h = he >> 8, s = he & 255;
    const float l32 = logf(1.0f / 32.0f), l512 = logf(1.0f / 512.0f);
    const float gamma = 1.0f - expf(l32 + (float)h * (l512 - l32) / 7.0f);
    const float g = powf(gamma, (float)s);
    rtab[32768 + e] = tk ? 1.0f / g : g;
  }
}

// ---- embed: src = [x,t] @ emb_W + emb_b  (fp32) --------------------------
__global__ __launch_bounds__(256)
void embed_kernel(const float* __restrict__ x, const float* __restrict__ t,
                  const float* __restrict__ W, const float* __restrict__ eb,
                  float* __restrict__ X) {
  const int gid = blockIdx.x * 256 + threadIdx.x;  // R*64
  const int row = gid >> 6, d = (gid & 63) * 8;
  const float xv = x[row], tv = t[row];
  #pragma unroll
  for (int j = 0; j < 8; j++)
    X[(size_t)row * 512 + d + j] =
        xv * W[d + j] + tv * W[512 + d + j] + eb[d + j];
}

// ---- layernorm row=512, fp32 -> split bf16 hi/lo planes (swizzled) -------
__global__ __launch_bounds__(256)
void ln_split(const float* __restrict__ X, const float* __restrict__ w,
              const float* __restrict__ bb, u16* __restrict__ hi,
              u16* __restrict__ lo) {
  const int row = blockIdx.x * 4 + (threadIdx.x >> 6);
  const int lane = threadIdx.x & 63;
  const float* xp = X + (size_t)row * 512 + lane * 8;
  float4 a0 = *(const float4*)xp;
  float4 a1 = *(const float4*)(xp + 4);
  float v[8] = {a0.x, a0.y, a0.z, a0.w, a1.x, a1.y, a1.z, a1.w};
  float s = 0.f, sq = 0.f;
  #pragma unroll
  for (int j = 0; j < 8; j++) { s += v[j]; sq += v[j] * v[j]; }
  s = wredf(s); sq = wredf(sq);
  const float mean = s * (1.f / 512.f);
  const float var = fmaxf(sq * (1.f / 512.f) - mean * mean, 0.f);
  const float inv = rsqrtf(var + 1e-5f);
  const float* wp = w + lane * 8;
  const float* bp = bb + lane * 8;
  float o[8];
  #pragma unroll
  for (int j = 0; j < 8; j++)
    o[j] = (v[j] - mean) * inv * wp[j] + bp[j];
  uint2 p0 = splitpk(o[0], o[1]), p1 = splitpk(o[2], o[3]);
  uint2 p2 = splitpk(o[4], o[5]), p3 = splitpk(o[6], o[7]);
  const size_t off = swz_idx(row, lane * 8, 512);
  *(int4*)(hi + off) = make_int4(p0.x, p1.x, p2.x, p3.x);
  *(int4*)(lo + off) = make_int4(p0.y, p1.y, p2.y, p3.y);
}

// ---- plain fp32 -> split planes (swizzled), no norm (head input) ---------
__global__ __launch_bounds__(256)
void split_kernel(const float* __restrict__ X, u16* __restrict__ hi,
                  u16* __restrict__ lo) {
  const int row = blockIdx.x * 4 + (threadIdx.x >> 6);
  const int lane = threadIdx.x & 63;
  const float* xp = X + (size_t)row * 512 + lane * 8;
  float v[8];
  ld4(v, xp); ld4(v + 4, xp + 4);
  uint2 p0 = splitpk(v[0], v[1]), p1 = splitpk(v[2], v[3]);
  uint2 p2 = splitpk(v[4], v[5]), p3 = splitpk(v[6], v[7]);
  const size_t off = swz_idx(row, lane * 8, 512);
  *(int4*)(hi + off) = make_int4(p0.x, p1.x, p2.x, p3.x);
  *(int4*)(lo + off) = make_int4(p0.y, p1.y, p2.y, p3.y);
}

// ---- tiled causal retention attention + groupnorm + gate -> GY planes ----
// QKVG row (3072): [Q(512) K(512) V(1024) G(1024)]; Q/K RAW — rotation and
// decay applied here during LDS staging via rtab lookups (cheap: 8x float2
// + 1 scalar per 16 elems). G pre-silu'd by the GEMM epilogue.
__global__ __launch_bounds__(256)
void attn_fused(const float* __restrict__ QKV, u16* __restrict__ GYh,
                u16* __restrict__ GYl, const float* __restrict__ gw,
                const float* __restrict__ gb, const float* __restrict__ rtab) {
  __shared__ float Qs[64][68];   // [e][s]
  __shared__ float Ks[64][68];   // [e][m]
  __shared__ float At[64][68];   // [m][s]
  const int h = blockIdx.y;
  const int r0 = blockIdx.x * 64;       // chunk-local first row
  const int b = r0 >> 8;
  const int s0 = r0 & 255;
  const int st = s0 >> 6;               // diagonal m-tile index
  const int tid = threadIdx.x;
  const int ty = tid >> 4, tx = tid & 15;
  const int rr = tid >> 2, e0 = (tid & 3) * 16;

  {  // stage Q transposed, rotated (*gamma^s * scale)
    const int s = (r0 + rr) & 255;
    const float gq = rtab[32768 + h * 256 + s];
    const float* qp = QKV + (size_t)(r0 + rr) * 3072 + h * 64 + e0;
    const float* rt = rtab + ((size_t)s * 32 + (e0 >> 1)) * 2;
    #pragma unroll
    for (int j = 0; j < 8; j++) {
      const float c = rt[2 * j] * gq, sn = rt[2 * j + 1] * gq;
      const float v0 = qp[2 * j], v1 = qp[2 * j + 1];
      Qs[e0 + 2 * j][rr]     = v0 * c - v1 * sn;
      Qs[e0 + 2 * j + 1][rr] = v1 * c + v0 * sn;
    }
  }

  float acc2[4][8];
  #pragma unroll
  for (int i = 0; i < 4; i++)
    #pragma unroll
    for (int j = 0; j < 8; j++) acc2[i][j] = 0.f;

  for (int mt = 0; mt <= st; mt++) {
    const int m0 = mt * 64;
    {  // stage K tile transposed, rotated (/gamma^m / scale)
      const int m = m0 + rr;
      const float gk = rtab[34816 + h * 256 + m];
      const float* kp = QKV + (size_t)(b * 256 + m) * 3072 + 512 + h * 64 + e0;
      const float* rt = rtab + 16384 + ((size_t)m * 32 + (e0 >> 1)) * 2;
      #pragma unroll
      for (int j = 0; j < 8; j++) {
        const float c = rt[2 * j] * gk, sn = rt[2 * j + 1] * gk;
        const float v0 = kp[2 * j], v1 = kp[2 * j + 1];
        Ks[e0 + 2 * j][rr]     = v0 * c - v1 * sn;
        Ks[e0 + 2 * j + 1][rr] = v1 * c + v0 * sn;
      }
    }
    __syncthreads();
    float a1[4][4];
    #pragma unroll
    for (int i = 0; i < 4; i++)
      #pragma unroll
      for (int j = 0; j < 4; j++) a1[i][j] = 0.f;
    #pragma unroll 4
    for (int e = 0; e < 64; e++) {
      float qa[4], kb[4];
      ld4(qa, &Qs[e][ty * 4]);
      ld4(kb, &Ks[e][tx * 4]);
      #pragma unroll
      for (int i = 0; i < 4; i++)
        #pragma unroll
        for (int j = 0; j < 4; j++)
          a1[i][j] = fmaf(qa[i], kb[j], a1[i][j]);
    }
    #pragma unroll
    for (int i = 0; i < 4; i++)
      #pragma unroll
      for (int j = 0; j < 4; j++) {
        float v = a1[i][j];
        if (mt == st && (m0 + tx * 4 + j) > (s0 + ty * 4 + i)) v = 0.f;
        At[tx * 4 + j][ty * 4 + i] = v;
      }
    __syncthreads();
    const float* vp = QKV + (size_t)(b * 256 + m0) * 3072 + 1024 + h * 128 + tx * 8;
    #pragma unroll 4
    for (int m = 0; m < 64; m++) {
      float av[4], vv[8];
      ld4(av, &At[m][ty * 4]);
      ld4(vv, vp);
      ld4(vv + 4, vp + 4);
      vp += 3072;
      #pragma unroll
      for (int i = 0; i < 4; i++)
        #pragma unroll
        for (int j = 0; j < 8; j++)
          acc2[i][j] = fmaf(av[i], vv[j], acc2[i][j]);
    }
    __syncthreads();
  }

  // epilogue: groupnorm (16-lane tx reduce) + affine + gate + split planes
  const int vi = h * 128 + tx * 8;
  float gwv[8], gbv[8];
  ld4(gwv, gw + vi); ld4(gwv + 4, gw + vi + 4);
  ld4(gbv, gb + vi); ld4(gbv + 4, gb + vi + 4);
  #pragma unroll
  for (int i = 0; i < 4; i++) {
    const int row = r0 + ty * 4 + i;
    float s = 0.f, sq = 0.f;
    #pragma unroll
    for (int j = 0; j < 8; j++) { s += acc2[i][j]; sq += acc2[i][j] * acc2[i][j]; }
    #pragma unroll
    for (int msk = 1; msk <= 8; msk <<= 1) {
      s += __shfl_xor(s, msk, 64);
      sq += __shfl_xor(sq, msk, 64);
    }
    const float mean = s * (1.f / 128.f);
    const float var = fmaxf(sq * (1.f / 128.f) - mean * mean, 0.f);
    const float inv = rsqrtf(var + 1e-5f);
    const float* gp = QKV + (size_t)row * 3072 + 2048 + vi;
    float gs[8];
    ld4(gs, gp); ld4(gs + 4, gp + 4);
    float o[8];
    #pragma unroll
    for (int j = 0; j < 8; j++)
      o[j] = ((acc2[i][j] - mean) * inv * gwv[j] + gbv[j]) * gs[j];
    uint2 p0 = splitpk(o[0], o[1]), p1 = splitpk(o[2], o[3]);
    uint2 p2 = splitpk(o[4], o[5]), p3 = splitpk(o[6], o[7]);
    const size_t off = swz_idx(row, vi, 1024);
    *(int4*)(GYh + off) = make_int4(p0.x, p1.x, p2.x, p3.x);
    *(int4*)(GYl + off) = make_int4(p0.y, p1.y, p2.y, p3.y);
  }
}

// ---- final N=1 dot (fp32) ------------------------------------------------
__global__ __launch_bounds__(256)
void head3_kernel(const float* __restrict__ X, const float* __restrict__ w,
                  const float* __restrict__ b3, float* __restrict__ out) {
  const int row = blockIdx.x * 4 + (threadIdx.x >> 6);
  const int lane = threadIdx.x & 63;
  const float* xp = X + (size_t)row * 512 + lane * 8;
  const float* wp = w + lane * 8;
  float s = 0.f;
  #pragma unroll
  for (int j = 0; j < 8; j++) s += xp[j] * wp[j];
  s = wredf(s);
  if (lane == 0) out[row] = s + b3[0];
}

// ---- weight pre-pack: W[K][N] -> swizzled Bt_hi/Bt_lo [N][K] bf16 --------
__global__ __launch_bounds__(256)
void pack_plain(const float* __restrict__ W, u16* __restrict__ hi,
                u16* __restrict__ lo, int N, int kshift) {
  const int idx = blockIdx.x * 256 + threadIdx.x;   // n*K + k (logical)
  const int K = 1 << kshift;
  const int n = idx >> kshift, k = idx & (K - 1);
  const float v = W[(size_t)k * N + n];
  const unsigned int h = bfh16(v);
  const float l = v - __uint_as_float(h << 16);
  const size_t o = swz_idx(n, k, K);
  hi[o] = (u16)h;
  lo[o] = (u16)bfh16(l);
}

// QKVG mapping: c<512 WQ(h,k,e); <1024 WK; <2048 WV(h,k,v); else WG[k][c-2048]
__global__ __launch_bounds__(256)
void pack_qkvg(const float* __restrict__ WQ, const float* __restrict__ WK,
               const float* __restrict__ WV, const float* __restrict__ WG,
               u16* __restrict__ hi, u16* __restrict__ lo) {
  const int idx = blockIdx.x * 256 + threadIdx.x;   // c*512 + k (logical)
  const int c = idx >> 9, k = idx & 511;
  float v;
  if (c < 512)
    v = WQ[((size_t)(c >> 6) * 512 + k) * 64 + (c & 63)];
  else if (c < 1024)
    v = WK[((size_t)((c - 512) >> 6) * 512 + k) * 64 + ((c - 512) & 63)];
  else if (c < 2048)
    v = WV[((size_t)((c - 1024) >> 7) * 512 + k) * 128 + ((c - 1024) & 127)];
  else
    v = WG[(size_t)k * 1024 + (c - 2048)];
  const unsigned int h = bfh16(v);
  const float l = v - __uint_as_float(h << 16);
  const size_t o = swz_idx(c, k, 512);
  hi[o] = (u16)h;
  lo[o] = (u16)bfh16(l);
}

// ---- bf16x3 MFMA GEMM, dbuf gload_lds + counted vmcnt + XCD swizzle ------
// (R7 structure.)  K-step t: issue stage(t+1) -> s_waitcnt vmcnt(8) ->
// s_barrier -> setprio(1) frag reads + 48 MFMA setprio(0) -> s_barrier.
// EPI 0: store    2: acc+aux   3: gelu(acc+bias)   4: acc+bias+aux
//     5: w0*sin(acc+b)+w1*cos(acc+b)
//     6: QKVG: col<2048 pass (raw Q/K/V); >=2048 silu (gate)
// OSPLIT 0: fp32 C.  1: swizzled split bf16 planes Ch/Cl.
template<int EPI, int OSPLIT>
__global__ __launch_bounds__(256, 2)
void gemm_lds(const u16* __restrict__ Agh, const u16* __restrict__ Agl,
              const u16* __restrict__ Bh, const u16* __restrict__ Bl,
              float* __restrict__ C, u16* __restrict__ Ch, u16* __restrict__ Cl,
              const int N, const int K,
              const float* __restrict__ bias, const float* __restrict__ aux,
              const float* __restrict__ wave2) {
  __shared__ __align__(16) u16 S[2][4][128][32];   // dbuf x {Ah,Al,Bh,Bl}
  const int tid = threadIdx.x;
  const int lane = tid & 63;
  const int wave = tid >> 6;
  const int wr = (wave >> 1) * 64, wc = (wave & 1) * 64;

  // XCD-chunked bijective remap, n-major logical order (T1)
  int bx = blockIdx.x, by = blockIdx.y;
  {
    const int gx = gridDim.x, gy = gridDim.y;
    const int nwg = gx * gy;
    if ((nwg & 7) == 0) {
      const int id = by * gx + bx;          // dispatch order (x fastest)
      const int q = nwg >> 3;
      const int L = (id & 7) * q + (id >> 3);
      bx = L / gy;                          // n-panel (contiguous per XCD)
      by = L - bx * gy;                     // m-panel
    }
  }
  const int m0 = by * 128, n0 = bx * 128;

  const int fm = lane & 15;
  const int q = lane >> 4;            // logical 16B chunk 0..3

  const u16* pb;
  if (wave == 0)      pb = Agh + (size_t)m0 * K;
  else if (wave == 1) pb = Agl + (size_t)m0 * K;
  else if (wave == 2) pb = Bh + (size_t)n0 * K;
  else                pb = Bl + (size_t)n0 * K;
  const u16* src0 = pb + (size_t)(lane >> 2) * K + (lane & 3) * 8;

  f32x4 acc[4][4];
  #pragma unroll
  for (int i = 0; i < 4; i++)
    #pragma unroll
    for (int j = 0; j < 4; j++)
      acc[i][j] = (f32x4){0.f, 0.f, 0.f, 0.f};

  {  // prologue: stage tile 0 into buf 0 (full drain via __syncthreads)
    u16* dst = &S[0][wave][0][0];
    #pragma unroll
    for (int i = 0; i < 8; i++)
      gload_lds16(src0 + (size_t)(i * 16) * K, dst + i * 512);
  }
  __syncthreads();

  for (int kt = 0; kt < K; kt += 32) {
    const int cur = (kt >> 5) & 1;
    if (kt + 32 < K) {  // issue next tile; keep its 8 loads in flight
      u16* dst = &S[cur ^ 1][wave][0][0];
      const u16* s = src0 + kt + 32;
      #pragma unroll
      for (int i = 0; i < 8; i++)
        gload_lds16(s + (size_t)(i * 16) * K, dst + i * 512);
      asm volatile("s_waitcnt vmcnt(8)" ::: "memory");
    } else {
      asm volatile("s_waitcnt vmcnt(0)" ::: "memory");
    }
    __builtin_amdgcn_sched_barrier(0);
    __builtin_amdgcn_s_barrier();
    __builtin_amdgcn_sched_barrier(0);
    __builtin_amdgcn_s_setprio(1);

    bf16x8 avh[4], avl[4];
    #pragma unroll
    for (int mf = 0; mf < 4; mf++) {
      const int m = wr + mf * 16 + fm;
      const int c = (q ^ ((m >> 1) & 3)) * 8;   // swizzled read
      avh[mf] = *(const bf16x8*)&S[cur][0][m][c];
      avl[mf] = *(const bf16x8*)&S[cur][1][m][c];
    }
    #pragma unroll
    for (int nf = 0; nf < 4; nf++) {
      const int n = wc + nf * 16 + fm;
      const int c = (q ^ ((n >> 1) & 3)) * 8;
      bf16x8 bh = *(const bf16x8*)&S[cur][2][n][c];
      bf16x8 bl = *(const bf16x8*)&S[cur][3][n][c];
      #pragma unroll
      for (int mf = 0; mf < 4; mf++) {
        acc[mf][nf] = __builtin_amdgcn_mfma_f32_16x16x32_bf16(avh[mf], bh, acc[mf][nf], 0, 0, 0);
        acc[mf][nf] = __builtin_amdgcn_mfma_f32_16x16x32_bf16(avl[mf], bh, acc[mf][nf], 0, 0, 0);
        acc[mf][nf] = __builtin_amdgcn_mfma_f32_16x16x32_bf16(avh[mf], bl, acc[mf][nf], 0, 0, 0);
      }
    }
    __builtin_amdgcn_s_setprio(0);
    __builtin_amdgcn_sched_barrier(0);
    __builtin_amdgcn_s_barrier();
  }

  // epilogue: D frag: col = lane&15, row = (lane>>4)*4 + r
  const int r0 = m0 + wr + (lane >> 4) * 4;
  const int c0 = n0 + wc + fm;
  #pragma unroll
  for (int mf = 0; mf < 4; mf++) {
    #pragma unroll
    for (int nf = 0; nf < 4; nf++) {
      const int col = c0 + nf * 16;
      #pragma unroll
      for (int r = 0; r < 4; r++) {
        const int row = r0 + mf * 16 + r;
        const size_t idx = (size_t)row * N + col;   // logical (C, aux)
        float v = acc[mf][nf][r];
        float o;
        if constexpr (EPI == 0) {
          o = v;
        } else if constexpr (EPI == 2) {
          o = v + aux[idx];
        } else if constexpr (EPI == 3) {
          v += bias[col];
          o = 0.5f * v * (1.f + erff(v * 0.70710678118654752f));
        } else if constexpr (EPI == 4) {
          o = v + bias[col] + aux[idx];
        } else if constexpr (EPI == 5) {
          v += bias[col];
          o = wave2[0] * sinf(v) + wave2[1] * cosf(v);
        } else {
          // EPI 6: raw Q/K/V pass; silu for gate cols (wave-uniform per nf)
          if (col < 2048) o = v;
          else            o = v / (1.f + expf(-v));
        }
        if constexpr (OSPLIT == 0) {
          C[idx] = o;
        } else {
          const size_t sidx = swz_idx(row, col, N);
          const unsigned int hb = bfh16(o);
          Ch[sidx] = (u16)hb;
          Cl[sidx] = (u16)bfh16(o - __uint_as_float(hb << 16));
        }
      }
    }
  }
}

// ---- launch --------------------------------------------------------------

extern "C" void kernel_launch(void* const* d_in, const int* in_sizes, int n_in,
                              void* d_out, int out_size, void* d_ws, size_t ws_size,
                              hipStream_t stream) {
  (void)in_sizes; (void)n_in; (void)out_size;
  const float* x    = (const float*)d_in[0];
  const float* t    = (const float*)d_in[1];
  const float* embW = (const float*)d_in[2];
  const float* embB = (const float*)d_in[3];
  const float* ln1w = (const float*)d_in[4];
  const float* ln1b = (const float*)d_in[5];
  const float* ln2w = (const float*)d_in[6];
  const float* ln2b = (const float*)d_in[7];
  const float* WQ   = (const float*)d_in[8];
  const float* WK   = (const float*)d_in[9];
  const float* WV   = (const float*)d_in[10];
  const float* WG   = (const float*)d_in[11];
  const float* WO   = (const float*)d_in[12];
  const float* gnw  = (const float*)d_in[13];
  const float* gnb  = (const float*)d_in[14];
  const float* f1W  = (const float*)d_in[15];
  const float* f1b  = (const float*)d_in[16];
  const float* f2W  = (const float*)d_in[17];
  const float* f2bp = (const float*)d_in[18];
  const float* h1W  = (const float*)d_in[19];
  const float* h1b  = (const float*)d_in[20];
  const float* wvw  = (const float*)d_in[21];
  const float* h2W  = (const float*)d_in[22];
  const float* h2b  = (const float*)d_in[23];
  const float* h3W  = (const float*)d_in[24];
  const float* h3b  = (const float*)d_in[25];

  // ---- packed-weight area (bf16 hi/lo, swizzled [N][K]) ----
  u16* P = (u16*)d_ws;
  const size_t SQKVG = 3072 * 512, SWO = 512 * 1024;
  const size_t SF1 = 128 * 512, SF2 = 512 * 128;
  const size_t PERL = 2 * (SQKVG + SWO + SF1 + SF2);
  const size_t HOFF = 4 * PERL;                 // heads after layers
  const size_t PACK_BYTES = (HOFF + 4 * 512 * 512) * 2;  // = 37748736
  const size_t TAB_BYTES = 36864 * 4;           // rotation/decay tables

  u16* h1h = P + HOFF;
  u16* h1l = h1h + 512 * 512;
  u16* h2h = h1l + 512 * 512;
  u16* h2l = h2h + 512 * 512;
  float* RT = (float*)((char*)d_ws + PACK_BYTES);

  const dim3 blk(256);

  // tables + pack all weights once
  tab_kernel<<<dim3(80), blk, 0, stream>>>(RT);
  for (int l = 0; l < 4; l++) {
    u16* qkvh = P + l * PERL;
    u16* qkvl = qkvh + SQKVG;
    u16* woh  = qkvl + SQKVG;
    u16* wol  = woh + SWO;
    u16* f1h  = wol + SWO;
    u16* f1l  = f1h + SF1;
    u16* f2h  = f1l + SF1;
    u16* f2l  = f2h + SF2;
    pack_qkvg<<<dim3(SQKVG / 256), blk, 0, stream>>>(
        WQ + (size_t)l * 262144, WK + (size_t)l * 262144,
        WV + (size_t)l * 524288, WG + (size_t)l * 524288, qkvh, qkvl);
    pack_plain<<<dim3(SWO / 256), blk, 0, stream>>>(WO + (size_t)l * 524288, woh, wol, 512, 10);
    pack_plain<<<dim3(SF1 / 256), blk, 0, stream>>>(f1W + (size_t)l * 65536, f1h, f1l, 128, 9);
    pack_plain<<<dim3(SF2 / 256), blk, 0, stream>>>(f2W + (size_t)l * 65536, f2h, f2l, 512, 7);
  }
  pack_plain<<<dim3(1024), blk, 0, stream>>>(h1W, h1h, h1l, 512, 9);
  pack_plain<<<dim3(1024), blk, 0, stream>>>(h2W, h2h, h2l, 512, 9);

  // ---- batch-chunking: NC=4 so the QKVG inter-kernel working set
  // (201 MB/chunk) is Infinity-Cache-resident -> the 805 MB/layer fp32
  // round trip QKVG-write -> attn-read is absorbed by L3, not HBM.
  // Chunks align to batch boundaries (R multiple of 256) so all attention
  // reads stay in-chunk; per-row math is bit-identical to NC=1.
  const size_t BASE = PACK_BYTES + TAB_BYTES;
  int NC = 4;
  while (NC < 256) {
    const size_t R = 65536u / NC;
    if (BASE + R * 22528 + 4096 <= ws_size) break;
    NC <<= 1;
  }
  const int R = 65536 / NC;   // rows per chunk (multiple of 256)

  float* Xf   = (float*)((char*)d_ws + BASE);  // R x 512 residual
  float* Xn   = Xf  + (size_t)R * 512;   // R x 512   LN planes
  float* QKVG = Xn  + (size_t)R * 512;   // R x 3072  QKVG fp32
  float* GYb  = QKVG + (size_t)R * 3072; // R x 1024  GY planes / mid / H1
  float* Yr   = GYb + (size_t)R * 1024;  // R x 512   Yr residual / H2 fp32

  u16* Xnh = (u16*)Xn;           u16* Xnl = Xnh + (size_t)R * 512;
  u16* GYh = (u16*)GYb;          u16* GYl = GYh + (size_t)R * 1024;
  u16* midh = (u16*)GYb;         u16* midl = midh + (size_t)R * 128;
  u16* H1h = (u16*)GYb;          u16* H1l = H1h + (size_t)R * 512;

  for (int c = 0; c < NC; c++) {
    const size_t off = (size_t)c * R;
    embed_kernel<<<dim3(R / 4), blk, 0, stream>>>(x + off, t + off, embW, embB, Xf);

    for (int l = 0; l < 4; l++) {
      u16* qkvh = P + l * PERL;
      u16* qkvl = qkvh + SQKVG;
      u16* woh  = qkvl + SQKVG;
      u16* wol  = woh + SWO;
      u16* f1h  = wol + SWO;
      u16* f1l  = f1h + SF1;
      u16* f2h  = f1l + SF1;
      u16* f2l  = f2h + SF2;

      ln_split<<<dim3(R / 4), blk, 0, stream>>>(Xf, ln1w + l * 512, ln1b + l * 512, Xnh, Xnl);
      // [Q|K|V|G] = Xn @ [WQ|WK|WV|WG][l]; silu on gate cols in epilogue
      gemm_lds<6, 0><<<dim3(24, R / 128), blk, 0, stream>>>(
          Xnh, Xnl, qkvh, qkvl, QKVG, nullptr, nullptr,
          3072, 512, nullptr, nullptr, nullptr);
      // retention attention (rotation at staging) + groupnorm + gate
      attn_fused<<<dim3(R / 64, 8), blk, 0, stream>>>(
          QKVG, GYh, GYl, gnw + l * 1024, gnb + l * 1024, RT);
      // Yr = GY @ WO[l] + X
      gemm_lds<2, 0><<<dim3(4, R / 128), blk, 0, stream>>>(
          GYh, GYl, woh, wol, Yr, nullptr, nullptr,
          512, 1024, nullptr, Xf, nullptr);
      ln_split<<<dim3(R / 4), blk, 0, stream>>>(Yr, ln2w + l * 512, ln2b + l * 512, Xnh, Xnl);
      // mid = gelu(Xn @ f1[l] + b1)  -> split planes (GY slot dead)
      gemm_lds<3, 1><<<dim3(1, R / 128), blk, 0, stream>>>(
          Xnh, Xnl, f1h, f1l, nullptr, midh, midl,
          128, 512, f1b + l * 128, nullptr, nullptr);
      // X = mid @ f2[l] + b2 + Yr
      gemm_lds<4, 0><<<dim3(4, R / 128), blk, 0, stream>>>(
          midh, midl, f2h, f2l, Xf, nullptr, nullptr,
          512, 128, f2bp + l * 512, Yr, nullptr);
    }

    // head: split Xf once, then gemm_lds all the way
    split_kernel<<<dim3(R / 4), blk, 0, stream>>>(Xf, Xnh, Xnl);
    gemm_lds<5, 1><<<dim3(4, R / 128), blk, 0, stream>>>(
        Xnh, Xnl, h1h, h1l, nullptr, H1h, H1l,
        512, 512, h1b, nullptr, wvw);
    gemm_lds<5, 0><<<dim3(4, R / 128), blk, 0, stream>>>(
        H1h, H1l, h2h, h2l, Yr, nullptr, nullptr,
        512, 512, h2b, nullptr, wvw + 2);
    head3_kernel<<<dim3(R / 4), blk, 0, stream>>>(
        Yr, h3W, h3b, (float*)d_out + off);
  }
}

// Round 12
// 8846.308 us; speedup vs baseline: 1.3789x; 1.1330x over previous
//
#include <hip/hip_runtime.h>
#include <cstdint>
#include <cstddef>

#define DEV static __device__ __forceinline__

typedef short bf16x8 __attribute__((ext_vector_type(8)));
typedef float f32x4 __attribute__((ext_vector_type(4)));
typedef unsigned short u16;

DEV float wredf(float v) {
  v += __shfl_xor(v, 32, 64); v += __shfl_xor(v, 16, 64);
  v += __shfl_xor(v, 8, 64);  v += __shfl_xor(v, 4, 64);
  v += __shfl_xor(v, 2, 64);  v += __shfl_xor(v, 1, 64);
  return v;
}

DEV void ld4(float* d, const float* p) {
  float4 t = *(const float4*)p;
  d[0] = t.x; d[1] = t.y; d[2] = t.z; d[3] = t.w;
}
DEV void st4(float* p, const float* s) {
  *(float4*)p = make_float4(s[0], s[1], s[2], s[3]);
}

// round-to-nearest-even fp32 -> bf16 bits
DEV unsigned int bfh16(float v) {
  unsigned int u = __float_as_uint(v);
  return (u + 0x7FFFu + ((u >> 16) & 1u)) >> 16;
}
// split pair (a,b) -> packed hi-word / lo-word (2x bf16 each)
DEV uint2 splitpk(float a, float b) {
  unsigned int ha = bfh16(a), hb = bfh16(b);
  float la = a - __uint_as_float(ha << 16);
  float lb = b - __uint_as_float(hb << 16);
  return make_uint2(ha | (hb << 16), bfh16(la) | (bfh16(lb) << 16));
}

// T2 swizzle for plane buffers: within each 32-elem k-segment, 16B chunk
// c -> c ^ ((row>>1)&3).  Writers store swizzled; gemm_lds reads swizzled;
// global_load_lds stages linearly (rule #21).
DEV size_t swz_idx(int row, int col, int ld) {
  return (size_t)row * ld + (col & ~31) +
         ((((col >> 3) & 3) ^ ((row >> 1) & 3)) << 3) + (col & 7);
}

// LDS swizzle for attention planes: rows of 64 u16 (128 B), 8 chunks of
// 16 B; chunk c -> c ^ (row & 7).  Frag reads then hit all 8 chunk slots
// across 8 consecutive rows (2-way max, free per m136).
DEV int lswc(int row, int c) { return row * 64 + ((c ^ (row & 7)) << 3); }
DEV int lsw16(int row, int m) {
  return row * 64 + (((m >> 3) ^ (row & 7)) << 3) + (m & 7);
}

// async global->LDS, 16B per lane: LDS dest = base + lane*16 (HW)
DEV void gload_lds16(const void* g, void* l) {
  __builtin_amdgcn_global_load_lds(
      (const __attribute__((address_space(1))) unsigned int*)g,
      (__attribute__((address_space(3))) unsigned int*)l, 16, 0, 0);
}

// ---- rotation/decay tables (once per launch) -----------------------------
// floats: [0,16384) rotq (s*32+i)*2 = {cos*sc, sin*sc}
//         [16384,32768) rotk = {cos/sc, sin/sc}
//         [32768,34816) gq[h][s] = gamma_h^s
//         [34816,36864) gk[h][s] = gamma_h^-s
__global__ __launch_bounds__(256)
void tab_kernel(float* __restrict__ rtab) {
  const int idx = blockIdx.x * 256 + threadIdx.x;
  if (idx < 16384) {
    const int tk = idx >> 13;          // 0=q, 1=k
    const int e = idx & 8191;
    const int s = e >> 5, i = e & 31;
    const float sv = (2.0f * i + 25.6f) / 89.6f;
    const float sc = powf(sv, (float)s / 512.0f);
    const float invf = powf(10000.0f, -(float)i / 32.0f);
    const float ang = (float)s * invf;
    const float f = tk ? 1.0f / sc : sc;
    rtab[tk * 16384 + e * 2]     = cosf(ang) * f;
    rtab[tk * 16384 + e * 2 + 1] = sinf(ang) * f;
  } else if (idx < 20480) {
    const int e = idx - 16384;         // 0..4095
    const int tk = e >> 11;            // 0=gq, 1=gk
    const int he = e & 2047;
    const int h = he >> 8, s = he & 255;
    const float l32 = logf(1.0f / 32.0f), l512 = logf(1.0f / 512.0f);
    const float gamma = 1.0f - expf(l32 + (float)h * (l512 - l32) / 7.0f);
    const float g = powf(gamma, (float)s);
    rtab[32768 + e] = tk ? 1.0f / g : g;
  }
}

// ---- embed: src = [x,t] @ emb_W + emb_b  (fp32) --------------------------
__global__ __launch_bounds__(256)
void embed_kernel(const float* __restrict__ x, const float* __restrict__ t,
                  const float* __restrict__ W, const float* __restrict__ eb,
                  float* __restrict__ X) {
  const int gid = blockIdx.x * 256 + threadIdx.x;  // R*64
  const int row = gid >> 6, d = (gid & 63) * 8;
  const float xv = x[row], tv = t[row];
  #pragma unroll
  for (int j = 0; j < 8; j++)
    X[(size_t)row * 512 + d + j] =
        xv * W[d + j] + tv * W[512 + d + j] + eb[d + j];
}

// ---- layernorm row=512, fp32 -> split bf16 hi/lo planes (swizzled) -------
__global__ __launch_bounds__(256)
void ln_split(const float* __restrict__ X, const float* __restrict__ w,
              const float* __restrict__ bb, u16* __restrict__ hi,
              u16* __restrict__ lo) {
  const int row = blockIdx.x * 4 + (threadIdx.x >> 6);
  const int lane = threadIdx.x & 63;
  const float* xp = X + (size_t)row * 512 + lane * 8;
  float4 a0 = *(const float4*)xp;
  float4 a1 = *(const float4*)(xp + 4);
  float v[8] = {a0.x, a0.y, a0.z, a0.w, a1.x, a1.y, a1.z, a1.w};
  float s = 0.f, sq = 0.f;
  #pragma unroll
  for (int j = 0; j < 8; j++) { s += v[j]; sq += v[j] * v[j]; }
  s = wredf(s); sq = wredf(sq);
  const float mean = s * (1.f / 512.f);
  const float var = fmaxf(sq * (1.f / 512.f) - mean * mean, 0.f);
  const float inv = rsqrtf(var + 1e-5f);
  const float* wp = w + lane * 8;
  const float* bp = bb + lane * 8;
  float o[8];
  #pragma unroll
  for (int j = 0; j < 8; j++)
    o[j] = (v[j] - mean) * inv * wp[j] + bp[j];
  uint2 p0 = splitpk(o[0], o[1]), p1 = splitpk(o[2], o[3]);
  uint2 p2 = splitpk(o[4], o[5]), p3 = splitpk(o[6], o[7]);
  const size_t off = swz_idx(row, lane * 8, 512);
  *(int4*)(hi + off) = make_int4(p0.x, p1.x, p2.x, p3.x);
  *(int4*)(lo + off) = make_int4(p0.y, p1.y, p2.y, p3.y);
}

// ---- plain fp32 -> split planes (swizzled), no norm (head input) ---------
__global__ __launch_bounds__(256)
void split_kernel(const float* __restrict__ X, u16* __restrict__ hi,
                  u16* __restrict__ lo) {
  const int row = blockIdx.x * 4 + (threadIdx.x >> 6);
  const int lane = threadIdx.x & 63;
  const float* xp = X + (size_t)row * 512 + lane * 8;
  float v[8];
  ld4(v, xp); ld4(v + 4, xp + 4);
  uint2 p0 = splitpk(v[0], v[1]), p1 = splitpk(v[2], v[3]);
  uint2 p2 = splitpk(v[4], v[5]), p3 = splitpk(v[6], v[7]);
  const size_t off = swz_idx(row, lane * 8, 512);
  *(int4*)(hi + off) = make_int4(p0.x, p1.x, p2.x, p3.x);
  *(int4*)(lo + off) = make_int4(p0.y, p1.y, p2.y, p3.y);
}

// ---- MFMA retention attention + groupnorm + gate -> GY planes ------------
// QKVG row (3072): [Q(512) K(512) V(1024) G(1024)]; Q/K raw, rotated+decayed
// at staging via rtab; G pre-silu'd by the GEMM epilogue.
// Block: 64 q-rows x 1 head, 4 waves.  Per K/V tile (64 rows):
//   QK^T: bf16x3 MFMA, A=Q[s][e], B=K[m][e] (row-major = B^T pattern)
//   mask in D-frag -> split P -> LDS planes -> PV: A=P[s][m], B=Vt[v][m].
// Wave w owns s-rows w*16..w*16+16, full 64 m / 128 v.
__global__ __launch_bounds__(256)
void attn_mfma(const float* __restrict__ QKV, u16* __restrict__ GYh,
               u16* __restrict__ GYl, const float* __restrict__ gw,
               const float* __restrict__ gb, const float* __restrict__ rtab) {
  __shared__ __align__(16) u16 QsH[64 * 64], QsL[64 * 64];
  __shared__ __align__(16) u16 KsH[64 * 64], KsL[64 * 64];
  __shared__ __align__(16) u16 Ph[64 * 64], Pl[64 * 64];
  __shared__ __align__(16) u16 VtH[128 * 64], VtL[128 * 64];
  const int h = blockIdx.y;
  const int r0 = blockIdx.x * 64;       // chunk-local first q-row
  const int b = r0 >> 8;
  const int s0 = r0 & 255;              // multiple of 64
  const int st = s0 >> 6;               // diagonal m-tile index
  const int tid = threadIdx.x;
  const int lane = tid & 63;
  const int w = tid >> 6;
  const int fr = lane & 15, fq = lane >> 4;

  {  // stage Q: rotate (*gamma^s * scale), split, swizzled planes
    const int rr = tid >> 2, e0 = (tid & 3) * 16;
    const int s = (r0 + rr) & 255;
    const float gq = rtab[32768 + h * 256 + s];
    const float* qp = QKV + (size_t)(r0 + rr) * 3072 + h * 64 + e0;
    const float* rt = rtab + ((size_t)s * 32 + (e0 >> 1)) * 2;
    float o[16];
    #pragma unroll
    for (int j = 0; j < 8; j++) {
      const float c = rt[2 * j] * gq, sn = rt[2 * j + 1] * gq;
      const float v0 = qp[2 * j], v1 = qp[2 * j + 1];
      o[2 * j]     = v0 * c - v1 * sn;
      o[2 * j + 1] = v1 * c + v0 * sn;
    }
    uint2 qq[8];
    #pragma unroll
    for (int i = 0; i < 8; i++) qq[i] = splitpk(o[2 * i], o[2 * i + 1]);
    const int c0 = e0 >> 3;
    *(int4*)&QsH[lswc(rr, c0)]     = make_int4(qq[0].x, qq[1].x, qq[2].x, qq[3].x);
    *(int4*)&QsH[lswc(rr, c0 + 1)] = make_int4(qq[4].x, qq[5].x, qq[6].x, qq[7].x);
    *(int4*)&QsL[lswc(rr, c0)]     = make_int4(qq[0].y, qq[1].y, qq[2].y, qq[3].y);
    *(int4*)&QsL[lswc(rr, c0 + 1)] = make_int4(qq[4].y, qq[5].y, qq[6].y, qq[7].y);
  }

  f32x4 acc[8];
  #pragma unroll
  for (int i = 0; i < 8; i++) acc[i] = (f32x4){0.f, 0.f, 0.f, 0.f};

  for (int mt = 0; mt <= st; mt++) {
    const int m0 = mt * 64;
    __syncthreads();   // prev PV done before K/Vt overwrite (Q safe: 1st use after next bar)

    {  // stage K: rotate (/gamma^m / scale), split, swizzled planes
      const int rr = tid >> 2, e0 = (tid & 3) * 16;
      const int m = m0 + rr;
      const float gk = rtab[34816 + h * 256 + m];
      const float* kp = QKV + (size_t)(b * 256 + m) * 3072 + 512 + h * 64 + e0;
      const float* rt = rtab + 16384 + ((size_t)m * 32 + (e0 >> 1)) * 2;
      float o[16];
      #pragma unroll
      for (int j = 0; j < 8; j++) {
        const float c = rt[2 * j] * gk, sn = rt[2 * j + 1] * gk;
        const float v0 = kp[2 * j], v1 = kp[2 * j + 1];
        o[2 * j]     = v0 * c - v1 * sn;
        o[2 * j + 1] = v1 * c + v0 * sn;
      }
      uint2 kk[8];
      #pragma unroll
      for (int i = 0; i < 8; i++) kk[i] = splitpk(o[2 * i], o[2 * i + 1]);
      const int c0 = e0 >> 3;
      *(int4*)&KsH[lswc(rr, c0)]     = make_int4(kk[0].x, kk[1].x, kk[2].x, kk[3].x);
      *(int4*)&KsH[lswc(rr, c0 + 1)] = make_int4(kk[4].x, kk[5].x, kk[6].x, kk[7].x);
      *(int4*)&KsL[lswc(rr, c0)]     = make_int4(kk[0].y, kk[1].y, kk[2].y, kk[3].y);
      *(int4*)&KsL[lswc(rr, c0 + 1)] = make_int4(kk[4].y, kk[5].y, kk[6].y, kk[7].y);
    }
    {  // stage V transposed: Vt[v][m] split planes
      const int vv = tid >> 1;          // 0..127
      const int mh = (tid & 1) * 32;    // 0 / 32
      const float* vp = QKV + (size_t)(b * 256 + m0 + mh) * 3072 + 1024 + h * 128 + vv;
      float pvv[32];
      #pragma unroll
      for (int mm = 0; mm < 32; mm++) pvv[mm] = vp[(size_t)mm * 3072];
      uint2 qv[16];
      #pragma unroll
      for (int i = 0; i < 16; i++) qv[i] = splitpk(pvv[2 * i], pvv[2 * i + 1]);
      const int cb = mh >> 3;           // 0 or 4
      #pragma unroll
      for (int j = 0; j < 4; j++) {
        *(int4*)&VtH[lswc(vv, cb + j)] =
            make_int4(qv[4 * j].x, qv[4 * j + 1].x, qv[4 * j + 2].x, qv[4 * j + 3].x);
        *(int4*)&VtL[lswc(vv, cb + j)] =
            make_int4(qv[4 * j].y, qv[4 * j + 1].y, qv[4 * j + 2].y, qv[4 * j + 3].y);
      }
    }
    __syncthreads();

    // QK^T: wave w -> rows w*16..+16, all 64 m (4 mf frags), K=64 (2 steps)
    f32x4 sa[4];
    #pragma unroll
    for (int i = 0; i < 4; i++) sa[i] = (f32x4){0.f, 0.f, 0.f, 0.f};
    #pragma unroll
    for (int kt = 0; kt < 2; kt++) {
      const int ck = fq + kt * 4;
      bf16x8 ah = *(const bf16x8*)&QsH[lswc(w * 16 + fr, ck)];
      bf16x8 al = *(const bf16x8*)&QsL[lswc(w * 16 + fr, ck)];
      #pragma unroll
      for (int mf = 0; mf < 4; mf++) {
        bf16x8 bh = *(const bf16x8*)&KsH[lswc(mf * 16 + fr, ck)];
        bf16x8 bl = *(const bf16x8*)&KsL[lswc(mf * 16 + fr, ck)];
        sa[mf] = __builtin_amdgcn_mfma_f32_16x16x32_bf16(ah, bh, sa[mf], 0, 0, 0);
        sa[mf] = __builtin_amdgcn_mfma_f32_16x16x32_bf16(al, bh, sa[mf], 0, 0, 0);
        sa[mf] = __builtin_amdgcn_mfma_f32_16x16x32_bf16(ah, bl, sa[mf], 0, 0, 0);
      }
    }
    // mask (diagonal tile) + split P -> LDS planes
    const bool diag = (mt == st);
    #pragma unroll
    for (int mf = 0; mf < 4; mf++) {
      const int ml = mf * 16 + fr;
      #pragma unroll
      for (int r = 0; r < 4; r++) {
        float v = sa[mf][r];
        const int sl = w * 16 + fq * 4 + r;
        if (diag && ml > sl) v = 0.f;
        const unsigned hb = bfh16(v);
        const int pi = lsw16(sl, ml);
        Ph[pi] = (u16)hb;
        Pl[pi] = (u16)bfh16(v - __uint_as_float(hb << 16));
      }
    }
    __syncthreads();

    // PV: wave w -> rows w*16..+16, all 128 v (8 vf frags), K=64 (2 steps)
    #pragma unroll
    for (int kt = 0; kt < 2; kt++) {
      const int ck = fq + kt * 4;
      bf16x8 ph = *(const bf16x8*)&Ph[lswc(w * 16 + fr, ck)];
      bf16x8 pl = *(const bf16x8*)&Pl[lswc(w * 16 + fr, ck)];
      #pragma unroll
      for (int vf = 0; vf < 8; vf++) {
        bf16x8 vh = *(const bf16x8*)&VtH[lswc(vf * 16 + fr, ck)];
        bf16x8 vl = *(const bf16x8*)&VtL[lswc(vf * 16 + fr, ck)];
        acc[vf] = __builtin_amdgcn_mfma_f32_16x16x32_bf16(ph, vh, acc[vf], 0, 0, 0);
        acc[vf] = __builtin_amdgcn_mfma_f32_16x16x32_bf16(pl, vh, acc[vf], 0, 0, 0);
        acc[vf] = __builtin_amdgcn_mfma_f32_16x16x32_bf16(ph, vl, acc[vf], 0, 0, 0);
      }
    }
  }

  // epilogue: groupnorm per row (16-lane group reduce) + affine + gate
  const int vi0 = h * 128;
  #pragma unroll
  for (int r = 0; r < 4; r++) {
    const int row = r0 + w * 16 + fq * 4 + r;
    float vals[8];
    float s = 0.f, sq = 0.f;
    #pragma unroll
    for (int vf = 0; vf < 8; vf++) {
      vals[vf] = acc[vf][r];
      s += vals[vf]; sq += vals[vf] * vals[vf];
    }
    #pragma unroll
    for (int msk = 1; msk <= 8; msk <<= 1) {
      s += __shfl_xor(s, msk, 64);
      sq += __shfl_xor(sq, msk, 64);
    }
    const float mean = s * (1.f / 128.f);
    const float var = fmaxf(sq * (1.f / 128.f) - mean * mean, 0.f);
    const float inv = rsqrtf(var + 1e-5f);
    const float* gp = QKV + (size_t)row * 3072 + 2048 + vi0;
    #pragma unroll
    for (int vf = 0; vf < 8; vf++) {
      const int vc = vf * 16 + fr;
      const float o = ((vals[vf] - mean) * inv * gw[vi0 + vc] + gb[vi0 + vc]) * gp[vc];
      const size_t off = swz_idx(row, vi0 + vc, 1024);
      const unsigned hb = bfh16(o);
      GYh[off] = (u16)hb;
      GYl[off] = (u16)bfh16(o - __uint_as_float(hb << 16));
    }
  }
}

// ---- final N=1 dot (fp32) ------------------------------------------------
__global__ __launch_bounds__(256)
void head3_kernel(const float* __restrict__ X, const float* __restrict__ w,
                  const float* __restrict__ b3, float* __restrict__ out) {
  const int row = blockIdx.x * 4 + (threadIdx.x >> 6);
  const int lane = threadIdx.x & 63;
  const float* xp = X + (size_t)row * 512 + lane * 8;
  const float* wp = w + lane * 8;
  float s = 0.f;
  #pragma unroll
  for (int j = 0; j < 8; j++) s += xp[j] * wp[j];
  s = wredf(s);
  if (lane == 0) out[row] = s + b3[0];
}

// ---- weight pre-pack: W[K][N] -> swizzled Bt_hi/Bt_lo [N][K] bf16 --------
__global__ __launch_bounds__(256)
void pack_plain(const float* __restrict__ W, u16* __restrict__ hi,
                u16* __restrict__ lo, int N, int kshift) {
  const int idx = blockIdx.x * 256 + threadIdx.x;   // n*K + k (logical)
  const int K = 1 << kshift;
  const int n = idx >> kshift, k = idx & (K - 1);
  const float v = W[(size_t)k * N + n];
  const unsigned int h = bfh16(v);
  const float l = v - __uint_as_float(h << 16);
  const size_t o = swz_idx(n, k, K);
  hi[o] = (u16)h;
  lo[o] = (u16)bfh16(l);
}

// QKVG mapping: c<512 WQ(h,k,e); <1024 WK; <2048 WV(h,k,v); else WG[k][c-2048]
__global__ __launch_bounds__(256)
void pack_qkvg(const float* __restrict__ WQ, const float* __restrict__ WK,
               const float* __restrict__ WV, const float* __restrict__ WG,
               u16* __restrict__ hi, u16* __restrict__ lo) {
  const int idx = blockIdx.x * 256 + threadIdx.x;   // c*512 + k (logical)
  const int c = idx >> 9, k = idx & 511;
  float v;
  if (c < 512)
    v = WQ[((size_t)(c >> 6) * 512 + k) * 64 + (c & 63)];
  else if (c < 1024)
    v = WK[((size_t)((c - 512) >> 6) * 512 + k) * 64 + ((c - 512) & 63)];
  else if (c < 2048)
    v = WV[((size_t)((c - 1024) >> 7) * 512 + k) * 128 + ((c - 1024) & 127)];
  else
    v = WG[(size_t)k * 1024 + (c - 2048)];
  const unsigned int h = bfh16(v);
  const float l = v - __uint_as_float(h << 16);
  const size_t o = swz_idx(c, k, 512);
  hi[o] = (u16)h;
  lo[o] = (u16)bfh16(l);
}

// ---- bf16x3 MFMA GEMM, dbuf gload_lds + counted vmcnt + XCD swizzle ------
// (R7 structure.)  K-step t: issue stage(t+1) -> s_waitcnt vmcnt(8) ->
// s_barrier -> setprio(1) frag reads + 48 MFMA setprio(0) -> s_barrier.
// EPI 0: store    2: acc+aux   3: gelu(acc+bias)   4: acc+bias+aux
//     5: w0*sin(acc+b)+w1*cos(acc+b)
//     6: QKVG: col<2048 pass (raw Q/K/V); >=2048 silu (gate)
// OSPLIT 0: fp32 C.  1: swizzled split bf16 planes Ch/Cl.
template<int EPI, int OSPLIT>
__global__ __launch_bounds__(256, 2)
void gemm_lds(const u16* __restrict__ Agh, const u16* __restrict__ Agl,
              const u16* __restrict__ Bh, const u16* __restrict__ Bl,
              float* __restrict__ C, u16* __restrict__ Ch, u16* __restrict__ Cl,
              const int N, const int K,
              const float* __restrict__ bias, const float* __restrict__ aux,
              const float* __restrict__ wave2) {
  __shared__ __align__(16) u16 S[2][4][128][32];   // dbuf x {Ah,Al,Bh,Bl}
  const int tid = threadIdx.x;
  const int lane = tid & 63;
  const int wave = tid >> 6;
  const int wr = (wave >> 1) * 64, wc = (wave & 1) * 64;

  // XCD-chunked bijective remap, n-major logical order (T1)
  int bx = blockIdx.x, by = blockIdx.y;
  {
    const int gx = gridDim.x, gy = gridDim.y;
    const int nwg = gx * gy;
    if ((nwg & 7) == 0) {
      const int id = by * gx + bx;          // dispatch order (x fastest)
      const int q = nwg >> 3;
      const int L = (id & 7) * q + (id >> 3);
      bx = L / gy;                          // n-panel (contiguous per XCD)
      by = L - bx * gy;                     // m-panel
    }
  }
  const int m0 = by * 128, n0 = bx * 128;

  const int fm = lane & 15;
  const int q = lane >> 4;            // logical 16B chunk 0..3

  const u16* pb;
  if (wave == 0)      pb = Agh + (size_t)m0 * K;
  else if (wave == 1) pb = Agl + (size_t)m0 * K;
  else if (wave == 2) pb = Bh + (size_t)n0 * K;
  else                pb = Bl + (size_t)n0 * K;
  const u16* src0 = pb + (size_t)(lane >> 2) * K + (lane & 3) * 8;

  f32x4 acc[4][4];
  #pragma unroll
  for (int i = 0; i < 4; i++)
    #pragma unroll
    for (int j = 0; j < 4; j++)
      acc[i][j] = (f32x4){0.f, 0.f, 0.f, 0.f};

  {  // prologue: stage tile 0 into buf 0 (full drain via __syncthreads)
    u16* dst = &S[0][wave][0][0];
    #pragma unroll
    for (int i = 0; i < 8; i++)
      gload_lds16(src0 + (size_t)(i * 16) * K, dst + i * 512);
  }
  __syncthreads();

  for (int kt = 0; kt < K; kt += 32) {
    const int cur = (kt >> 5) & 1;
    if (kt + 32 < K) {  // issue next tile; keep its 8 loads in flight
      u16* dst = &S[cur ^ 1][wave][0][0];
      const u16* s = src0 + kt + 32;
      #pragma unroll
      for (int i = 0; i < 8; i++)
        gload_lds16(s + (size_t)(i * 16) * K, dst + i * 512);
      asm volatile("s_waitcnt vmcnt(8)" ::: "memory");
    } else {
      asm volatile("s_waitcnt vmcnt(0)" ::: "memory");
    }
    __builtin_amdgcn_sched_barrier(0);
    __builtin_amdgcn_s_barrier();
    __builtin_amdgcn_sched_barrier(0);
    __builtin_amdgcn_s_setprio(1);

    bf16x8 avh[4], avl[4];
    #pragma unroll
    for (int mf = 0; mf < 4; mf++) {
      const int m = wr + mf * 16 + fm;
      const int c = (q ^ ((m >> 1) & 3)) * 8;   // swizzled read
      avh[mf] = *(const bf16x8*)&S[cur][0][m][c];
      avl[mf] = *(const bf16x8*)&S[cur][1][m][c];
    }
    #pragma unroll
    for (int nf = 0; nf < 4; nf++) {
      const int n = wc + nf * 16 + fm;
      const int c = (q ^ ((n >> 1) & 3)) * 8;
      bf16x8 bh = *(const bf16x8*)&S[cur][2][n][c];
      bf16x8 bl = *(const bf16x8*)&S[cur][3][n][c];
      #pragma unroll
      for (int mf = 0; mf < 4; mf++) {
        acc[mf][nf] = __builtin_amdgcn_mfma_f32_16x16x32_bf16(avh[mf], bh, acc[mf][nf], 0, 0, 0);
        acc[mf][nf] = __builtin_amdgcn_mfma_f32_16x16x32_bf16(avl[mf], bh, acc[mf][nf], 0, 0, 0);
        acc[mf][nf] = __builtin_amdgcn_mfma_f32_16x16x32_bf16(avh[mf], bl, acc[mf][nf], 0, 0, 0);
      }
    }
    __builtin_amdgcn_s_setprio(0);
    __builtin_amdgcn_sched_barrier(0);
    __builtin_amdgcn_s_barrier();
  }

  // epilogue: D frag: col = lane&15, row = (lane>>4)*4 + r
  const int r0 = m0 + wr + (lane >> 4) * 4;
  const int c0 = n0 + wc + fm;
  #pragma unroll
  for (int mf = 0; mf < 4; mf++) {
    #pragma unroll
    for (int nf = 0; nf < 4; nf++) {
      const int col = c0 + nf * 16;
      #pragma unroll
      for (int r = 0; r < 4; r++) {
        const int row = r0 + mf * 16 + r;
        const size_t idx = (size_t)row * N + col;   // logical (C, aux)
        float v = acc[mf][nf][r];
        float o;
        if constexpr (EPI == 0) {
          o = v;
        } else if constexpr (EPI == 2) {
          o = v + aux[idx];
        } else if constexpr (EPI == 3) {
          v += bias[col];
          o = 0.5f * v * (1.f + erff(v * 0.70710678118654752f));
        } else if constexpr (EPI == 4) {
          o = v + bias[col] + aux[idx];
        } else if constexpr (EPI == 5) {
          v += bias[col];
          o = wave2[0] * sinf(v) + wave2[1] * cosf(v);
        } else {
          // EPI 6: raw Q/K/V pass; silu for gate cols (wave-uniform per nf)
          if (col < 2048) o = v;
          else            o = v / (1.f + expf(-v));
        }
        if constexpr (OSPLIT == 0) {
          C[idx] = o;
        } else {
          const size_t sidx = swz_idx(row, col, N);
          const unsigned int hb = bfh16(o);
          Ch[sidx] = (u16)hb;
          Cl[sidx] = (u16)bfh16(o - __uint_as_float(hb << 16));
        }
      }
    }
  }
}

// ---- launch --------------------------------------------------------------

extern "C" void kernel_launch(void* const* d_in, const int* in_sizes, int n_in,
                              void* d_out, int out_size, void* d_ws, size_t ws_size,
                              hipStream_t stream) {
  (void)in_sizes; (void)n_in; (void)out_size;
  const float* x    = (const float*)d_in[0];
  const float* t    = (const float*)d_in[1];
  const float* embW = (const float*)d_in[2];
  const float* embB = (const float*)d_in[3];
  const float* ln1w = (const float*)d_in[4];
  const float* ln1b = (const float*)d_in[5];
  const float* ln2w = (const float*)d_in[6];
  const float* ln2b = (const float*)d_in[7];
  const float* WQ   = (const float*)d_in[8];
  const float* WK   = (const float*)d_in[9];
  const float* WV   = (const float*)d_in[10];
  const float* WG   = (const float*)d_in[11];
  const float* WO   = (const float*)d_in[12];
  const float* gnw  = (const float*)d_in[13];
  const float* gnb  = (const float*)d_in[14];
  const float* f1W  = (const float*)d_in[15];
  const float* f1b  = (const float*)d_in[16];
  const float* f2W  = (const float*)d_in[17];
  const float* f2bp = (const float*)d_in[18];
  const float* h1W  = (const float*)d_in[19];
  const float* h1b  = (const float*)d_in[20];
  const float* wvw  = (const float*)d_in[21];
  const float* h2W  = (const float*)d_in[22];
  const float* h2b  = (const float*)d_in[23];
  const float* h3W  = (const float*)d_in[24];
  const float* h3b  = (const float*)d_in[25];

  // ---- packed-weight area (bf16 hi/lo, swizzled [N][K]) ----
  u16* P = (u16*)d_ws;
  const size_t SQKVG = 3072 * 512, SWO = 512 * 1024;
  const size_t SF1 = 128 * 512, SF2 = 512 * 128;
  const size_t PERL = 2 * (SQKVG + SWO + SF1 + SF2);
  const size_t HOFF = 4 * PERL;                 // heads after layers
  const size_t PACK_BYTES = (HOFF + 4 * 512 * 512) * 2;  // = 37748736
  const size_t TAB_BYTES = 36864 * 4;           // rotation/decay tables

  u16* h1h = P + HOFF;
  u16* h1l = h1h + 512 * 512;
  u16* h2h = h1l + 512 * 512;
  u16* h2l = h2h + 512 * 512;
  float* RT = (float*)((char*)d_ws + PACK_BYTES);

  const dim3 blk(256);

  // tables + pack all weights once
  tab_kernel<<<dim3(80), blk, 0, stream>>>(RT);
  for (int l = 0; l < 4; l++) {
    u16* qkvh = P + l * PERL;
    u16* qkvl = qkvh + SQKVG;
    u16* woh  = qkvl + SQKVG;
    u16* wol  = woh + SWO;
    u16* f1h  = wol + SWO;
    u16* f1l  = f1h + SF1;
    u16* f2h  = f1l + SF1;
    u16* f2l  = f2h + SF2;
    pack_qkvg<<<dim3(SQKVG / 256), blk, 0, stream>>>(
        WQ + (size_t)l * 262144, WK + (size_t)l * 262144,
        WV + (size_t)l * 524288, WG + (size_t)l * 524288, qkvh, qkvl);
    pack_plain<<<dim3(SWO / 256), blk, 0, stream>>>(WO + (size_t)l * 524288, woh, wol, 512, 10);
    pack_plain<<<dim3(SF1 / 256), blk, 0, stream>>>(f1W + (size_t)l * 65536, f1h, f1l, 128, 9);
    pack_plain<<<dim3(SF2 / 256), blk, 0, stream>>>(f2W + (size_t)l * 65536, f2h, f2l, 512, 7);
  }
  pack_plain<<<dim3(1024), blk, 0, stream>>>(h1W, h1h, h1l, 512, 9);
  pack_plain<<<dim3(1024), blk, 0, stream>>>(h2W, h2h, h2l, 512, 9);

  // ---- batch-chunking: NC=4 (R11: L3-resident inter-kernel working set)
  const size_t BASE = PACK_BYTES + TAB_BYTES;
  int NC = 4;
  while (NC < 256) {
    const size_t R = 65536u / NC;
    if (BASE + R * 22528 + 4096 <= ws_size) break;
    NC <<= 1;
  }
  const int R = 65536 / NC;   // rows per chunk (multiple of 256)

  float* Xf   = (float*)((char*)d_ws + BASE);  // R x 512 residual
  float* Xn   = Xf  + (size_t)R * 512;   // R x 512   LN planes
  float* QKVG = Xn  + (size_t)R * 512;   // R x 3072  QKVG fp32
  float* GYb  = QKVG + (size_t)R * 3072; // R x 1024  GY planes / mid / H1
  float* Yr   = GYb + (size_t)R * 1024;  // R x 512   Yr residual / H2 fp32

  u16* Xnh = (u16*)Xn;           u16* Xnl = Xnh + (size_t)R * 512;
  u16* GYh = (u16*)GYb;          u16* GYl = GYh + (size_t)R * 1024;
  u16* midh = (u16*)GYb;         u16* midl = midh + (size_t)R * 128;
  u16* H1h = (u16*)GYb;          u16* H1l = H1h + (size_t)R * 512;

  for (int c = 0; c < NC; c++) {
    const size_t off = (size_t)c * R;
    embed_kernel<<<dim3(R / 4), blk, 0, stream>>>(x + off, t + off, embW, embB, Xf);

    for (int l = 0; l < 4; l++) {
      u16* qkvh = P + l * PERL;
      u16* qkvl = qkvh + SQKVG;
      u16* woh  = qkvl + SQKVG;
      u16* wol  = woh + SWO;
      u16* f1h  = wol + SWO;
      u16* f1l  = f1h + SF1;
      u16* f2h  = f1l + SF1;
      u16* f2l  = f2h + SF2;

      ln_split<<<dim3(R / 4), blk, 0, stream>>>(Xf, ln1w + l * 512, ln1b + l * 512, Xnh, Xnl);
      // [Q|K|V|G] = Xn @ [WQ|WK|WV|WG][l]; silu on gate cols in epilogue
      gemm_lds<6, 0><<<dim3(24, R / 128), blk, 0, stream>>>(
          Xnh, Xnl, qkvh, qkvl, QKVG, nullptr, nullptr,
          3072, 512, nullptr, nullptr, nullptr);
      // MFMA retention attention (rotation at staging) + groupnorm + gate
      attn_mfma<<<dim3(R / 64, 8), blk, 0, stream>>>(
          QKVG, GYh, GYl, gnw + l * 1024, gnb + l * 1024, RT);
      // Yr = GY @ WO[l] + X
      gemm_lds<2, 0><<<dim3(4, R / 128), blk, 0, stream>>>(
          GYh, GYl, woh, wol, Yr, nullptr, nullptr,
          512, 1024, nullptr, Xf, nullptr);
      ln_split<<<dim3(R / 4), blk, 0, stream>>>(Yr, ln2w + l * 512, ln2b + l * 512, Xnh, Xnl);
      // mid = gelu(Xn @ f1[l] + b1)  -> split planes (GY slot dead)
      gemm_lds<3, 1><<<dim3(1, R / 128), blk, 0, stream>>>(
          Xnh, Xnl, f1h, f1l, nullptr, midh, midl,
          128, 512, f1b + l * 128, nullptr, nullptr);
      // X = mid @ f2[l] + b2 + Yr
      gemm_lds<4, 0><<<dim3(4, R / 128), blk, 0, stream>>>(
          midh, midl, f2h, f2l, Xf, nullptr, nullptr,
          512, 128, f2bp + l * 512, Yr, nullptr);
    }

    // head: split Xf once, then gemm_lds all the way
    split_kernel<<<dim3(R / 4), blk, 0, stream>>>(Xf, Xnh, Xnl);
    gemm_lds<5, 1><<<dim3(4, R / 128), blk, 0, stream>>>(
        Xnh, Xnl, h1h, h1l, nullptr, H1h, H1l,
        512, 512, h1b, nullptr, wvw);
    gemm_lds<5, 0><<<dim3(4, R / 128), blk, 0, stream>>>(
        H1h, H1l, h2h, h2l, Yr, nullptr, nullptr,
        512, 512, h2b, nullptr, wvw + 2);
    head3_kernel<<<dim3(R / 4), blk, 0, stream>>>(
        Yr, h3W, h3b, (float*)d_out + off);
  }
}

// Round 14
// 8447.149 us; speedup vs baseline: 1.4440x; 1.0473x over previous
//
#include <hip/hip_runtime.h>
#include <cstdint>
#include <cstddef>

#define DEV static __device__ __forceinline__

typedef short bf16x8 __attribute__((ext_vector_type(8)));
typedef float f32x4 __attribute__((ext_vector_type(4)));
typedef unsigned short u16;

DEV float wredf(float v) {
  v += __shfl_xor(v, 32, 64); v += __shfl_xor(v, 16, 64);
  v += __shfl_xor(v, 8, 64);  v += __shfl_xor(v, 4, 64);
  v += __shfl_xor(v, 2, 64);  v += __shfl_xor(v, 1, 64);
  return v;
}

DEV void ld4(float* d, const float* p) {
  float4 t = *(const float4*)p;
  d[0] = t.x; d[1] = t.y; d[2] = t.z; d[3] = t.w;
}
DEV void st4(float* p, const float* s) {
  *(float4*)p = make_float4(s[0], s[1], s[2], s[3]);
}

// round-to-nearest-even fp32 -> bf16 bits
DEV unsigned int bfh16(float v) {
  unsigned int u = __float_as_uint(v);
  return (u + 0x7FFFu + ((u >> 16) & 1u)) >> 16;
}
// split pair (a,b) -> packed hi-word / lo-word (2x bf16 each)
DEV uint2 splitpk(float a, float b) {
  unsigned int ha = bfh16(a), hb = bfh16(b);
  float la = a - __uint_as_float(ha << 16);
  float lb = b - __uint_as_float(hb << 16);
  return make_uint2(ha | (hb << 16), bfh16(la) | (bfh16(lb) << 16));
}

// T2 swizzle for plane buffers: within each 32-elem k-segment, 16B chunk
// c -> c ^ ((row>>1)&3).  Writers store swizzled; gemm reads swizzled;
// global_load_lds stages linearly (rule #21).
DEV size_t swz_idx(int row, int col, int ld) {
  return (size_t)row * ld + (col & ~31) +
         ((((col >> 3) & 3) ^ ((row >> 1) & 3)) << 3) + (col & 7);
}

// LDS swizzle for attention planes: rows of 64 u16 (128 B), 8 chunks of
// 16 B; chunk c -> c ^ (row & 7).
DEV int lswc(int row, int c) { return row * 64 + ((c ^ (row & 7)) << 3); }
DEV int lsw16(int row, int m) {
  return row * 64 + (((m >> 3) ^ (row & 7)) << 3) + (m & 7);
}

// async global->LDS, 16B per lane: LDS dest = base + lane*16 (HW)
DEV void gload_lds16(const void* g, void* l) {
  __builtin_amdgcn_global_load_lds(
      (const __attribute__((address_space(1))) unsigned int*)g,
      (__attribute__((address_space(3))) unsigned int*)l, 16, 0, 0);
}

// ---- rotation/decay tables (once per launch) -----------------------------
__global__ __launch_bounds__(256)
void tab_kernel(float* __restrict__ rtab) {
  const int idx = blockIdx.x * 256 + threadIdx.x;
  if (idx < 16384) {
    const int tk = idx >> 13;          // 0=q, 1=k
    const int e = idx & 8191;
    const int s = e >> 5, i = e & 31;
    const float sv = (2.0f * i + 25.6f) / 89.6f;
    const float sc = powf(sv, (float)s / 512.0f);
    const float invf = powf(10000.0f, -(float)i / 32.0f);
    const float ang = (float)s * invf;
    const float f = tk ? 1.0f / sc : sc;
    rtab[tk * 16384 + e * 2]     = cosf(ang) * f;
    rtab[tk * 16384 + e * 2 + 1] = sinf(ang) * f;
  } else if (idx < 20480) {
    const int e = idx - 16384;         // 0..4095
    const int tk = e >> 11;            // 0=gq, 1=gk
    const int he = e & 2047;
    const int h = he >> 8, s = he & 255;
    const float l32 = logf(1.0f / 32.0f), l512 = logf(1.0f / 512.0f);
    const float gamma = 1.0f - expf(l32 + (float)h * (l512 - l32) / 7.0f);
    const float g = powf(gamma, (float)s);
    rtab[32768 + e] = tk ? 1.0f / g : g;
  }
}

// ---- embed: src = [x,t] @ emb_W + emb_b  (fp32) --------------------------
__global__ __launch_bounds__(256)
void embed_kernel(const float* __restrict__ x, const float* __restrict__ t,
                  const float* __restrict__ W, const float* __restrict__ eb,
                  float* __restrict__ X) {
  const int gid = blockIdx.x * 256 + threadIdx.x;  // R*64
  const int row = gid >> 6, d = (gid & 63) * 8;
  const float xv = x[row], tv = t[row];
  #pragma unroll
  for (int j = 0; j < 8; j++)
    X[(size_t)row * 512 + d + j] =
        xv * W[d + j] + tv * W[512 + d + j] + eb[d + j];
}

// ---- layernorm row=512, fp32 -> split bf16 hi/lo planes (swizzled) -------
__global__ __launch_bounds__(256)
void ln_split(const float* __restrict__ X, const float* __restrict__ w,
              const float* __restrict__ bb, u16* __restrict__ hi,
              u16* __restrict__ lo) {
  const int row = blockIdx.x * 4 + (threadIdx.x >> 6);
  const int lane = threadIdx.x & 63;
  const float* xp = X + (size_t)row * 512 + lane * 8;
  float4 a0 = *(const float4*)xp;
  float4 a1 = *(const float4*)(xp + 4);
  float v[8] = {a0.x, a0.y, a0.z, a0.w, a1.x, a1.y, a1.z, a1.w};
  float s = 0.f, sq = 0.f;
  #pragma unroll
  for (int j = 0; j < 8; j++) { s += v[j]; sq += v[j] * v[j]; }
  s = wredf(s); sq = wredf(sq);
  const float mean = s * (1.f / 512.f);
  const float var = fmaxf(sq * (1.f / 512.f) - mean * mean, 0.f);
  const float inv = rsqrtf(var + 1e-5f);
  const float* wp = w + lane * 8;
  const float* bp = bb + lane * 8;
  float o[8];
  #pragma unroll
  for (int j = 0; j < 8; j++)
    o[j] = (v[j] - mean) * inv * wp[j] + bp[j];
  uint2 p0 = splitpk(o[0], o[1]), p1 = splitpk(o[2], o[3]);
  uint2 p2 = splitpk(o[4], o[5]), p3 = splitpk(o[6], o[7]);
  const size_t off = swz_idx(row, lane * 8, 512);
  *(int4*)(hi + off) = make_int4(p0.x, p1.x, p2.x, p3.x);
  *(int4*)(lo + off) = make_int4(p0.y, p1.y, p2.y, p3.y);
}

// ---- plain fp32 -> split planes (swizzled), no norm (head input) ---------
__global__ __launch_bounds__(256)
void split_kernel(const float* __restrict__ X, u16* __restrict__ hi,
                  u16* __restrict__ lo) {
  const int row = blockIdx.x * 4 + (threadIdx.x >> 6);
  const int lane = threadIdx.x & 63;
  const float* xp = X + (size_t)row * 512 + lane * 8;
  float v[8];
  ld4(v, xp); ld4(v + 4, xp + 4);
  uint2 p0 = splitpk(v[0], v[1]), p1 = splitpk(v[2], v[3]);
  uint2 p2 = splitpk(v[4], v[5]), p3 = splitpk(v[6], v[7]);
  const size_t off = swz_idx(row, lane * 8, 512);
  *(int4*)(hi + off) = make_int4(p0.x, p1.x, p2.x, p3.x);
  *(int4*)(lo + off) = make_int4(p0.y, p1.y, p2.y, p3.y);
}

// ---- MFMA retention attention + groupnorm + gate -> GY planes ------------
__global__ __launch_bounds__(256)
void attn_mfma(const float* __restrict__ QKV, u16* __restrict__ GYh,
               u16* __restrict__ GYl, const float* __restrict__ gw,
               const float* __restrict__ gb, const float* __restrict__ rtab) {
  __shared__ __align__(16) u16 QsH[64 * 64], QsL[64 * 64];
  __shared__ __align__(16) u16 KsH[64 * 64], KsL[64 * 64];
  __shared__ __align__(16) u16 Ph[64 * 64], Pl[64 * 64];
  __shared__ __align__(16) u16 VtH[128 * 64], VtL[128 * 64];
  const int h = blockIdx.y;
  const int r0 = blockIdx.x * 64;       // chunk-local first q-row
  const int b = r0 >> 8;
  const int s0 = r0 & 255;              // multiple of 64
  const int st = s0 >> 6;               // diagonal m-tile index
  const int tid = threadIdx.x;
  const int lane = tid & 63;
  const int w = tid >> 6;
  const int fr = lane & 15, fq = lane >> 4;

  {  // stage Q: rotate (*gamma^s * scale), split, swizzled planes
    const int rr = tid >> 2, e0 = (tid & 3) * 16;
    const int s = (r0 + rr) & 255;
    const float gq = rtab[32768 + h * 256 + s];
    const float* qp = QKV + (size_t)(r0 + rr) * 3072 + h * 64 + e0;
    const float* rt = rtab + ((size_t)s * 32 + (e0 >> 1)) * 2;
    float o[16];
    #pragma unroll
    for (int j = 0; j < 8; j++) {
      const float c = rt[2 * j] * gq, sn = rt[2 * j + 1] * gq;
      const float v0 = qp[2 * j], v1 = qp[2 * j + 1];
      o[2 * j]     = v0 * c - v1 * sn;
      o[2 * j + 1] = v1 * c + v0 * sn;
    }
    uint2 qq[8];
    #pragma unroll
    for (int i = 0; i < 8; i++) qq[i] = splitpk(o[2 * i], o[2 * i + 1]);
    const int c0 = e0 >> 3;
    *(int4*)&QsH[lswc(rr, c0)]     = make_int4(qq[0].x, qq[1].x, qq[2].x, qq[3].x);
    *(int4*)&QsH[lswc(rr, c0 + 1)] = make_int4(qq[4].x, qq[5].x, qq[6].x, qq[7].x);
    *(int4*)&QsL[lswc(rr, c0)]     = make_int4(qq[0].y, qq[1].y, qq[2].y, qq[3].y);
    *(int4*)&QsL[lswc(rr, c0 + 1)] = make_int4(qq[4].y, qq[5].y, qq[6].y, qq[7].y);
  }

  f32x4 acc[8];
  #pragma unroll
  for (int i = 0; i < 8; i++) acc[i] = (f32x4){0.f, 0.f, 0.f, 0.f};

  for (int mt = 0; mt <= st; mt++) {
    const int m0 = mt * 64;
    __syncthreads();   // prev PV done before K/Vt overwrite

    {  // stage K: rotate (/gamma^m / scale), split, swizzled planes
      const int rr = tid >> 2, e0 = (tid & 3) * 16;
      const int m = m0 + rr;
      const float gk = rtab[34816 + h * 256 + m];
      const float* kp = QKV + (size_t)(b * 256 + m) * 3072 + 512 + h * 64 + e0;
      const float* rt = rtab + 16384 + ((size_t)m * 32 + (e0 >> 1)) * 2;
      float o[16];
      #pragma unroll
      for (int j = 0; j < 8; j++) {
        const float c = rt[2 * j] * gk, sn = rt[2 * j + 1] * gk;
        const float v0 = kp[2 * j], v1 = kp[2 * j + 1];
        o[2 * j]     = v0 * c - v1 * sn;
        o[2 * j + 1] = v1 * c + v0 * sn;
      }
      uint2 kk[8];
      #pragma unroll
      for (int i = 0; i < 8; i++) kk[i] = splitpk(o[2 * i], o[2 * i + 1]);
      const int c0 = e0 >> 3;
      *(int4*)&KsH[lswc(rr, c0)]     = make_int4(kk[0].x, kk[1].x, kk[2].x, kk[3].x);
      *(int4*)&KsH[lswc(rr, c0 + 1)] = make_int4(kk[4].x, kk[5].x, kk[6].x, kk[7].x);
      *(int4*)&KsL[lswc(rr, c0)]     = make_int4(kk[0].y, kk[1].y, kk[2].y, kk[3].y);
      *(int4*)&KsL[lswc(rr, c0 + 1)] = make_int4(kk[4].y, kk[5].y, kk[6].y, kk[7].y);
    }
    {  // stage V transposed: Vt[v][m] split planes
      const int vv = tid >> 1;          // 0..127
      const int mh = (tid & 1) * 32;    // 0 / 32
      const float* vp = QKV + (size_t)(b * 256 + m0 + mh) * 3072 + 1024 + h * 128 + vv;
      float pvv[32];
      #pragma unroll
      for (int mm = 0; mm < 32; mm++) pvv[mm] = vp[(size_t)mm * 3072];
      uint2 qv[16];
      #pragma unroll
      for (int i = 0; i < 16; i++) qv[i] = splitpk(pvv[2 * i], pvv[2 * i + 1]);
      const int cb = mh >> 3;           // 0 or 4
      #pragma unroll
      for (int j = 0; j < 4; j++) {
        *(int4*)&VtH[lswc(vv, cb + j)] =
            make_int4(qv[4 * j].x, qv[4 * j + 1].x, qv[4 * j + 2].x, qv[4 * j + 3].x);
        *(int4*)&VtL[lswc(vv, cb + j)] =
            make_int4(qv[4 * j].y, qv[4 * j + 1].y, qv[4 * j + 2].y, qv[4 * j + 3].y);
      }
    }
    __syncthreads();

    // QK^T: wave w -> rows w*16..+16, all 64 m (4 mf frags), K=64 (2 steps)
    f32x4 sa[4];
    #pragma unroll
    for (int i = 0; i < 4; i++) sa[i] = (f32x4){0.f, 0.f, 0.f, 0.f};
    #pragma unroll
    for (int kt = 0; kt < 2; kt++) {
      const int ck = fq + kt * 4;
      bf16x8 ah = *(const bf16x8*)&QsH[lswc(w * 16 + fr, ck)];
      bf16x8 al = *(const bf16x8*)&QsL[lswc(w * 16 + fr, ck)];
      #pragma unroll
      for (int mf = 0; mf < 4; mf++) {
        bf16x8 bh = *(const bf16x8*)&KsH[lswc(mf * 16 + fr, ck)];
        bf16x8 bl = *(const bf16x8*)&KsL[lswc(mf * 16 + fr, ck)];
        sa[mf] = __builtin_amdgcn_mfma_f32_16x16x32_bf16(ah, bh, sa[mf], 0, 0, 0);
        sa[mf] = __builtin_amdgcn_mfma_f32_16x16x32_bf16(al, bh, sa[mf], 0, 0, 0);
        sa[mf] = __builtin_amdgcn_mfma_f32_16x16x32_bf16(ah, bl, sa[mf], 0, 0, 0);
      }
    }
    // mask (diagonal tile) + split P -> LDS planes
    const bool diag = (mt == st);
    #pragma unroll
    for (int mf = 0; mf < 4; mf++) {
      const int ml = mf * 16 + fr;
      #pragma unroll
      for (int r = 0; r < 4; r++) {
        float v = sa[mf][r];
        const int sl = w * 16 + fq * 4 + r;
        if (diag && ml > sl) v = 0.f;
        const unsigned hb = bfh16(v);
        const int pi = lsw16(sl, ml);
        Ph[pi] = (u16)hb;
        Pl[pi] = (u16)bfh16(v - __uint_as_float(hb << 16));
      }
    }
    __syncthreads();

    // PV: wave w -> rows w*16..+16, all 128 v (8 vf frags), K=64 (2 steps)
    #pragma unroll
    for (int kt = 0; kt < 2; kt++) {
      const int ck = fq + kt * 4;
      bf16x8 ph = *(const bf16x8*)&Ph[lswc(w * 16 + fr, ck)];
      bf16x8 pl = *(const bf16x8*)&Pl[lswc(w * 16 + fr, ck)];
      #pragma unroll
      for (int vf = 0; vf < 8; vf++) {
        bf16x8 vh = *(const bf16x8*)&VtH[lswc(vf * 16 + fr, ck)];
        bf16x8 vl = *(const bf16x8*)&VtL[lswc(vf * 16 + fr, ck)];
        acc[vf] = __builtin_amdgcn_mfma_f32_16x16x32_bf16(ph, vh, acc[vf], 0, 0, 0);
        acc[vf] = __builtin_amdgcn_mfma_f32_16x16x32_bf16(pl, vh, acc[vf], 0, 0, 0);
        acc[vf] = __builtin_amdgcn_mfma_f32_16x16x32_bf16(ph, vl, acc[vf], 0, 0, 0);
      }
    }
  }

  // epilogue: groupnorm per row (16-lane group reduce) + affine + gate
  const int vi0 = h * 128;
  #pragma unroll
  for (int r = 0; r < 4; r++) {
    const int row = r0 + w * 16 + fq * 4 + r;
    float vals[8];
    float s = 0.f, sq = 0.f;
    #pragma unroll
    for (int vf = 0; vf < 8; vf++) {
      vals[vf] = acc[vf][r];
      s += vals[vf]; sq += vals[vf] * vals[vf];
    }
    #pragma unroll
    for (int msk = 1; msk <= 8; msk <<= 1) {
      s += __shfl_xor(s, msk, 64);
      sq += __shfl_xor(sq, msk, 64);
    }
    const float mean = s * (1.f / 128.f);
    const float var = fmaxf(sq * (1.f / 128.f) - mean * mean, 0.f);
    const float inv = rsqrtf(var + 1e-5f);
    const float* gp = QKV + (size_t)row * 3072 + 2048 + vi0;
    #pragma unroll
    for (int vf = 0; vf < 8; vf++) {
      const int vc = vf * 16 + fr;
      const float o = ((vals[vf] - mean) * inv * gw[vi0 + vc] + gb[vi0 + vc]) * gp[vc];
      const size_t off = swz_idx(row, vi0 + vc, 1024);
      const unsigned hb = bfh16(o);
      GYh[off] = (u16)hb;
      GYl[off] = (u16)bfh16(o - __uint_as_float(hb << 16));
    }
  }
}

// ---- final N=1 dot (fp32) ------------------------------------------------
__global__ __launch_bounds__(256)
void head3_kernel(const float* __restrict__ X, const float* __restrict__ w,
                  const float* __restrict__ b3, float* __restrict__ out) {
  const int row = blockIdx.x * 4 + (threadIdx.x >> 6);
  const int lane = threadIdx.x & 63;
  const float* xp = X + (size_t)row * 512 + lane * 8;
  const float* wp = w + lane * 8;
  float s = 0.f;
  #pragma unroll
  for (int j = 0; j < 8; j++) s += xp[j] * wp[j];
  s = wredf(s);
  if (lane == 0) out[row] = s + b3[0];
}

// ---- weight pre-pack: W[K][N] -> swizzled Bt_hi/Bt_lo [N][K] bf16 --------
__global__ __launch_bounds__(256)
void pack_plain(const float* __restrict__ W, u16* __restrict__ hi,
                u16* __restrict__ lo, int N, int kshift) {
  const int idx = blockIdx.x * 256 + threadIdx.x;   // n*K + k (logical)
  const int K = 1 << kshift;
  const int n = idx >> kshift, k = idx & (K - 1);
  const float v = W[(size_t)k * N + n];
  const unsigned int h = bfh16(v);
  const float l = v - __uint_as_float(h << 16);
  const size_t o = swz_idx(n, k, K);
  hi[o] = (u16)h;
  lo[o] = (u16)bfh16(l);
}

// QKVG mapping: c<512 WQ(h,k,e); <1024 WK; <2048 WV(h,k,v); else WG[k][c-2048]
__global__ __launch_bounds__(256)
void pack_qkvg(const float* __restrict__ WQ, const float* __restrict__ WK,
               const float* __restrict__ WV, const float* __restrict__ WG,
               u16* __restrict__ hi, u16* __restrict__ lo) {
  const int idx = blockIdx.x * 256 + threadIdx.x;   // c*512 + k (logical)
  const int c = idx >> 9, k = idx & 511;
  float v;
  if (c < 512)
    v = WQ[((size_t)(c >> 6) * 512 + k) * 64 + (c & 63)];
  else if (c < 1024)
    v = WK[((size_t)((c - 512) >> 6) * 512 + k) * 64 + ((c - 512) & 63)];
  else if (c < 2048)
    v = WV[((size_t)((c - 1024) >> 7) * 512 + k) * 128 + ((c - 1024) & 127)];
  else
    v = WG[(size_t)k * 1024 + (c - 2048)];
  const unsigned int h = bfh16(v);
  const float l = v - __uint_as_float(h << 16);
  const size_t o = swz_idx(c, k, 512);
  hi[o] = (u16)h;
  lo[o] = (u16)bfh16(l);
}

// ---- 128x256 bf16x3 MFMA GEMM for QKVG (R7 schedule, wider N tile) -------
// 512 threads / 8 waves (2Mx4N), each wave 64x64 out (acc[4][4] - same
// register budget as the proven 128^2 kernel).  LDS flattened
// S[2][768][32] u16 = 96 KiB: rows 0..127 Ah, 128..255 Al, 256..511 Bh,
// 512..767 Bl.  Waves 0-5 each stage one 128-row chunk (8x gload_lds16 /
// thread / step, wave-uniform source); waves 6-7 skip staging but run the
// same barriers (vmcnt with 0 outstanding = no-op).  Per K-step: issue
// stage(t+1) -> vmcnt(8) -> barrier -> setprio(1) frags + 48 MFMA/wave
// setprio(0) -> barrier.  EPI: col<2048 pass, >=2048 silu.
__global__ __launch_bounds__(512, 2)
void gemm_qkvg(const u16* __restrict__ Agh, const u16* __restrict__ Agl,
               const u16* __restrict__ Bh, const u16* __restrict__ Bl,
               float* __restrict__ C, const int N, const int K) {
  __shared__ __align__(16) u16 S[2][768][32];   // 96 KiB
  const int tid = threadIdx.x;
  const int lane = tid & 63;
  const int w = tid >> 6;            // 0..7
  const int wr = (w >> 2) * 64;      // 0 / 64
  const int wc = (w & 3) * 64;       // 0,64,128,192

  // XCD-chunked bijective remap, n-major logical order (T1)
  int bx = blockIdx.x, by = blockIdx.y;
  {
    const int gx = gridDim.x, gy = gridDim.y;
    const int nwg = gx * gy;
    if ((nwg & 7) == 0) {
      const int id = by * gx + bx;
      const int q = nwg >> 3;
      const int L = (id & 7) * q + (id >> 3);
      bx = L / gy;
      by = L - bx * gy;
    }
  }
  const int m0 = by * 128, n0 = bx * 256;

  const int fm = lane & 15;
  const int fq = lane >> 4;          // k-chunk / D-row-quad

  // staging source for waves 0..5 (wave-uniform buffer+row-base)
  const u16* src0 = nullptr;
  if (w < 6) {
    const u16* base;
    int rb;
    if (w == 0)      { base = Agh; rb = m0; }
    else if (w == 1) { base = Agl; rb = m0; }
    else if (w == 2) { base = Bh;  rb = n0; }
    else if (w == 3) { base = Bh;  rb = n0 + 128; }
    else if (w == 4) { base = Bl;  rb = n0; }
    else             { base = Bl;  rb = n0 + 128; }
    src0 = base + (size_t)(rb + (lane >> 2)) * K + (lane & 3) * 8;
  }

  f32x4 acc[4][4];
  #pragma unroll
  for (int i = 0; i < 4; i++)
    #pragma unroll
    for (int j = 0; j < 4; j++)
      acc[i][j] = (f32x4){0.f, 0.f, 0.f, 0.f};

  if (w < 6) {  // prologue: stage tile 0 into buf 0
    u16* dst = &S[0][w * 128][0];
    #pragma unroll
    for (int i = 0; i < 8; i++)
      gload_lds16(src0 + (size_t)(i * 16) * K, dst + i * 512);
  }
  __syncthreads();

  for (int kt = 0; kt < K; kt += 32) {
    const int cur = (kt >> 5) & 1;
    if (kt + 32 < K) {
      if (w < 6) {
        u16* dst = &S[cur ^ 1][w * 128][0];
        const u16* s = src0 + kt + 32;
        #pragma unroll
        for (int i = 0; i < 8; i++)
          gload_lds16(s + (size_t)(i * 16) * K, dst + i * 512);
      }
      asm volatile("s_waitcnt vmcnt(8)" ::: "memory");
    } else {
      asm volatile("s_waitcnt vmcnt(0)" ::: "memory");
    }
    __builtin_amdgcn_sched_barrier(0);
    __builtin_amdgcn_s_barrier();
    __builtin_amdgcn_sched_barrier(0);
    __builtin_amdgcn_s_setprio(1);

    bf16x8 avh[4], avl[4];
    #pragma unroll
    for (int mf = 0; mf < 4; mf++) {
      const int m = wr + mf * 16 + fm;          // 0..127
      const int c = (fq ^ ((m >> 1) & 3)) * 8;  // swizzled read
      avh[mf] = *(const bf16x8*)&S[cur][m][c];
      avl[mf] = *(const bf16x8*)&S[cur][128 + m][c];
    }
    #pragma unroll
    for (int nf = 0; nf < 4; nf++) {
      const int n = wc + nf * 16 + fm;          // 0..255
      const int c = (fq ^ ((n >> 1) & 3)) * 8;
      bf16x8 bh = *(const bf16x8*)&S[cur][256 + n][c];
      bf16x8 bl = *(const bf16x8*)&S[cur][512 + n][c];
      #pragma unroll
      for (int mf = 0; mf < 4; mf++) {
        acc[mf][nf] = __builtin_amdgcn_mfma_f32_16x16x32_bf16(avh[mf], bh, acc[mf][nf], 0, 0, 0);
        acc[mf][nf] = __builtin_amdgcn_mfma_f32_16x16x32_bf16(avl[mf], bh, acc[mf][nf], 0, 0, 0);
        acc[mf][nf] = __builtin_amdgcn_mfma_f32_16x16x32_bf16(avh[mf], bl, acc[mf][nf], 0, 0, 0);
      }
    }
    __builtin_amdgcn_s_setprio(0);
    __builtin_amdgcn_sched_barrier(0);
    __builtin_amdgcn_s_barrier();
  }

  // epilogue: D frag: col = fm, row = fq*4 + r
  #pragma unroll
  for (int mf = 0; mf < 4; mf++) {
    #pragma unroll
    for (int nf = 0; nf < 4; nf++) {
      const int col = n0 + wc + nf * 16 + fm;
      #pragma unroll
      for (int r = 0; r < 4; r++) {
        const int row = m0 + wr + mf * 16 + fq * 4 + r;
        const size_t idx = (size_t)row * N + col;
        float v = acc[mf][nf][r];
        C[idx] = (col < 2048) ? v : v / (1.f + expf(-v));
      }
    }
  }
}

// ---- bf16x3 MFMA GEMM 128x128 (R7 schedule) ------------------------------
// EPI 0: store    2: acc+aux   3: gelu(acc+bias)   4: acc+bias+aux
//     5: w0*sin(acc+b)+w1*cos(acc+b)
// OSPLIT 0: fp32 C.  1: swizzled split bf16 planes Ch/Cl.
template<int EPI, int OSPLIT>
__global__ __launch_bounds__(256, 2)
void gemm_lds(const u16* __restrict__ Agh, const u16* __restrict__ Agl,
              const u16* __restrict__ Bh, const u16* __restrict__ Bl,
              float* __restrict__ C, u16* __restrict__ Ch, u16* __restrict__ Cl,
              const int N, const int K,
              const float* __restrict__ bias, const float* __restrict__ aux,
              const float* __restrict__ wave2) {
  __shared__ __align__(16) u16 S[2][4][128][32];   // dbuf x {Ah,Al,Bh,Bl}
  const int tid = threadIdx.x;
  const int lane = tid & 63;
  const int wave = tid >> 6;
  const int wr = (wave >> 1) * 64, wc = (wave & 1) * 64;

  // XCD-chunked bijective remap, n-major logical order (T1)
  int bx = blockIdx.x, by = blockIdx.y;
  {
    const int gx = gridDim.x, gy = gridDim.y;
    const int nwg = gx * gy;
    if ((nwg & 7) == 0) {
      const int id = by * gx + bx;
      const int q = nwg >> 3;
      const int L = (id & 7) * q + (id >> 3);
      bx = L / gy;
      by = L - bx * gy;
    }
  }
  const int m0 = by * 128, n0 = bx * 128;

  const int fm = lane & 15;
  const int q = lane >> 4;            // logical 16B chunk 0..3

  const u16* pb;
  if (wave == 0)      pb = Agh + (size_t)m0 * K;
  else if (wave == 1) pb = Agl + (size_t)m0 * K;
  else if (wave == 2) pb = Bh + (size_t)n0 * K;
  else                pb = Bl + (size_t)n0 * K;
  const u16* src0 = pb + (size_t)(lane >> 2) * K + (lane & 3) * 8;

  f32x4 acc[4][4];
  #pragma unroll
  for (int i = 0; i < 4; i++)
    #pragma unroll
    for (int j = 0; j < 4; j++)
      acc[i][j] = (f32x4){0.f, 0.f, 0.f, 0.f};

  {  // prologue: stage tile 0 into buf 0
    u16* dst = &S[0][wave][0][0];
    #pragma unroll
    for (int i = 0; i < 8; i++)
      gload_lds16(src0 + (size_t)(i * 16) * K, dst + i * 512);
  }
  __syncthreads();

  for (int kt = 0; kt < K; kt += 32) {
    const int cur = (kt >> 5) & 1;
    if (kt + 32 < K) {
      u16* dst = &S[cur ^ 1][wave][0][0];
      const u16* s = src0 + kt + 32;
      #pragma unroll
      for (int i = 0; i < 8; i++)
        gload_lds16(s + (size_t)(i * 16) * K, dst + i * 512);
      asm volatile("s_waitcnt vmcnt(8)" ::: "memory");
    } else {
      asm volatile("s_waitcnt vmcnt(0)" ::: "memory");
    }
    __builtin_amdgcn_sched_barrier(0);
    __builtin_amdgcn_s_barrier();
    __builtin_amdgcn_sched_barrier(0);
    __builtin_amdgcn_s_setprio(1);

    bf16x8 avh[4], avl[4];
    #pragma unroll
    for (int mf = 0; mf < 4; mf++) {
      const int m = wr + mf * 16 + fm;
      const int c = (q ^ ((m >> 1) & 3)) * 8;   // swizzled read
      avh[mf] = *(const bf16x8*)&S[cur][0][m][c];
      avl[mf] = *(const bf16x8*)&S[cur][1][m][c];
    }
    #pragma unroll
    for (int nf = 0; nf < 4; nf++) {
      const int n = wc + nf * 16 + fm;
      const int c = (q ^ ((n >> 1) & 3)) * 8;
      bf16x8 bh = *(const bf16x8*)&S[cur][2][n][c];
      bf16x8 bl = *(const bf16x8*)&S[cur][3][n][c];
      #pragma unroll
      for (int mf = 0; mf < 4; mf++) {
        acc[mf][nf] = __builtin_amdgcn_mfma_f32_16x16x32_bf16(avh[mf], bh, acc[mf][nf], 0, 0, 0);
        acc[mf][nf] = __builtin_amdgcn_mfma_f32_16x16x32_bf16(avl[mf], bh, acc[mf][nf], 0, 0, 0);
        acc[mf][nf] = __builtin_amdgcn_mfma_f32_16x16x32_bf16(avh[mf], bl, acc[mf][nf], 0, 0, 0);
      }
    }
    __builtin_amdgcn_s_setprio(0);
    __builtin_amdgcn_sched_barrier(0);
    __builtin_amdgcn_s_barrier();
  }

  // epilogue: D frag: col = lane&15, row = (lane>>4)*4 + r
  const int r0 = m0 + wr + (lane >> 4) * 4;
  const int c0 = n0 + wc + fm;
  #pragma unroll
  for (int mf = 0; mf < 4; mf++) {
    #pragma unroll
    for (int nf = 0; nf < 4; nf++) {
      const int col = c0 + nf * 16;
      #pragma unroll
      for (int r = 0; r < 4; r++) {
        const int row = r0 + mf * 16 + r;
        const size_t idx = (size_t)row * N + col;   // logical (C, aux)
        float v = acc[mf][nf][r];
        float o;
        if constexpr (EPI == 0) {
          o = v;
        } else if constexpr (EPI == 2) {
          o = v + aux[idx];
        } else if constexpr (EPI == 3) {
          v += bias[col];
          o = 0.5f * v * (1.f + erff(v * 0.70710678118654752f));
        } else if constexpr (EPI == 4) {
          o = v + bias[col] + aux[idx];
        } else {
          v += bias[col];
          o = wave2[0] * sinf(v) + wave2[1] * cosf(v);
        }
        if constexpr (OSPLIT == 0) {
          C[idx] = o;
        } else {
          const size_t sidx = swz_idx(row, col, N);
          const unsigned int hb = bfh16(o);
          Ch[sidx] = (u16)hb;
          Cl[sidx] = (u16)bfh16(o - __uint_as_float(hb << 16));
        }
      }
    }
  }
}

// ---- launch --------------------------------------------------------------

extern "C" void kernel_launch(void* const* d_in, const int* in_sizes, int n_in,
                              void* d_out, int out_size, void* d_ws, size_t ws_size,
                              hipStream_t stream) {
  (void)in_sizes; (void)n_in; (void)out_size;
  const float* x    = (const float*)d_in[0];
  const float* t    = (const float*)d_in[1];
  const float* embW = (const float*)d_in[2];
  const float* embB = (const float*)d_in[3];
  const float* ln1w = (const float*)d_in[4];
  const float* ln1b = (const float*)d_in[5];
  const float* ln2w = (const float*)d_in[6];
  const float* ln2b = (const float*)d_in[7];
  const float* WQ   = (const float*)d_in[8];
  const float* WK   = (const float*)d_in[9];
  const float* WV   = (const float*)d_in[10];
  const float* WG   = (const float*)d_in[11];
  const float* WO   = (const float*)d_in[12];
  const float* gnw  = (const float*)d_in[13];
  const float* gnb  = (const float*)d_in[14];
  const float* f1W  = (const float*)d_in[15];
  const float* f1b  = (const float*)d_in[16];
  const float* f2W  = (const float*)d_in[17];
  const float* f2bp = (const float*)d_in[18];
  const float* h1W  = (const float*)d_in[19];
  const float* h1b  = (const float*)d_in[20];
  const float* wvw  = (const float*)d_in[21];
  const float* h2W  = (const float*)d_in[22];
  const float* h2b  = (const float*)d_in[23];
  const float* h3W  = (const float*)d_in[24];
  const float* h3b  = (const float*)d_in[25];

  // ---- packed-weight area (bf16 hi/lo, swizzled [N][K]) ----
  u16* P = (u16*)d_ws;
  const size_t SQKVG = 3072 * 512, SWO = 512 * 1024;
  const size_t SF1 = 128 * 512, SF2 = 512 * 128;
  const size_t PERL = 2 * (SQKVG + SWO + SF1 + SF2);
  const size_t HOFF = 4 * PERL;                 // heads after layers
  const size_t PACK_BYTES = (HOFF + 4 * 512 * 512) * 2;  // = 37748736
  const size_t TAB_BYTES = 36864 * 4;           // rotation/decay tables

  u16* h1h = P + HOFF;
  u16* h1l = h1h + 512 * 512;
  u16* h2h = h1l + 512 * 512;
  u16* h2l = h2h + 512 * 512;
  float* RT = (float*)((char*)d_ws + PACK_BYTES);

  const dim3 blk(256);

  // tables + pack all weights once
  tab_kernel<<<dim3(80), blk, 0, stream>>>(RT);
  for (int l = 0; l < 4; l++) {
    u16* qkvh = P + l * PERL;
    u16* qkvl = qkvh + SQKVG;
    u16* woh  = qkvl + SQKVG;
    u16* wol  = woh + SWO;
    u16* f1h  = wol + SWO;
    u16* f1l  = f1h + SF1;
    u16* f2h  = f1l + SF1;
    u16* f2l  = f2h + SF2;
    pack_qkvg<<<dim3(SQKVG / 256), blk, 0, stream>>>(
        WQ + (size_t)l * 262144, WK + (size_t)l * 262144,
        WV + (size_t)l * 524288, WG + (size_t)l * 524288, qkvh, qkvl);
    pack_plain<<<dim3(SWO / 256), blk, 0, stream>>>(WO + (size_t)l * 524288, woh, wol, 512, 10);
    pack_plain<<<dim3(SF1 / 256), blk, 0, stream>>>(f1W + (size_t)l * 65536, f1h, f1l, 128, 9);
    pack_plain<<<dim3(SF2 / 256), blk, 0, stream>>>(f2W + (size_t)l * 65536, f2h, f2l, 512, 7);
  }
  pack_plain<<<dim3(1024), blk, 0, stream>>>(h1W, h1h, h1l, 512, 9);
  pack_plain<<<dim3(1024), blk, 0, stream>>>(h2W, h2h, h2l, 512, 9);

  // ---- batch-chunking: NC=4 (R11: L3-resident inter-kernel working set)
  const size_t BASE = PACK_BYTES + TAB_BYTES;
  int NC = 4;
  while (NC < 256) {
    const size_t R = 65536u / NC;
    if (BASE + R * 22528 + 4096 <= ws_size) break;
    NC <<= 1;
  }
  const int R = 65536 / NC;   // rows per chunk (multiple of 256)

  float* Xf   = (float*)((char*)d_ws + BASE);  // R x 512 residual
  float* Xn   = Xf  + (size_t)R * 512;   // R x 512   LN planes
  float* QKVG = Xn  + (size_t)R * 512;   // R x 3072  QKVG fp32
  float* GYb  = QKVG + (size_t)R * 3072; // R x 1024  GY planes / mid / H1
  float* Yr   = GYb + (size_t)R * 1024;  // R x 512   Yr residual / H2 fp32

  u16* Xnh = (u16*)Xn;           u16* Xnl = Xnh + (size_t)R * 512;
  u16* GYh = (u16*)GYb;          u16* GYl = GYh + (size_t)R * 1024;
  u16* midh = (u16*)GYb;         u16* midl = midh + (size_t)R * 128;
  u16* H1h = (u16*)GYb;          u16* H1l = H1h + (size_t)R * 512;

  for (int c = 0; c < NC; c++) {
    const size_t off = (size_t)c * R;
    embed_kernel<<<dim3(R / 4), blk, 0, stream>>>(x + off, t + off, embW, embB, Xf);

    for (int l = 0; l < 4; l++) {
      u16* qkvh = P + l * PERL;
      u16* qkvl = qkvh + SQKVG;
      u16* woh  = qkvl + SQKVG;
      u16* wol  = woh + SWO;
      u16* f1h  = wol + SWO;
      u16* f1l  = f1h + SF1;
      u16* f2h  = f1l + SF1;
      u16* f2l  = f2h + SF2;

      ln_split<<<dim3(R / 4), blk, 0, stream>>>(Xf, ln1w + l * 512, ln1b + l * 512, Xnh, Xnl);
      // [Q|K|V|G] = Xn @ [WQ|WK|WV|WG][l] - 128x256 tile kernel
      gemm_qkvg<<<dim3(12, R / 128), dim3(512), 0, stream>>>(
          Xnh, Xnl, qkvh, qkvl, QKVG, 3072, 512);
      // MFMA retention attention (rotation at staging) + groupnorm + gate
      attn_mfma<<<dim3(R / 64, 8), blk, 0, stream>>>(
          QKVG, GYh, GYl, gnw + l * 1024, gnb + l * 1024, RT);
      // Yr = GY @ WO[l] + X
      gemm_lds<2, 0><<<dim3(4, R / 128), blk, 0, stream>>>(
          GYh, GYl, woh, wol, Yr, nullptr, nullptr,
          512, 1024, nullptr, Xf, nullptr);
      ln_split<<<dim3(R / 4), blk, 0, stream>>>(Yr, ln2w + l * 512, ln2b + l * 512, Xnh, Xnl);
      // mid = gelu(Xn @ f1[l] + b1)  -> split planes (GY slot dead)
      gemm_lds<3, 1><<<dim3(1, R / 128), blk, 0, stream>>>(
          Xnh, Xnl, f1h, f1l, nullptr, midh, midl,
          128, 512, f1b + l * 128, nullptr, nullptr);
      // X = mid @ f2[l] + b2 + Yr
      gemm_lds<4, 0><<<dim3(4, R / 128), blk, 0, stream>>>(
          midh, midl, f2h, f2l, Xf, nullptr, nullptr,
          512, 128, f2bp + l * 512, Yr, nullptr);
    }

    // head: split Xf once, then gemm_lds all the way
    split_kernel<<<dim3(R / 4), blk, 0, stream>>>(Xf, Xnh, Xnl);
    gemm_lds<5, 1><<<dim3(4, R / 128), blk, 0, stream>>>(
        Xnh, Xnl, h1h, h1l, nullptr, H1h, H1l,
        512, 512, h1b, nullptr, wvw);
    gemm_lds<5, 0><<<dim3(4, R / 128), blk, 0, stream>>>(
        H1h, H1l, h2h, h2l, Yr, nullptr, nullptr,
        512, 512, h2b, nullptr, wvw + 2);
    head3_kernel<<<dim3(R / 4), blk, 0, stream>>>(
        Yr, h3W, h3b, (float*)d_out + off);
  }
}